// Round 1
// baseline (996.175 us; speedup 1.0000x reference)
//
#include <hip/hip_runtime.h>
#include <math.h>

#define NN 50000
#define EE 800000
#define E2 850000   // EE + NN self loops

// ---------------- edge helpers ----------------
__device__ __forceinline__ int edge_src(const int* ei, int e) {
  return (e < EE) ? ei[e] : (e - EE);
}
__device__ __forceinline__ int edge_dst(const int* ei, int e) {
  return (e < EE) ? ei[EE + e] : (e - EE);
}

// ---------------- CSR build ----------------
__global__ void k_deg(const int* __restrict__ ei, int* __restrict__ deg) {
  int e = blockIdx.x * blockDim.x + threadIdx.x;
  if (e < E2) atomicAdd(&deg[edge_dst(ei, e)], 1);
}

__global__ void k_scan(const int* __restrict__ deg, int* __restrict__ rowptr) {
  __shared__ int sdata[1024];
  __shared__ int sbase;
  if (threadIdx.x == 0) { sbase = 0; rowptr[0] = 0; }
  __syncthreads();
  for (int start = 0; start < NN; start += 1024) {
    int i = start + threadIdx.x;
    int v = (i < NN) ? deg[i] : 0;
    sdata[threadIdx.x] = v;
    __syncthreads();
    for (int off = 1; off < 1024; off <<= 1) {
      int t = 0;
      if (threadIdx.x >= off) t = sdata[threadIdx.x - off];
      __syncthreads();
      if (threadIdx.x >= off) sdata[threadIdx.x] += t;
      __syncthreads();
    }
    if (i < NN) rowptr[i + 1] = sbase + sdata[threadIdx.x];
    __syncthreads();
    if (threadIdx.x == 0) sbase += sdata[1023];
    __syncthreads();
  }
}

__global__ void k_fill(const int* __restrict__ ei, const int* __restrict__ rowptr,
                       int* __restrict__ cnt, int* __restrict__ csr) {
  int e = blockIdx.x * blockDim.x + threadIdx.x;
  if (e >= E2) return;
  int d = edge_dst(ei, e);
  int s = edge_src(ei, e);
  int pos = rowptr[d] + atomicAdd(&cnt[d], 1);
  csr[pos] = s;
}

__global__ void k_dinv(const int* __restrict__ deg, float* __restrict__ dinv) {
  int i = blockIdx.x * blockDim.x + threadIdx.x;
  if (i < NN) dinv[i] = rsqrtf(fmaxf((float)deg[i], 1e-12f));
}

// ---------------- generic fp32 GEMM: C = act(A[M,K] @ B[K,NC] + bias) ----------------
// K, NC multiples of 64. act: 0 none, 1 relu.
__global__ __launch_bounds__(256) void k_gemm(const float* __restrict__ A,
                                              const float* __restrict__ B,
                                              const float* __restrict__ bias,
                                              float* __restrict__ C,
                                              int M, int K, int NC, int act) {
  __shared__ float As[64][68];  // transposed: As[k_local][row_local]
  __shared__ float Bs[64][68];  // Bs[k_local][col_local]
  int tx = threadIdx.x & 15;
  int ty = threadIdx.x >> 4;
  int rowBase = blockIdx.x * 64;
  int colBase = blockIdx.y * 64;
  float acc[4][4];
#pragma unroll
  for (int i = 0; i < 4; ++i)
#pragma unroll
    for (int j = 0; j < 4; ++j) acc[i][j] = 0.f;

  for (int kc = 0; kc < K; kc += 64) {
#pragma unroll
    for (int l = 0; l < 4; ++l) {
      int r = ty + l * 16;
      int gr = rowBase + r;
      float4 av = make_float4(0.f, 0.f, 0.f, 0.f);
      if (gr < M) av = *(const float4*)&A[(size_t)gr * K + kc + tx * 4];
      As[tx * 4 + 0][r] = av.x;
      As[tx * 4 + 1][r] = av.y;
      As[tx * 4 + 2][r] = av.z;
      As[tx * 4 + 3][r] = av.w;
      float4 bv = *(const float4*)&B[(size_t)(kc + r) * NC + colBase + tx * 4];
      *(float4*)&Bs[r][tx * 4] = bv;
    }
    __syncthreads();
#pragma unroll
    for (int kk = 0; kk < 64; ++kk) {
      float4 av = *(const float4*)&As[kk][ty * 4];
      float4 bv = *(const float4*)&Bs[kk][tx * 4];
      float a_[4] = {av.x, av.y, av.z, av.w};
      float b_[4] = {bv.x, bv.y, bv.z, bv.w};
#pragma unroll
      for (int i = 0; i < 4; ++i)
#pragma unroll
        for (int j = 0; j < 4; ++j) acc[i][j] = fmaf(a_[i], b_[j], acc[i][j]);
    }
    __syncthreads();
  }

  float4 bb = make_float4(0.f, 0.f, 0.f, 0.f);
  if (bias) bb = *(const float4*)&bias[colBase + tx * 4];
#pragma unroll
  for (int i = 0; i < 4; ++i) {
    int gr = rowBase + ty * 4 + i;
    if (gr < M) {
      float4 v;
      v.x = acc[i][0] + bb.x;
      v.y = acc[i][1] + bb.y;
      v.z = acc[i][2] + bb.z;
      v.w = acc[i][3] + bb.w;
      if (act == 1) {
        v.x = fmaxf(v.x, 0.f); v.y = fmaxf(v.y, 0.f);
        v.z = fmaxf(v.z, 0.f); v.w = fmaxf(v.w, 0.f);
      }
      *(float4*)&C[(size_t)gr * NC + colBase + tx * 4] = v;
    }
  }
}

// ---------------- attention dot products ----------------
// es[n,h] = sum_d h1[n,h*64+d]*a_src[h,d]; 4 heads, 256 channels. wave per node.
__global__ void k_dots1(const float* __restrict__ h1, const float* __restrict__ a_src,
                        const float* __restrict__ a_dst, float* __restrict__ es,
                        float* __restrict__ ed) {
  int wave = threadIdx.x >> 6;
  int lane = threadIdx.x & 63;
  int i = blockIdx.x * 4 + wave;
  if (i >= NN) return;
  float4 hv = *(const float4*)&h1[(size_t)i * 256 + lane * 4];
  float4 as = *(const float4*)&a_src[lane * 4];
  float4 ad = *(const float4*)&a_dst[lane * 4];
  float ps = hv.x * as.x + hv.y * as.y + hv.z * as.z + hv.w * as.w;
  float pd = hv.x * ad.x + hv.y * ad.y + hv.z * ad.z + hv.w * ad.w;
#pragma unroll
  for (int off = 8; off > 0; off >>= 1) {
    ps += __shfl_xor(ps, off);
    pd += __shfl_xor(pd, off);
  }
  if ((lane & 15) == 0) {
    int h = lane >> 4;
    es[i * 4 + h] = ps;
    ed[i * 4 + h] = pd;
  }
}

// 1 head, 64 channels. wave per node.
__global__ void k_dots2(const float* __restrict__ h2, const float* __restrict__ a_src,
                        const float* __restrict__ a_dst, float* __restrict__ es,
                        float* __restrict__ ed) {
  int wave = threadIdx.x >> 6;
  int lane = threadIdx.x & 63;
  int i = blockIdx.x * 4 + wave;
  if (i >= NN) return;
  float h = h2[(size_t)i * 64 + lane];
  float ps = h * a_src[lane];
  float pd = h * a_dst[lane];
#pragma unroll
  for (int off = 32; off > 0; off >>= 1) {
    ps += __shfl_xor(ps, off);
    pd += __shfl_xor(pd, off);
  }
  if (lane == 0) { es[i] = ps; ed[i] = pd; }
}

__device__ __forceinline__ float leaky(float x) { return x > 0.f ? x : 0.2f * x; }

// ---------------- GAT layer-1 aggregation (4 heads x 64) ----------------
__global__ void k_gat1(const float* __restrict__ h1, const float* __restrict__ es,
                       const float* __restrict__ ed, const int* __restrict__ rowptr,
                       const int* __restrict__ csr, const float* __restrict__ b1,
                       float* __restrict__ out) {
  int wave = threadIdx.x >> 6;
  int lane = threadIdx.x & 63;
  int i = blockIdx.x * 4 + wave;
  if (i >= NN) return;
  int start = rowptr[i], end = rowptr[i + 1];
  float4 edv = *(const float4*)&ed[i * 4];

  float m0 = -1e30f, m1 = -1e30f, m2 = -1e30f, m3 = -1e30f;
  float s0 = 0.f, s1 = 0.f, s2 = 0.f, s3 = 0.f;
  for (int k = start + lane; k < end; k += 64) {
    int s = csr[k];
    float4 esv = *(const float4*)&es[s * 4];
    float e0 = leaky(esv.x + edv.x);
    float e1 = leaky(esv.y + edv.y);
    float e2 = leaky(esv.z + edv.z);
    float e3 = leaky(esv.w + edv.w);
    float mn;
    mn = fmaxf(m0, e0); s0 = s0 * __expf(m0 - mn) + __expf(e0 - mn); m0 = mn;
    mn = fmaxf(m1, e1); s1 = s1 * __expf(m1 - mn) + __expf(e1 - mn); m1 = mn;
    mn = fmaxf(m2, e2); s2 = s2 * __expf(m2 - mn) + __expf(e2 - mn); m2 = mn;
    mn = fmaxf(m3, e3); s3 = s3 * __expf(m3 - mn) + __expf(e3 - mn); m3 = mn;
  }
#pragma unroll
  for (int off = 32; off > 0; off >>= 1) {
    float mo, so, mn;
    mo = __shfl_xor(m0, off); so = __shfl_xor(s0, off);
    mn = fmaxf(m0, mo); s0 = s0 * __expf(m0 - mn) + so * __expf(mo - mn); m0 = mn;
    mo = __shfl_xor(m1, off); so = __shfl_xor(s1, off);
    mn = fmaxf(m1, mo); s1 = s1 * __expf(m1 - mn) + so * __expf(mo - mn); m1 = mn;
    mo = __shfl_xor(m2, off); so = __shfl_xor(s2, off);
    mn = fmaxf(m2, mo); s2 = s2 * __expf(m2 - mn) + so * __expf(mo - mn); m2 = mn;
    mo = __shfl_xor(m3, off); so = __shfl_xor(s3, off);
    mn = fmaxf(m3, mo); s3 = s3 * __expf(m3 - mn) + so * __expf(mo - mn); m3 = mn;
  }
  int h = lane >> 4;
  float mh = (h == 0) ? m0 : (h == 1) ? m1 : (h == 2) ? m2 : m3;
  float sh = (h == 0) ? s0 : (h == 1) ? s1 : (h == 2) ? s2 : s3;
  float edh = (h == 0) ? edv.x : (h == 1) ? edv.y : (h == 2) ? edv.z : edv.w;
  float invh = 1.f / (sh + 1e-16f);

  float4 acc = make_float4(0.f, 0.f, 0.f, 0.f);
  for (int k = start; k < end; ++k) {
    int s = csr[k];
    float e = leaky(es[s * 4 + h] + edh);
    float w = __expf(e - mh) * invh;
    float4 hv = *(const float4*)&h1[(size_t)s * 256 + lane * 4];
    acc.x = fmaf(hv.x, w, acc.x);
    acc.y = fmaf(hv.y, w, acc.y);
    acc.z = fmaf(hv.z, w, acc.z);
    acc.w = fmaf(hv.w, w, acc.w);
  }
  float4 bv = *(const float4*)&b1[lane * 4];
  float4 o;
  o.x = acc.x + bv.x; o.y = acc.y + bv.y; o.z = acc.z + bv.z; o.w = acc.w + bv.w;
  *(float4*)&out[(size_t)i * 256 + lane * 4] = o;
}

// ---------------- GCN aggregation (64 ch) ----------------
__global__ void k_gcn(const float* __restrict__ hg, const float* __restrict__ dinv,
                      const int* __restrict__ rowptr, const int* __restrict__ csr,
                      const float* __restrict__ bg, float* __restrict__ out) {
  int wave = threadIdx.x >> 6;
  int lane = threadIdx.x & 63;
  int i = blockIdx.x * 4 + wave;
  if (i >= NN) return;
  int start = rowptr[i], end = rowptr[i + 1];
  float di = dinv[i];
  float acc = 0.f;
  for (int k = start; k < end; ++k) {
    int s = csr[k];
    acc = fmaf(hg[(size_t)s * 64 + lane], dinv[s], acc);
  }
  out[(size_t)i * 64 + lane] = acc * di + bg[lane];
}

// ---------------- GAT layer-2 aggregation (1 head x 64) ----------------
__global__ void k_gat2(const float* __restrict__ h2, const float* __restrict__ es,
                       const float* __restrict__ ed, const int* __restrict__ rowptr,
                       const int* __restrict__ csr, const float* __restrict__ b2,
                       float* __restrict__ out) {
  int wave = threadIdx.x >> 6;
  int lane = threadIdx.x & 63;
  int i = blockIdx.x * 4 + wave;
  if (i >= NN) return;
  int start = rowptr[i], end = rowptr[i + 1];
  float edi = ed[i];
  float m = -1e30f, ssum = 0.f;
  for (int k = start + lane; k < end; k += 64) {
    int s = csr[k];
    float e = leaky(es[s] + edi);
    float mn = fmaxf(m, e);
    ssum = ssum * __expf(m - mn) + __expf(e - mn);
    m = mn;
  }
#pragma unroll
  for (int off = 32; off > 0; off >>= 1) {
    float mo = __shfl_xor(m, off);
    float so = __shfl_xor(ssum, off);
    float mn = fmaxf(m, mo);
    ssum = ssum * __expf(m - mn) + so * __expf(mo - mn);
    m = mn;
  }
  float inv = 1.f / (ssum + 1e-16f);
  float acc = 0.f;
  for (int k = start; k < end; ++k) {
    int s = csr[k];
    float e = leaky(es[s] + edi);
    float w = __expf(e - m) * inv;
    acc = fmaf(h2[(size_t)s * 64 + lane], w, acc);
  }
  out[(size_t)i * 64 + lane] = acc + b2[lane];
}

// ---------------- BatchNorm ----------------
// stats[c] = sum, stats[C+c] = sumsq (must be pre-zeroed)
__global__ void k_bnstats(const float* __restrict__ x, float* __restrict__ stats, int C) {
  int tid = threadIdx.x;
  int c = tid & (C - 1);
  int rpb = 256 / C;
  int rsub = tid / C;
  float sum = 0.f, sq = 0.f;
  for (int r = blockIdx.x * rpb + rsub; r < NN; r += gridDim.x * rpb) {
    float v = x[(size_t)r * C + c];
    sum += v;
    sq = fmaf(v, v, sq);
  }
  atomicAdd(&stats[c], sum);
  atomicAdd(&stats[C + c], sq);
}

// act: 1 relu, 2 elu
__global__ void k_bnapply(float* __restrict__ x, const float* __restrict__ stats,
                          const float* __restrict__ g, const float* __restrict__ beta,
                          int C, int act, int total4) {
  int idx = blockIdx.x * blockDim.x + threadIdx.x;
  if (idx >= total4) return;
  int i = idx * 4;
  int c0 = i & (C - 1);
  float4 v = *(float4*)&x[i];
  float vv[4] = {v.x, v.y, v.z, v.w};
  const float invN = 1.0f / (float)NN;
#pragma unroll
  for (int j = 0; j < 4; ++j) {
    int c = c0 + j;
    float mu = stats[c] * invN;
    float var = stats[C + c] * invN - mu * mu;
    float rs = rsqrtf(var + 1e-5f);
    float y = (vv[j] - mu) * rs * g[c] + beta[c];
    if (act == 1) y = fmaxf(y, 0.f);
    else y = (y > 0.f) ? y : expm1f(y);
    vv[j] = y;
  }
  v.x = vv[0]; v.y = vv[1]; v.z = vv[2]; v.w = vv[3];
  *(float4*)&x[i] = v;
}

// ---------------- host ----------------
extern "C" void kernel_launch(void* const* d_in, const int* in_sizes, int n_in,
                              void* d_out, int out_size, void* d_ws, size_t ws_size,
                              hipStream_t stream) {
  const float* x        = (const float*)d_in[0];
  const int*   ei       = (const int*)d_in[1];
  // d_in[2] edge_attr ignored
  const float* W1       = (const float*)d_in[3];
  const float* att_src1 = (const float*)d_in[4];
  const float* att_dst1 = (const float*)d_in[5];
  const float* b1       = (const float*)d_in[6];
  const float* g1       = (const float*)d_in[7];
  const float* beta1    = (const float*)d_in[8];
  const float* Wg       = (const float*)d_in[9];
  const float* bg       = (const float*)d_in[10];
  const float* g2       = (const float*)d_in[11];
  const float* beta2    = (const float*)d_in[12];
  const float* W2       = (const float*)d_in[13];
  const float* att_src2 = (const float*)d_in[14];
  const float* att_dst2 = (const float*)d_in[15];
  const float* b2       = (const float*)d_in[16];
  const float* g3       = (const float*)d_in[17];
  const float* beta3    = (const float*)d_in[18];
  const float* Wp1      = (const float*)d_in[19];
  const float* bp1      = (const float*)d_in[20];
  const float* Wp2      = (const float*)d_in[21];
  const float* bp2      = (const float*)d_in[22];
  float* out = (float*)d_out;

  char* w = (char*)d_ws;
  const size_t OFF_BUFA = 0;                          // N*256 f32
  const size_t OFF_BUFB = 51200000;                   // N*256 f32
  const size_t OFF_BUFC = 102400000;                  // N*128 f32
  const size_t OFF_ES1  = 128000000;                  // N*4 f32
  const size_t OFF_ED1  = 128800000;                  // N*4 f32
  const size_t OFF_ES2  = 129600000;                  // N f32
  const size_t OFF_ED2  = 129800000;                  // N f32
  const size_t OFF_DINV = 130000000;                  // N f32
  const size_t OFF_DEG  = 130200000;                  // N i32
  const size_t OFF_RP   = 130400000;                  // (N+1) i32
  const size_t OFF_CNT  = 130600256;                  // N i32
  const size_t OFF_CSR  = 130800256;                  // E2 i32
  const size_t OFF_ST   = 134200256;                  // 768 f32 (3 stat sets)

  float* bufA  = (float*)(w + OFF_BUFA);
  float* bufB  = (float*)(w + OFF_BUFB);
  float* bufC  = (float*)(w + OFF_BUFC);
  float* es1   = (float*)(w + OFF_ES1);
  float* ed1   = (float*)(w + OFF_ED1);
  float* es2   = (float*)(w + OFF_ES2);
  float* ed2   = (float*)(w + OFF_ED2);
  float* dinv  = (float*)(w + OFF_DINV);
  int*   deg   = (int*)(w + OFF_DEG);
  int*   rowptr= (int*)(w + OFF_RP);
  int*   cnt   = (int*)(w + OFF_CNT);
  int*   csr   = (int*)(w + OFF_CSR);
  float* st1   = (float*)(w + OFF_ST);        // 512 floats
  float* st2   = st1 + 512;                   // 128 floats
  float* st3   = st2 + 128;                   // 128 floats

  // zero accumulators (ws is re-poisoned before every call)
  hipMemsetAsync(deg, 0, NN * sizeof(int), stream);
  hipMemsetAsync(cnt, 0, NN * sizeof(int), stream);
  hipMemsetAsync(st1, 0, 768 * sizeof(float), stream);

  const int EB = (E2 + 255) / 256;
  const int NB = (NN + 255) / 256;
  const int WB = NN / 4;  // wave-per-node blocks (4 waves of 64 per 256-thread block)

  // CSR build
  k_deg<<<EB, 256, 0, stream>>>(ei, deg);
  k_scan<<<1, 1024, 0, stream>>>(deg, rowptr);
  k_fill<<<EB, 256, 0, stream>>>(ei, rowptr, cnt, csr);
  k_dinv<<<NB, 256, 0, stream>>>(deg, dinv);

  // GAT1: h1 = x @ W1  [N,256]
  k_gemm<<<dim3((NN + 63) / 64, 4), 256, 0, stream>>>(x, W1, nullptr, bufA, NN, 128, 256, 0);
  k_dots1<<<WB, 256, 0, stream>>>(bufA, att_src1, att_dst1, es1, ed1);
  k_gat1<<<WB, 256, 0, stream>>>(bufA, es1, ed1, rowptr, csr, b1, bufB);
  // BN1 + ELU (in place on bufB)
  k_bnstats<<<512, 256, 0, stream>>>(bufB, st1, 256);
  k_bnapply<<<(NN * 256 / 4 + 255) / 256, 256, 0, stream>>>(bufB, st1, g1, beta1, 256, 2, NN * 256 / 4);

  // GCN: hg = bufB @ Wg [N,64] -> bufA ; aggregate -> bufC (first N*64)
  k_gemm<<<dim3((NN + 63) / 64, 1), 256, 0, stream>>>(bufB, Wg, nullptr, bufA, NN, 256, 64, 0);
  k_gcn<<<WB, 256, 0, stream>>>(bufA, dinv, rowptr, csr, bg, bufC);
  // BN2 + ReLU
  k_bnstats<<<512, 256, 0, stream>>>(bufC, st2, 64);
  k_bnapply<<<(NN * 64 / 4 + 255) / 256, 256, 0, stream>>>(bufC, st2, g2, beta2, 64, 1, NN * 64 / 4);

  // GAT2: h2 = bufC @ W2 [N,64] -> bufA
  k_gemm<<<dim3((NN + 63) / 64, 1), 256, 0, stream>>>(bufC, W2, nullptr, bufA, NN, 64, 64, 0);
  k_dots2<<<WB, 256, 0, stream>>>(bufA, att_src2, att_dst2, es2, ed2);
  k_gat2<<<WB, 256, 0, stream>>>(bufA, es2, ed2, rowptr, csr, b2, bufB);
  // BN3 + ELU
  k_bnstats<<<512, 256, 0, stream>>>(bufB, st3, 64);
  k_bnapply<<<(NN * 64 / 4 + 255) / 256, 256, 0, stream>>>(bufB, st3, g3, beta3, 64, 2, NN * 64 / 4);

  // projector: relu(bufB @ Wp1 + bp1) -> bufC [N,128]; bufC @ Wp2 + bp2 -> out [N,64]
  k_gemm<<<dim3((NN + 63) / 64, 2), 256, 0, stream>>>(bufB, Wp1, bp1, bufC, NN, 64, 128, 1);
  k_gemm<<<dim3((NN + 63) / 64, 1), 256, 0, stream>>>(bufC, Wp2, bp2, out, NN, 128, 64, 0);
}

// Round 2
// 950.705 us; speedup vs baseline: 1.0478x; 1.0478x over previous
//
#include <hip/hip_runtime.h>
#include <math.h>

#define NN 50000
#define EE 800000
#define E2 850000   // EE + NN self loops

// ---------------- bf16 helpers ----------------
__device__ __forceinline__ float bf2f(unsigned short u) {
  return __uint_as_float(((unsigned int)u) << 16);
}
__device__ __forceinline__ unsigned short f2bf(float f) {
  unsigned int x = __float_as_uint(f);
  unsigned int r = (x + 0x7fffu + ((x >> 16) & 1u)) >> 16;  // RNE
  return (unsigned short)r;
}

// ---------------- edge helpers ----------------
__device__ __forceinline__ int edge_src(const int* ei, int e) {
  return (e < EE) ? ei[e] : (e - EE);
}
__device__ __forceinline__ int edge_dst(const int* ei, int e) {
  return (e < EE) ? ei[EE + e] : (e - EE);
}

// ---------------- CSR build ----------------
__global__ void k_deg(const int* __restrict__ ei, int* __restrict__ deg) {
  int e = blockIdx.x * blockDim.x + threadIdx.x;
  if (e < E2) atomicAdd(&deg[edge_dst(ei, e)], 1);
}

// single block, thread-sequential chunks: ~25 barriers total instead of ~1000
__global__ __launch_bounds__(1024) void k_scan(const int* __restrict__ deg,
                                               int* __restrict__ rowptr) {
  __shared__ int totals[1024];
  const int CH = (NN + 1023) / 1024;  // 49
  int t = threadIdx.x;
  int beg = t * CH;
  int end = beg + CH;
  if (end > NN) end = NN;
  int s = 0;
  for (int i = beg; i < end; ++i) s += deg[i];
  totals[t] = s;
  __syncthreads();
  for (int off = 1; off < 1024; off <<= 1) {
    int v = 0;
    if (t >= off) v = totals[t - off];
    __syncthreads();
    if (t >= off) totals[t] += v;
    __syncthreads();
  }
  int base = (t == 0) ? 0 : totals[t - 1];
  for (int i = beg; i < end; ++i) {
    rowptr[i] = base;
    base += deg[i];
  }
  if (t == 0) rowptr[NN] = E2;  // total edge count is fixed
}

__global__ void k_fill(const int* __restrict__ ei, const int* __restrict__ rowptr,
                       int* __restrict__ cnt, int* __restrict__ csr) {
  int e = blockIdx.x * blockDim.x + threadIdx.x;
  if (e >= E2) return;
  int d = edge_dst(ei, e);
  int s = edge_src(ei, e);
  int pos = rowptr[d] + atomicAdd(&cnt[d], 1);
  csr[pos] = s;
}

__global__ void k_dinv(const int* __restrict__ deg, float* __restrict__ dinv) {
  int i = blockIdx.x * blockDim.x + threadIdx.x;
  if (i < NN) dinv[i] = rsqrtf(fmaxf((float)deg[i], 1e-12f));
}

// ---------------- generic fp32 GEMM: C = act(A[M,K] @ B[K,NC] + bias) ----------------
// K, NC multiples of 64. act: 0 none, 1 relu. Cbf: optional bf16 mirror of C.
__global__ __launch_bounds__(256) void k_gemm(const float* __restrict__ A,
                                              const float* __restrict__ B,
                                              const float* __restrict__ bias,
                                              float* __restrict__ C,
                                              unsigned short* __restrict__ Cbf,
                                              int M, int K, int NC, int act) {
  __shared__ float As[64][68];  // transposed: As[k_local][row_local]
  __shared__ float Bs[64][68];  // Bs[k_local][col_local]
  int tx = threadIdx.x & 15;
  int ty = threadIdx.x >> 4;
  int rowBase = blockIdx.x * 64;
  int colBase = blockIdx.y * 64;
  float acc[4][4];
#pragma unroll
  for (int i = 0; i < 4; ++i)
#pragma unroll
    for (int j = 0; j < 4; ++j) acc[i][j] = 0.f;

  for (int kc = 0; kc < K; kc += 64) {
#pragma unroll
    for (int l = 0; l < 4; ++l) {
      int r = ty + l * 16;
      int gr = rowBase + r;
      float4 av = make_float4(0.f, 0.f, 0.f, 0.f);
      if (gr < M) av = *(const float4*)&A[(size_t)gr * K + kc + tx * 4];
      As[tx * 4 + 0][r] = av.x;
      As[tx * 4 + 1][r] = av.y;
      As[tx * 4 + 2][r] = av.z;
      As[tx * 4 + 3][r] = av.w;
      float4 bv = *(const float4*)&B[(size_t)(kc + r) * NC + colBase + tx * 4];
      *(float4*)&Bs[r][tx * 4] = bv;
    }
    __syncthreads();
#pragma unroll
    for (int kk = 0; kk < 64; ++kk) {
      float4 av = *(const float4*)&As[kk][ty * 4];
      float4 bv = *(const float4*)&Bs[kk][tx * 4];
      float a_[4] = {av.x, av.y, av.z, av.w};
      float b_[4] = {bv.x, bv.y, bv.z, bv.w};
#pragma unroll
      for (int i = 0; i < 4; ++i)
#pragma unroll
        for (int j = 0; j < 4; ++j) acc[i][j] = fmaf(a_[i], b_[j], acc[i][j]);
    }
    __syncthreads();
  }

  float4 bb = make_float4(0.f, 0.f, 0.f, 0.f);
  if (bias) bb = *(const float4*)&bias[colBase + tx * 4];
#pragma unroll
  for (int i = 0; i < 4; ++i) {
    int gr = rowBase + ty * 4 + i;
    if (gr < M) {
      float4 v;
      v.x = acc[i][0] + bb.x;
      v.y = acc[i][1] + bb.y;
      v.z = acc[i][2] + bb.z;
      v.w = acc[i][3] + bb.w;
      if (act == 1) {
        v.x = fmaxf(v.x, 0.f); v.y = fmaxf(v.y, 0.f);
        v.z = fmaxf(v.z, 0.f); v.w = fmaxf(v.w, 0.f);
      }
      *(float4*)&C[(size_t)gr * NC + colBase + tx * 4] = v;
      if (Cbf) {
        ushort4 u;
        u.x = f2bf(v.x); u.y = f2bf(v.y); u.z = f2bf(v.z); u.w = f2bf(v.w);
        *(ushort4*)&Cbf[(size_t)gr * NC + colBase + tx * 4] = u;
      }
    }
  }
}

// ---------------- attention dot products ----------------
__global__ void k_dots1(const float* __restrict__ h1, const float* __restrict__ a_src,
                        const float* __restrict__ a_dst, float* __restrict__ es,
                        float* __restrict__ ed) {
  int wave = threadIdx.x >> 6;
  int lane = threadIdx.x & 63;
  int i = blockIdx.x * 4 + wave;
  if (i >= NN) return;
  float4 hv = *(const float4*)&h1[(size_t)i * 256 + lane * 4];
  float4 as = *(const float4*)&a_src[lane * 4];
  float4 ad = *(const float4*)&a_dst[lane * 4];
  float ps = hv.x * as.x + hv.y * as.y + hv.z * as.z + hv.w * as.w;
  float pd = hv.x * ad.x + hv.y * ad.y + hv.z * ad.z + hv.w * ad.w;
#pragma unroll
  for (int off = 8; off > 0; off >>= 1) {
    ps += __shfl_xor(ps, off);
    pd += __shfl_xor(pd, off);
  }
  if ((lane & 15) == 0) {
    int h = lane >> 4;
    es[i * 4 + h] = ps;
    ed[i * 4 + h] = pd;
  }
}

__global__ void k_dots2(const float* __restrict__ h2, const float* __restrict__ a_src,
                        const float* __restrict__ a_dst, float* __restrict__ es,
                        float* __restrict__ ed) {
  int wave = threadIdx.x >> 6;
  int lane = threadIdx.x & 63;
  int i = blockIdx.x * 4 + wave;
  if (i >= NN) return;
  float h = h2[(size_t)i * 64 + lane];
  float ps = h * a_src[lane];
  float pd = h * a_dst[lane];
#pragma unroll
  for (int off = 32; off > 0; off >>= 1) {
    ps += __shfl_xor(ps, off);
    pd += __shfl_xor(pd, off);
  }
  if (lane == 0) { es[i] = ps; ed[i] = pd; }
}

__device__ __forceinline__ float leaky(float x) { return x > 0.f ? x : 0.2f * x; }

// ---------------- GAT layer-1 aggregation (4 heads x 64, bf16 gather) ----------------
__global__ void k_gat1(const unsigned short* __restrict__ h1b, const float* __restrict__ es,
                       const float* __restrict__ ed, const int* __restrict__ rowptr,
                       const int* __restrict__ csr, const float* __restrict__ b1,
                       float* __restrict__ out) {
  int wave = threadIdx.x >> 6;
  int lane = threadIdx.x & 63;
  int i = blockIdx.x * 4 + wave;
  if (i >= NN) return;
  int start = rowptr[i], end = rowptr[i + 1];
  float4 edv = *(const float4*)&ed[i * 4];

  float m0 = -1e30f, m1 = -1e30f, m2 = -1e30f, m3 = -1e30f;
  float s0 = 0.f, s1 = 0.f, s2 = 0.f, s3 = 0.f;
  for (int k = start + lane; k < end; k += 64) {
    int s = csr[k];
    float4 esv = *(const float4*)&es[s * 4];
    float e0 = leaky(esv.x + edv.x);
    float e1 = leaky(esv.y + edv.y);
    float e2 = leaky(esv.z + edv.z);
    float e3 = leaky(esv.w + edv.w);
    float mn;
    mn = fmaxf(m0, e0); s0 = s0 * __expf(m0 - mn) + __expf(e0 - mn); m0 = mn;
    mn = fmaxf(m1, e1); s1 = s1 * __expf(m1 - mn) + __expf(e1 - mn); m1 = mn;
    mn = fmaxf(m2, e2); s2 = s2 * __expf(m2 - mn) + __expf(e2 - mn); m2 = mn;
    mn = fmaxf(m3, e3); s3 = s3 * __expf(m3 - mn) + __expf(e3 - mn); m3 = mn;
  }
#pragma unroll
  for (int off = 32; off > 0; off >>= 1) {
    float mo, so, mn;
    mo = __shfl_xor(m0, off); so = __shfl_xor(s0, off);
    mn = fmaxf(m0, mo); s0 = s0 * __expf(m0 - mn) + so * __expf(mo - mn); m0 = mn;
    mo = __shfl_xor(m1, off); so = __shfl_xor(s1, off);
    mn = fmaxf(m1, mo); s1 = s1 * __expf(m1 - mn) + so * __expf(mo - mn); m1 = mn;
    mo = __shfl_xor(m2, off); so = __shfl_xor(s2, off);
    mn = fmaxf(m2, mo); s2 = s2 * __expf(m2 - mn) + so * __expf(mo - mn); m2 = mn;
    mo = __shfl_xor(m3, off); so = __shfl_xor(s3, off);
    mn = fmaxf(m3, mo); s3 = s3 * __expf(m3 - mn) + so * __expf(mo - mn); m3 = mn;
  }
  int h = lane >> 4;
  float mh = (h == 0) ? m0 : (h == 1) ? m1 : (h == 2) ? m2 : m3;
  float sh = (h == 0) ? s0 : (h == 1) ? s1 : (h == 2) ? s2 : s3;
  float edh = (h == 0) ? edv.x : (h == 1) ? edv.y : (h == 2) ? edv.z : edv.w;
  float invh = 1.f / (sh + 1e-16f);

  float4 acc = make_float4(0.f, 0.f, 0.f, 0.f);
  for (int k = start; k < end; ++k) {
    int s = csr[k];
    float e = leaky(es[s * 4 + h] + edh);
    float w = __expf(e - mh);
    ushort4 hv4 = *(const ushort4*)&h1b[(size_t)s * 256 + lane * 4];
    acc.x = fmaf(bf2f(hv4.x), w, acc.x);
    acc.y = fmaf(bf2f(hv4.y), w, acc.y);
    acc.z = fmaf(bf2f(hv4.z), w, acc.z);
    acc.w = fmaf(bf2f(hv4.w), w, acc.w);
  }
  float4 bv = *(const float4*)&b1[lane * 4];
  float4 o;
  o.x = fmaf(acc.x, invh, bv.x);
  o.y = fmaf(acc.y, invh, bv.y);
  o.z = fmaf(acc.z, invh, bv.z);
  o.w = fmaf(acc.w, invh, bv.w);
  *(float4*)&out[(size_t)i * 256 + lane * 4] = o;
}

// ---------------- GCN aggregation (64 ch, bf16 gather) ----------------
__global__ void k_gcn(const unsigned short* __restrict__ hgb, const float* __restrict__ dinv,
                      const int* __restrict__ rowptr, const int* __restrict__ csr,
                      const float* __restrict__ bg, float* __restrict__ out) {
  int wave = threadIdx.x >> 6;
  int lane = threadIdx.x & 63;
  int i = blockIdx.x * 4 + wave;
  if (i >= NN) return;
  int start = rowptr[i], end = rowptr[i + 1];
  float di = dinv[i];
  float acc = 0.f;
  for (int k = start; k < end; ++k) {
    int s = csr[k];
    acc = fmaf(bf2f(hgb[(size_t)s * 64 + lane]), dinv[s], acc);
  }
  out[(size_t)i * 64 + lane] = fmaf(acc, di, bg[lane]);
}

// ---------------- GAT layer-2 aggregation (1 head x 64, bf16 gather) ----------------
__global__ void k_gat2(const unsigned short* __restrict__ h2b, const float* __restrict__ es,
                       const float* __restrict__ ed, const int* __restrict__ rowptr,
                       const int* __restrict__ csr, const float* __restrict__ b2,
                       float* __restrict__ out) {
  int wave = threadIdx.x >> 6;
  int lane = threadIdx.x & 63;
  int i = blockIdx.x * 4 + wave;
  if (i >= NN) return;
  int start = rowptr[i], end = rowptr[i + 1];
  float edi = ed[i];
  float m = -1e30f, ssum = 0.f;
  for (int k = start + lane; k < end; k += 64) {
    int s = csr[k];
    float e = leaky(es[s] + edi);
    float mn = fmaxf(m, e);
    ssum = ssum * __expf(m - mn) + __expf(e - mn);
    m = mn;
  }
#pragma unroll
  for (int off = 32; off > 0; off >>= 1) {
    float mo = __shfl_xor(m, off);
    float so = __shfl_xor(ssum, off);
    float mn = fmaxf(m, mo);
    ssum = ssum * __expf(m - mn) + so * __expf(mo - mn);
    m = mn;
  }
  float inv = 1.f / (ssum + 1e-16f);
  float acc = 0.f;
  for (int k = start; k < end; ++k) {
    int s = csr[k];
    float e = leaky(es[s] + edi);
    float w = __expf(e - m);
    acc = fmaf(bf2f(h2b[(size_t)s * 64 + lane]), w, acc);
  }
  out[(size_t)i * 64 + lane] = fmaf(acc, inv, b2[lane]);
}

// ---------------- BatchNorm ----------------
__global__ void k_bnstats(const float* __restrict__ x, float* __restrict__ stats, int C) {
  int tid = threadIdx.x;
  int c = tid & (C - 1);
  int rpb = 256 / C;
  int rsub = tid / C;
  float sum = 0.f, sq = 0.f;
  for (int r = blockIdx.x * rpb + rsub; r < NN; r += gridDim.x * rpb) {
    float v = x[(size_t)r * C + c];
    sum += v;
    sq = fmaf(v, v, sq);
  }
  atomicAdd(&stats[c], sum);
  atomicAdd(&stats[C + c], sq);
}

// act: 1 relu, 2 elu
__global__ void k_bnapply(float* __restrict__ x, const float* __restrict__ stats,
                          const float* __restrict__ g, const float* __restrict__ beta,
                          int C, int act, int total4) {
  int idx = blockIdx.x * blockDim.x + threadIdx.x;
  if (idx >= total4) return;
  int i = idx * 4;
  int c0 = i & (C - 1);
  float4 v = *(float4*)&x[i];
  float vv[4] = {v.x, v.y, v.z, v.w};
  const float invN = 1.0f / (float)NN;
#pragma unroll
  for (int j = 0; j < 4; ++j) {
    int c = c0 + j;
    float mu = stats[c] * invN;
    float var = stats[C + c] * invN - mu * mu;
    float rs = rsqrtf(var + 1e-5f);
    float y = (vv[j] - mu) * rs * g[c] + beta[c];
    if (act == 1) y = fmaxf(y, 0.f);
    else y = (y > 0.f) ? y : expm1f(y);
    vv[j] = y;
  }
  v.x = vv[0]; v.y = vv[1]; v.z = vv[2]; v.w = vv[3];
  *(float4*)&x[i] = v;
}

// ---------------- host ----------------
extern "C" void kernel_launch(void* const* d_in, const int* in_sizes, int n_in,
                              void* d_out, int out_size, void* d_ws, size_t ws_size,
                              hipStream_t stream) {
  const float* x        = (const float*)d_in[0];
  const int*   ei       = (const int*)d_in[1];
  const float* W1       = (const float*)d_in[3];
  const float* att_src1 = (const float*)d_in[4];
  const float* att_dst1 = (const float*)d_in[5];
  const float* b1       = (const float*)d_in[6];
  const float* g1       = (const float*)d_in[7];
  const float* beta1    = (const float*)d_in[8];
  const float* Wg       = (const float*)d_in[9];
  const float* bg       = (const float*)d_in[10];
  const float* g2       = (const float*)d_in[11];
  const float* beta2    = (const float*)d_in[12];
  const float* W2       = (const float*)d_in[13];
  const float* att_src2 = (const float*)d_in[14];
  const float* att_dst2 = (const float*)d_in[15];
  const float* b2       = (const float*)d_in[16];
  const float* g3       = (const float*)d_in[17];
  const float* beta3    = (const float*)d_in[18];
  const float* Wp1      = (const float*)d_in[19];
  const float* bp1      = (const float*)d_in[20];
  const float* Wp2      = (const float*)d_in[21];
  const float* bp2      = (const float*)d_in[22];
  float* out = (float*)d_out;

  char* w = (char*)d_ws;
  const size_t OFF_BUFA = 0;                          // N*256 f32 (51.2 MB)
  const size_t OFF_BUFB = 51200000;                   // N*256 f32 (51.2 MB)
  const size_t OFF_BUFC = 102400000;                  // N*128 f32 (25.6 MB)
  const size_t OFF_ES1  = 128000000;
  const size_t OFF_ED1  = 128800000;
  const size_t OFF_ES2  = 129600000;
  const size_t OFF_ED2  = 129800000;
  const size_t OFF_DINV = 130000000;
  const size_t OFF_DEG  = 130200000;
  const size_t OFF_RP   = 130400000;
  const size_t OFF_CNT  = 130600256;
  const size_t OFF_CSR  = 130800256;
  const size_t OFF_ST   = 134200256;

  float* bufA  = (float*)(w + OFF_BUFA);
  float* bufB  = (float*)(w + OFF_BUFB);
  float* bufC  = (float*)(w + OFF_BUFC);
  float* es1   = (float*)(w + OFF_ES1);
  float* ed1   = (float*)(w + OFF_ED1);
  float* es2   = (float*)(w + OFF_ES2);
  float* ed2   = (float*)(w + OFF_ED2);
  float* dinv  = (float*)(w + OFF_DINV);
  int*   deg   = (int*)(w + OFF_DEG);
  int*   rowptr= (int*)(w + OFF_RP);
  int*   cnt   = (int*)(w + OFF_CNT);
  int*   csr   = (int*)(w + OFF_CSR);
  float* st1   = (float*)(w + OFF_ST);
  float* st2   = st1 + 512;
  float* st3   = st2 + 128;

  // bf16 mirrors aliased into dead regions:
  // h1b (N*256 bf16 = 25.6 MB) lives in bufC, which is dead until k_gcn output.
  unsigned short* h1b = (unsigned short*)bufC;
  // hgb / h2b (N*64 bf16 = 6.4 MB each) live in the upper half of bufA
  // (bufA's live fp32 content in those phases is only N*64 = 12.8 MB).
  unsigned short* hgb = (unsigned short*)(w + OFF_BUFA + 25600000);
  unsigned short* h2b = (unsigned short*)(w + OFF_BUFA + 25600000);

  hipMemsetAsync(deg, 0, NN * sizeof(int), stream);
  hipMemsetAsync(cnt, 0, NN * sizeof(int), stream);
  hipMemsetAsync(st1, 0, 768 * sizeof(float), stream);

  const int EB = (E2 + 255) / 256;
  const int NB = (NN + 255) / 256;
  const int WB = NN / 4;

  // CSR build
  k_deg<<<EB, 256, 0, stream>>>(ei, deg);
  k_scan<<<1, 1024, 0, stream>>>(deg, rowptr);
  k_fill<<<EB, 256, 0, stream>>>(ei, rowptr, cnt, csr);
  k_dinv<<<NB, 256, 0, stream>>>(deg, dinv);

  // GAT1: h1 = x @ W1  [N,256] -> bufA fp32 + h1b bf16
  k_gemm<<<dim3((NN + 63) / 64, 4), 256, 0, stream>>>(x, W1, nullptr, bufA, h1b, NN, 128, 256, 0);
  k_dots1<<<WB, 256, 0, stream>>>(bufA, att_src1, att_dst1, es1, ed1);
  k_gat1<<<WB, 256, 0, stream>>>(h1b, es1, ed1, rowptr, csr, b1, bufB);
  k_bnstats<<<512, 256, 0, stream>>>(bufB, st1, 256);
  k_bnapply<<<(NN * 256 / 4 + 255) / 256, 256, 0, stream>>>(bufB, st1, g1, beta1, 256, 2, NN * 256 / 4);

  // GCN: hg = bufB @ Wg [N,64] -> bufA fp32 + hgb bf16 ; aggregate -> bufC
  k_gemm<<<dim3((NN + 63) / 64, 1), 256, 0, stream>>>(bufB, Wg, nullptr, bufA, hgb, NN, 256, 64, 0);
  k_gcn<<<WB, 256, 0, stream>>>(hgb, dinv, rowptr, csr, bg, bufC);
  k_bnstats<<<512, 256, 0, stream>>>(bufC, st2, 64);
  k_bnapply<<<(NN * 64 / 4 + 255) / 256, 256, 0, stream>>>(bufC, st2, g2, beta2, 64, 1, NN * 64 / 4);

  // GAT2: h2 = bufC @ W2 [N,64] -> bufA fp32 + h2b bf16
  k_gemm<<<dim3((NN + 63) / 64, 1), 256, 0, stream>>>(bufC, W2, nullptr, bufA, h2b, NN, 64, 64, 0);
  k_dots2<<<WB, 256, 0, stream>>>(bufA, att_src2, att_dst2, es2, ed2);
  k_gat2<<<WB, 256, 0, stream>>>(h2b, es2, ed2, rowptr, csr, b2, bufB);
  k_bnstats<<<512, 256, 0, stream>>>(bufB, st3, 64);
  k_bnapply<<<(NN * 64 / 4 + 255) / 256, 256, 0, stream>>>(bufB, st3, g3, beta3, 64, 2, NN * 64 / 4);

  // projector
  k_gemm<<<dim3((NN + 63) / 64, 2), 256, 0, stream>>>(bufB, Wp1, bp1, bufC, nullptr, NN, 64, 128, 1);
  k_gemm<<<dim3((NN + 63) / 64, 1), 256, 0, stream>>>(bufC, Wp2, bp2, out, nullptr, NN, 128, 64, 0);
}

// Round 3
// 670.948 us; speedup vs baseline: 1.4847x; 1.4170x over previous
//
#include <hip/hip_runtime.h>
#include <math.h>

#define NN 50000
#define EE 800000
#define E2 850000   // EE + NN self loops

// ---------------- bf16 helpers ----------------
__device__ __forceinline__ float bf2f(unsigned short u) {
  return __uint_as_float(((unsigned int)u) << 16);
}
__device__ __forceinline__ unsigned short f2bf(float f) {
  unsigned int x = __float_as_uint(f);
  unsigned int r = (x + 0x7fffu + ((x >> 16) & 1u)) >> 16;  // RNE
  return (unsigned short)r;
}

__device__ __forceinline__ float leaky(float x) { return x > 0.f ? x : 0.2f * x; }

// ---------------- edge helpers ----------------
__device__ __forceinline__ int edge_src(const int* ei, int e) {
  return (e < EE) ? ei[e] : (e - EE);
}
__device__ __forceinline__ int edge_dst(const int* ei, int e) {
  return (e < EE) ? ei[EE + e] : (e - EE);
}

// ---------------- CSR build ----------------
__global__ void k_deg(const int* __restrict__ ei, int* __restrict__ deg) {
  int e = blockIdx.x * blockDim.x + threadIdx.x;
  if (e < E2) atomicAdd(&deg[edge_dst(ei, e)], 1);
}

// single block; also emits cnt (=rowptr copy for fill) and dinv
__global__ __launch_bounds__(1024) void k_scan(const int* __restrict__ deg,
                                               int* __restrict__ rowptr,
                                               int* __restrict__ cnt,
                                               float* __restrict__ dinv) {
  __shared__ int totals[1024];
  const int CH = (NN + 1023) / 1024;  // 49
  int t = threadIdx.x;
  int beg = t * CH;
  int end = beg + CH;
  if (end > NN) end = NN;
  int s = 0;
  for (int i = beg; i < end; ++i) s += deg[i];
  totals[t] = s;
  __syncthreads();
  for (int off = 1; off < 1024; off <<= 1) {
    int v = 0;
    if (t >= off) v = totals[t - off];
    __syncthreads();
    if (t >= off) totals[t] += v;
    __syncthreads();
  }
  int base = (t == 0) ? 0 : totals[t - 1];
  for (int i = beg; i < end; ++i) {
    rowptr[i] = base;
    cnt[i] = base;
    dinv[i] = rsqrtf((float)deg[i]);  // deg >= 1 (self-loop)
    base += deg[i];
  }
  if (t == 0) rowptr[NN] = E2;
}

__global__ void k_fill(const int* __restrict__ ei, int* __restrict__ cnt,
                       int* __restrict__ csr) {
  int e = blockIdx.x * blockDim.x + threadIdx.x;
  if (e >= E2) return;
  int d = edge_dst(ei, e);
  int s = edge_src(ei, e);
  int pos = atomicAdd(&cnt[d], 1);
  csr[pos] = s;
}

// ---------------- fused fp32 GEMM ----------------
// C = outAct( inAct(BN(A))[M,K] @ B[K,NC] + biasOut )
// BN (optional): per-channel scale/shift from 32-copy stats (sum, sumsq).
// Outputs: optional fp32 Cf, optional bf16 Cbf (scaled by rowScale[row] if given).
__global__ __launch_bounds__(256) void k_gemm(
    const float* __restrict__ A, const float* __restrict__ B,
    const float* __restrict__ biasOut,
    const float* __restrict__ bnst, const float* __restrict__ bng,
    const float* __restrict__ bnb, int inAct, int outAct,
    float* __restrict__ Cf, unsigned short* __restrict__ Cbf,
    const float* __restrict__ rowScale,
    int M, int K, int NC) {
  __shared__ float As[64][68];
  __shared__ float Bs[64][68];
  __shared__ float sSc[256], sSh[256];
  int tx = threadIdx.x & 15;
  int ty = threadIdx.x >> 4;
  if (bnst) {
    int c = threadIdx.x;
    if (c < K) {
      float sum = 0.f, sq = 0.f;
      for (int cp = 0; cp < 32; ++cp) {
        sum += bnst[cp * 2 * K + c];
        sq += bnst[cp * 2 * K + K + c];
      }
      const float invN = 1.0f / (float)NN;
      float mu = sum * invN;
      float var = sq * invN - mu * mu;
      float rs = rsqrtf(var + 1e-5f);
      float sc = rs * bng[c];
      sSc[c] = sc;
      sSh[c] = fmaf(-mu, sc, bnb[c]);
    }
    __syncthreads();
  }
  int rowBase = blockIdx.x * 64;
  int colBase = blockIdx.y * 64;
  float acc[4][4];
#pragma unroll
  for (int i = 0; i < 4; ++i)
#pragma unroll
    for (int j = 0; j < 4; ++j) acc[i][j] = 0.f;

  for (int kc = 0; kc < K; kc += 64) {
#pragma unroll
    for (int l = 0; l < 4; ++l) {
      int r = ty + l * 16;
      int gr = rowBase + r;
      float4 av = make_float4(0.f, 0.f, 0.f, 0.f);
      if (gr < M) av = *(const float4*)&A[(size_t)gr * K + kc + tx * 4];
      if (bnst) {
        int c = kc + tx * 4;
        av.x = fmaf(av.x, sSc[c + 0], sSh[c + 0]);
        av.y = fmaf(av.y, sSc[c + 1], sSh[c + 1]);
        av.z = fmaf(av.z, sSc[c + 2], sSh[c + 2]);
        av.w = fmaf(av.w, sSc[c + 3], sSh[c + 3]);
      }
      if (inAct == 1) {
        av.x = fmaxf(av.x, 0.f); av.y = fmaxf(av.y, 0.f);
        av.z = fmaxf(av.z, 0.f); av.w = fmaxf(av.w, 0.f);
      } else if (inAct == 2) {
        av.x = av.x > 0.f ? av.x : expm1f(av.x);
        av.y = av.y > 0.f ? av.y : expm1f(av.y);
        av.z = av.z > 0.f ? av.z : expm1f(av.z);
        av.w = av.w > 0.f ? av.w : expm1f(av.w);
      }
      As[tx * 4 + 0][r] = av.x;
      As[tx * 4 + 1][r] = av.y;
      As[tx * 4 + 2][r] = av.z;
      As[tx * 4 + 3][r] = av.w;
      float4 bv = *(const float4*)&B[(size_t)(kc + r) * NC + colBase + tx * 4];
      *(float4*)&Bs[r][tx * 4] = bv;
    }
    __syncthreads();
#pragma unroll
    for (int kk = 0; kk < 64; ++kk) {
      float4 av = *(const float4*)&As[kk][ty * 4];
      float4 bv = *(const float4*)&Bs[kk][tx * 4];
      float a_[4] = {av.x, av.y, av.z, av.w};
      float b_[4] = {bv.x, bv.y, bv.z, bv.w};
#pragma unroll
      for (int i = 0; i < 4; ++i)
#pragma unroll
        for (int j = 0; j < 4; ++j) acc[i][j] = fmaf(a_[i], b_[j], acc[i][j]);
    }
    __syncthreads();
  }

  float4 bb = make_float4(0.f, 0.f, 0.f, 0.f);
  if (biasOut) bb = *(const float4*)&biasOut[colBase + tx * 4];
#pragma unroll
  for (int i = 0; i < 4; ++i) {
    int gr = rowBase + ty * 4 + i;
    if (gr < M) {
      float4 v;
      v.x = acc[i][0] + bb.x;
      v.y = acc[i][1] + bb.y;
      v.z = acc[i][2] + bb.z;
      v.w = acc[i][3] + bb.w;
      if (outAct == 1) {
        v.x = fmaxf(v.x, 0.f); v.y = fmaxf(v.y, 0.f);
        v.z = fmaxf(v.z, 0.f); v.w = fmaxf(v.w, 0.f);
      }
      if (Cf) *(float4*)&Cf[(size_t)gr * NC + colBase + tx * 4] = v;
      if (Cbf) {
        float rs_ = rowScale ? rowScale[gr] : 1.f;
        ushort4 u;
        u.x = f2bf(v.x * rs_); u.y = f2bf(v.y * rs_);
        u.z = f2bf(v.z * rs_); u.w = f2bf(v.w * rs_);
        *(ushort4*)&Cbf[(size_t)gr * NC + colBase + tx * 4] = u;
      }
    }
  }
}

// ---------------- attention dot products (from bf16) ----------------
__global__ void k_dots1(const unsigned short* __restrict__ h1b,
                        const float* __restrict__ a_src, const float* __restrict__ a_dst,
                        float* __restrict__ es, float* __restrict__ ed) {
  int wave = threadIdx.x >> 6;
  int lane = threadIdx.x & 63;
  int i = blockIdx.x * 4 + wave;
  if (i >= NN) return;
  ushort4 hv4 = *(const ushort4*)&h1b[(size_t)i * 256 + lane * 4];
  float4 hv = make_float4(bf2f(hv4.x), bf2f(hv4.y), bf2f(hv4.z), bf2f(hv4.w));
  float4 as = *(const float4*)&a_src[lane * 4];
  float4 ad = *(const float4*)&a_dst[lane * 4];
  float ps = hv.x * as.x + hv.y * as.y + hv.z * as.z + hv.w * as.w;
  float pd = hv.x * ad.x + hv.y * ad.y + hv.z * ad.z + hv.w * ad.w;
#pragma unroll
  for (int off = 8; off > 0; off >>= 1) {
    ps += __shfl_xor(ps, off);
    pd += __shfl_xor(pd, off);
  }
  if ((lane & 15) == 0) {
    int h = lane >> 4;
    es[i * 4 + h] = ps;
    ed[i * 4 + h] = pd;
  }
}

__global__ void k_dots2(const unsigned short* __restrict__ h2b,
                        const float* __restrict__ a_src, const float* __restrict__ a_dst,
                        float* __restrict__ es, float* __restrict__ ed) {
  int wave = threadIdx.x >> 6;
  int lane = threadIdx.x & 63;
  int i = blockIdx.x * 4 + wave;
  if (i >= NN) return;
  float h = bf2f(h2b[(size_t)i * 64 + lane]);
  float ps = h * a_src[lane];
  float pd = h * a_dst[lane];
#pragma unroll
  for (int off = 32; off > 0; off >>= 1) {
    ps += __shfl_xor(ps, off);
    pd += __shfl_xor(pd, off);
  }
  if (lane == 0) { es[i] = ps; ed[i] = pd; }
}

// ---------------- softmax stats + edge weights, GAT1 (4 heads) ----------------
// 16 lanes per node. Writes w1[h*E2 + k] = exp(e - m_h)/sum_h.
__global__ __launch_bounds__(256) void k_soft1(const float* __restrict__ es,
                                               const float* __restrict__ ed,
                                               const int* __restrict__ rowptr,
                                               const int* __restrict__ csr,
                                               float* __restrict__ w1) {
  int node = blockIdx.x * 16 + (threadIdx.x >> 4);
  int sub = threadIdx.x & 15;
  int start = rowptr[node], end = rowptr[node + 1];
  float4 edv = *(const float4*)&ed[node * 4];
  float m0 = -1e30f, m1 = -1e30f, m2 = -1e30f, m3 = -1e30f;
  float s0 = 0.f, s1 = 0.f, s2 = 0.f, s3 = 0.f;
  for (int k = start + sub; k < end; k += 16) {
    int s = csr[k];
    float4 esv = *(const float4*)&es[s * 4];
    float e0 = leaky(esv.x + edv.x);
    float e1 = leaky(esv.y + edv.y);
    float e2 = leaky(esv.z + edv.z);
    float e3 = leaky(esv.w + edv.w);
    float mn;
    mn = fmaxf(m0, e0); s0 = s0 * __expf(m0 - mn) + __expf(e0 - mn); m0 = mn;
    mn = fmaxf(m1, e1); s1 = s1 * __expf(m1 - mn) + __expf(e1 - mn); m1 = mn;
    mn = fmaxf(m2, e2); s2 = s2 * __expf(m2 - mn) + __expf(e2 - mn); m2 = mn;
    mn = fmaxf(m3, e3); s3 = s3 * __expf(m3 - mn) + __expf(e3 - mn); m3 = mn;
  }
#pragma unroll
  for (int off = 1; off < 16; off <<= 1) {
    float mo, so, mn;
    mo = __shfl_xor(m0, off); so = __shfl_xor(s0, off);
    mn = fmaxf(m0, mo); s0 = s0 * __expf(m0 - mn) + so * __expf(mo - mn); m0 = mn;
    mo = __shfl_xor(m1, off); so = __shfl_xor(s1, off);
    mn = fmaxf(m1, mo); s1 = s1 * __expf(m1 - mn) + so * __expf(mo - mn); m1 = mn;
    mo = __shfl_xor(m2, off); so = __shfl_xor(s2, off);
    mn = fmaxf(m2, mo); s2 = s2 * __expf(m2 - mn) + so * __expf(mo - mn); m2 = mn;
    mo = __shfl_xor(m3, off); so = __shfl_xor(s3, off);
    mn = fmaxf(m3, mo); s3 = s3 * __expf(m3 - mn) + so * __expf(mo - mn); m3 = mn;
  }
  float i0 = 1.f / (s0 + 1e-16f);
  float i1 = 1.f / (s1 + 1e-16f);
  float i2 = 1.f / (s2 + 1e-16f);
  float i3 = 1.f / (s3 + 1e-16f);
  for (int k = start + sub; k < end; k += 16) {
    int s = csr[k];
    float4 esv = *(const float4*)&es[s * 4];
    w1[k]          = __expf(leaky(esv.x + edv.x) - m0) * i0;
    w1[E2 + k]     = __expf(leaky(esv.y + edv.y) - m1) * i1;
    w1[2 * E2 + k] = __expf(leaky(esv.z + edv.z) - m2) * i2;
    w1[3 * E2 + k] = __expf(leaky(esv.w + edv.w) - m3) * i3;
  }
}

// ---------------- softmax stats + edge weights, GAT2 (1 head) ----------------
__global__ __launch_bounds__(256) void k_soft2(const float* __restrict__ es,
                                               const float* __restrict__ ed,
                                               const int* __restrict__ rowptr,
                                               const int* __restrict__ csr,
                                               float* __restrict__ w2) {
  int node = blockIdx.x * 16 + (threadIdx.x >> 4);
  int sub = threadIdx.x & 15;
  int start = rowptr[node], end = rowptr[node + 1];
  float edi = ed[node];
  float m = -1e30f, ss = 0.f;
  for (int k = start + sub; k < end; k += 16) {
    float e = leaky(es[csr[k]] + edi);
    float mn = fmaxf(m, e);
    ss = ss * __expf(m - mn) + __expf(e - mn);
    m = mn;
  }
#pragma unroll
  for (int off = 1; off < 16; off <<= 1) {
    float mo = __shfl_xor(m, off);
    float so = __shfl_xor(ss, off);
    float mn = fmaxf(m, mo);
    ss = ss * __expf(m - mn) + so * __expf(mo - mn);
    m = mn;
  }
  float inv = 1.f / (ss + 1e-16f);
  for (int k = start + sub; k < end; k += 16) {
    float e = leaky(es[csr[k]] + edi);
    w2[k] = __expf(e - m) * inv;
  }
}

// ---------------- GAT1 gather (lean) + BN1 stats ----------------
__global__ __launch_bounds__(256) void k_gat1(const unsigned short* __restrict__ h1b,
                                              const float* __restrict__ w1,
                                              const int* __restrict__ rowptr,
                                              const int* __restrict__ csr,
                                              const float* __restrict__ b1,
                                              float* __restrict__ out,
                                              float* __restrict__ st) {
  __shared__ float2 sm[4][256];
  int wave = threadIdx.x >> 6;
  int lane = threadIdx.x & 63;
  int i = blockIdx.x * 4 + wave;
  int start = rowptr[i], end = rowptr[i + 1];
  const float* wh = w1 + (size_t)(lane >> 4) * E2;
  float4 acc = make_float4(0.f, 0.f, 0.f, 0.f);
  int k = start;
  for (; k + 4 <= end; k += 4) {
    int sA = csr[k], sB = csr[k + 1], sC = csr[k + 2], sD = csr[k + 3];
    float wA = wh[k], wB = wh[k + 1], wC = wh[k + 2], wD = wh[k + 3];
    ushort4 a0 = *(const ushort4*)&h1b[(size_t)sA * 256 + lane * 4];
    ushort4 a1 = *(const ushort4*)&h1b[(size_t)sB * 256 + lane * 4];
    ushort4 a2 = *(const ushort4*)&h1b[(size_t)sC * 256 + lane * 4];
    ushort4 a3 = *(const ushort4*)&h1b[(size_t)sD * 256 + lane * 4];
    acc.x = fmaf(bf2f(a0.x), wA, fmaf(bf2f(a1.x), wB, fmaf(bf2f(a2.x), wC, fmaf(bf2f(a3.x), wD, acc.x))));
    acc.y = fmaf(bf2f(a0.y), wA, fmaf(bf2f(a1.y), wB, fmaf(bf2f(a2.y), wC, fmaf(bf2f(a3.y), wD, acc.y))));
    acc.z = fmaf(bf2f(a0.z), wA, fmaf(bf2f(a1.z), wB, fmaf(bf2f(a2.z), wC, fmaf(bf2f(a3.z), wD, acc.z))));
    acc.w = fmaf(bf2f(a0.w), wA, fmaf(bf2f(a1.w), wB, fmaf(bf2f(a2.w), wC, fmaf(bf2f(a3.w), wD, acc.w))));
  }
  for (; k < end; ++k) {
    int s = csr[k];
    float wv = wh[k];
    ushort4 a0 = *(const ushort4*)&h1b[(size_t)s * 256 + lane * 4];
    acc.x = fmaf(bf2f(a0.x), wv, acc.x);
    acc.y = fmaf(bf2f(a0.y), wv, acc.y);
    acc.z = fmaf(bf2f(a0.z), wv, acc.z);
    acc.w = fmaf(bf2f(a0.w), wv, acc.w);
  }
  float4 bv = *(const float4*)&b1[lane * 4];
  float4 o;
  o.x = acc.x + bv.x; o.y = acc.y + bv.y; o.z = acc.z + bv.z; o.w = acc.w + bv.w;
  *(float4*)&out[(size_t)i * 256 + lane * 4] = o;
  sm[wave][lane * 4 + 0] = make_float2(o.x, o.x * o.x);
  sm[wave][lane * 4 + 1] = make_float2(o.y, o.y * o.y);
  sm[wave][lane * 4 + 2] = make_float2(o.z, o.z * o.z);
  sm[wave][lane * 4 + 3] = make_float2(o.w, o.w * o.w);
  __syncthreads();
  int c = threadIdx.x;
  float s_ = 0.f, q_ = 0.f;
#pragma unroll
  for (int wv = 0; wv < 4; ++wv) { float2 v = sm[wv][c]; s_ += v.x; q_ += v.y; }
  float* dst = st + (size_t)(blockIdx.x & 31) * 512;
  atomicAdd(&dst[c], s_);
  atomicAdd(&dst[256 + c], q_);
}

// ---------------- GCN gather (hgb pre-scaled by dinv[src]) + BN2 stats ----------------
__global__ __launch_bounds__(256) void k_gcn(const unsigned short* __restrict__ hgb,
                                             const float* __restrict__ dinv,
                                             const int* __restrict__ rowptr,
                                             const int* __restrict__ csr,
                                             const float* __restrict__ bg,
                                             float* __restrict__ out,
                                             float* __restrict__ st) {
  __shared__ float2 sm[4][64];
  int wave = threadIdx.x >> 6;
  int lane = threadIdx.x & 63;
  int i = blockIdx.x * 4 + wave;
  int start = rowptr[i], end = rowptr[i + 1];
  float acc = 0.f;
  int k = start;
  for (; k + 4 <= end; k += 4) {
    int sA = csr[k], sB = csr[k + 1], sC = csr[k + 2], sD = csr[k + 3];
    acc += bf2f(hgb[(size_t)sA * 64 + lane]) + bf2f(hgb[(size_t)sB * 64 + lane]) +
           bf2f(hgb[(size_t)sC * 64 + lane]) + bf2f(hgb[(size_t)sD * 64 + lane]);
  }
  for (; k < end; ++k) acc += bf2f(hgb[(size_t)csr[k] * 64 + lane]);
  float o = fmaf(acc, dinv[i], bg[lane]);
  out[(size_t)i * 64 + lane] = o;
  sm[wave][lane] = make_float2(o, o * o);
  __syncthreads();
  if (threadIdx.x < 64) {
    int c = threadIdx.x;
    float s_ = 0.f, q_ = 0.f;
#pragma unroll
    for (int wv = 0; wv < 4; ++wv) { float2 v = sm[wv][c]; s_ += v.x; q_ += v.y; }
    float* dst = st + (size_t)(blockIdx.x & 31) * 128;
    atomicAdd(&dst[c], s_);
    atomicAdd(&dst[64 + c], q_);
  }
}

// ---------------- GAT2 gather (lean) + BN3 stats ----------------
__global__ __launch_bounds__(256) void k_gat2(const unsigned short* __restrict__ h2b,
                                              const float* __restrict__ w2,
                                              const int* __restrict__ rowptr,
                                              const int* __restrict__ csr,
                                              const float* __restrict__ b2,
                                              float* __restrict__ out,
                                              float* __restrict__ st) {
  __shared__ float2 sm[4][64];
  int wave = threadIdx.x >> 6;
  int lane = threadIdx.x & 63;
  int i = blockIdx.x * 4 + wave;
  int start = rowptr[i], end = rowptr[i + 1];
  float acc = 0.f;
  int k = start;
  for (; k + 4 <= end; k += 4) {
    int sA = csr[k], sB = csr[k + 1], sC = csr[k + 2], sD = csr[k + 3];
    float wA = w2[k], wB = w2[k + 1], wC = w2[k + 2], wD = w2[k + 3];
    acc = fmaf(bf2f(h2b[(size_t)sA * 64 + lane]), wA,
          fmaf(bf2f(h2b[(size_t)sB * 64 + lane]), wB,
          fmaf(bf2f(h2b[(size_t)sC * 64 + lane]), wC,
          fmaf(bf2f(h2b[(size_t)sD * 64 + lane]), wD, acc))));
  }
  for (; k < end; ++k)
    acc = fmaf(bf2f(h2b[(size_t)csr[k] * 64 + lane]), w2[k], acc);
  float o = acc + b2[lane];
  out[(size_t)i * 64 + lane] = o;
  sm[wave][lane] = make_float2(o, o * o);
  __syncthreads();
  if (threadIdx.x < 64) {
    int c = threadIdx.x;
    float s_ = 0.f, q_ = 0.f;
#pragma unroll
    for (int wv = 0; wv < 4; ++wv) { float2 v = sm[wv][c]; s_ += v.x; q_ += v.y; }
    float* dst = st + (size_t)(blockIdx.x & 31) * 128;
    atomicAdd(&dst[c], s_);
    atomicAdd(&dst[64 + c], q_);
  }
}

// ---------------- host ----------------
extern "C" void kernel_launch(void* const* d_in, const int* in_sizes, int n_in,
                              void* d_out, int out_size, void* d_ws, size_t ws_size,
                              hipStream_t stream) {
  const float* x        = (const float*)d_in[0];
  const int*   ei       = (const int*)d_in[1];
  const float* W1       = (const float*)d_in[3];
  const float* att_src1 = (const float*)d_in[4];
  const float* att_dst1 = (const float*)d_in[5];
  const float* b1       = (const float*)d_in[6];
  const float* g1       = (const float*)d_in[7];
  const float* beta1    = (const float*)d_in[8];
  const float* Wg       = (const float*)d_in[9];
  const float* bg       = (const float*)d_in[10];
  const float* g2       = (const float*)d_in[11];
  const float* beta2    = (const float*)d_in[12];
  const float* W2       = (const float*)d_in[13];
  const float* att_src2 = (const float*)d_in[14];
  const float* att_dst2 = (const float*)d_in[15];
  const float* b2       = (const float*)d_in[16];
  const float* g3       = (const float*)d_in[17];
  const float* beta3    = (const float*)d_in[18];
  const float* Wp1      = (const float*)d_in[19];
  const float* bp1      = (const float*)d_in[20];
  const float* Wp2      = (const float*)d_in[21];
  const float* bp2      = (const float*)d_in[22];
  float* out = (float*)d_out;

  char* w = (char*)d_ws;
  // liveness-based aliasing: bufD reuses bufB; hidden reuses h1b; w2 reuses w1.
  float*          bufB   = (float*)(w + 0);                    // gat1 out raw [N,256]
  float*          bufD   = (float*)(w + 0);                    // gat2 out raw [N,64]
  unsigned short* h1b    = (unsigned short*)(w + 51200000);    // [N,256] bf16
  float*          hidden = (float*)(w + 51200000);             // proj hidden [N,128]
  float*          w1     = (float*)(w + 76800000);             // [4,E2] f32
  float*          w2     = (float*)(w + 76800000);             // [E2] f32
  unsigned short* hgb    = (unsigned short*)(w + 90400000);    // [N,64] bf16 (dinv-scaled)
  float*          bufC   = (float*)(w + 96800000);             // gcn out raw [N,64]
  unsigned short* h2b    = (unsigned short*)(w + 109600000);   // [N,64] bf16
  float*          es1    = (float*)(w + 116000000);
  float*          ed1    = (float*)(w + 116800000);
  float*          es2    = (float*)(w + 117600000);
  float*          ed2    = (float*)(w + 117800000);
  float*          dinv   = (float*)(w + 118000000);
  int*            deg    = (int*)(w + 118200000);
  int*            rowptr = (int*)(w + 118400000);
  int*            cnt    = (int*)(w + 118600064);
  int*            csr    = (int*)(w + 118800064);
  float*          st1    = (float*)(w + 122200064);            // 32*512 f32
  float*          st2    = st1 + 32 * 512;                     // 32*128 f32
  float*          st3    = st2 + 32 * 128;                     // 32*128 f32

  hipMemsetAsync(deg, 0, NN * sizeof(int), stream);
  hipMemsetAsync(st1, 0, (32 * 512 + 32 * 128 + 32 * 128) * sizeof(float), stream);

  const int EB = (E2 + 255) / 256;
  const int WB = NN / 4;       // 12500 (exact)
  const int SB = NN / 16;      // 3125 (exact)
  const int GX = (NN + 63) / 64;  // 782

  // CSR build
  k_deg<<<EB, 256, 0, stream>>>(ei, deg);
  k_scan<<<1, 1024, 0, stream>>>(deg, rowptr, cnt, dinv);
  k_fill<<<EB, 256, 0, stream>>>(ei, cnt, csr);

  // GAT1
  k_gemm<<<dim3(GX, 4), 256, 0, stream>>>(x, W1, nullptr, nullptr, nullptr, nullptr,
                                          0, 0, nullptr, h1b, nullptr, NN, 128, 256);
  k_dots1<<<WB, 256, 0, stream>>>(h1b, att_src1, att_dst1, es1, ed1);
  k_soft1<<<SB, 256, 0, stream>>>(es1, ed1, rowptr, csr, w1);
  k_gat1<<<WB, 256, 0, stream>>>(h1b, w1, rowptr, csr, b1, bufB, st1);

  // GCN (BN1+ELU fused into A staging; hgb pre-scaled by dinv[row])
  k_gemm<<<dim3(GX, 1), 256, 0, stream>>>(bufB, Wg, nullptr, st1, g1, beta1,
                                          2, 0, nullptr, hgb, dinv, NN, 256, 64);
  k_gcn<<<WB, 256, 0, stream>>>(hgb, dinv, rowptr, csr, bg, bufC, st2);

  // GAT2 (BN2+ReLU fused)
  k_gemm<<<dim3(GX, 1), 256, 0, stream>>>(bufC, W2, nullptr, st2, g2, beta2,
                                          1, 0, nullptr, h2b, nullptr, NN, 64, 64);
  k_dots2<<<WB, 256, 0, stream>>>(h2b, att_src2, att_dst2, es2, ed2);
  k_soft2<<<SB, 256, 0, stream>>>(es2, ed2, rowptr, csr, w2);
  k_gat2<<<WB, 256, 0, stream>>>(h2b, w2, rowptr, csr, b2, bufD, st3);

  // projector (BN3+ELU fused into p1 staging)
  k_gemm<<<dim3(GX, 2), 256, 0, stream>>>(bufD, Wp1, bp1, st3, g3, beta3,
                                          2, 1, hidden, nullptr, nullptr, NN, 64, 128);
  k_gemm<<<dim3(GX, 1), 256, 0, stream>>>(hidden, Wp2, bp2, nullptr, nullptr, nullptr,
                                          0, 0, out, nullptr, nullptr, NN, 128, 64);
}

// Round 4
// 542.180 us; speedup vs baseline: 1.8374x; 1.2375x over previous
//
#include <hip/hip_runtime.h>
#include <math.h>

#define NN 50000
#define EE 800000
#define E2 850000   // EE + NN self loops
#define SCB 196     // ceil(NN/256) scan blocks

// ---------------- bf16 helpers ----------------
__device__ __forceinline__ float bf2f(unsigned short u) {
  return __uint_as_float(((unsigned int)u) << 16);
}
__device__ __forceinline__ unsigned short f2bf(float f) {
  unsigned int x = __float_as_uint(f);
  unsigned int r = (x + 0x7fffu + ((x >> 16) & 1u)) >> 16;  // RNE
  return (unsigned short)r;
}

__device__ __forceinline__ float leaky(float x) { return x > 0.f ? x : 0.2f * x; }

// ---------------- edge helpers ----------------
__device__ __forceinline__ int edge_src(const int* ei, int e) {
  return (e < EE) ? ei[e] : (e - EE);
}
__device__ __forceinline__ int edge_dst(const int* ei, int e) {
  return (e < EE) ? ei[EE + e] : (e - EE);
}

// ---------------- CSR build ----------------
__global__ void k_deg(const int* __restrict__ ei, int* __restrict__ deg) {
  int e = blockIdx.x * blockDim.x + threadIdx.x;
  if (e < E2) atomicAdd(&deg[edge_dst(ei, e)], 1);
}

// phase 1: per-block sums of 256-element chunks
__global__ __launch_bounds__(256) void k_scan1(const int* __restrict__ deg,
                                               int* __restrict__ partial) {
  __shared__ int sd[256];
  int i = blockIdx.x * 256 + threadIdx.x;
  sd[threadIdx.x] = (i < NN) ? deg[i] : 0;
  __syncthreads();
  for (int off = 128; off > 0; off >>= 1) {
    if (threadIdx.x < off) sd[threadIdx.x] += sd[threadIdx.x + off];
    __syncthreads();
  }
  if (threadIdx.x == 0) partial[blockIdx.x] = sd[0];
}

// phase 2: exclusive scan of SCB partials (single tiny block)
__global__ __launch_bounds__(256) void k_scan2(int* __restrict__ partial) {
  __shared__ int sd[256];
  int t = threadIdx.x;
  int orig = (t < SCB) ? partial[t] : 0;
  sd[t] = orig;
  __syncthreads();
  for (int off = 1; off < 256; off <<= 1) {
    int v = (t >= off) ? sd[t - off] : 0;
    __syncthreads();
    sd[t] += v;
    __syncthreads();
  }
  if (t < SCB) partial[t] = sd[t] - orig;  // exclusive
}

// phase 3: local scan + offset -> rowptr/cnt/dinv
__global__ __launch_bounds__(256) void k_scan3(const int* __restrict__ deg,
                                               const int* __restrict__ partial,
                                               int* __restrict__ rowptr,
                                               int* __restrict__ cnt,
                                               float* __restrict__ dinv) {
  __shared__ int sd[256];
  int t = threadIdx.x;
  int i = blockIdx.x * 256 + t;
  int v = (i < NN) ? deg[i] : 0;
  sd[t] = v;
  __syncthreads();
  for (int off = 1; off < 256; off <<= 1) {
    int u = (t >= off) ? sd[t - off] : 0;
    __syncthreads();
    sd[t] += u;
    __syncthreads();
  }
  if (i < NN) {
    int excl = partial[blockIdx.x] + sd[t] - v;
    rowptr[i] = excl;
    cnt[i] = excl;
    dinv[i] = rsqrtf((float)v);  // deg >= 1 (self-loop)
  }
  if (i == 0) rowptr[NN] = E2;
}

__global__ void k_fill(const int* __restrict__ ei, int* __restrict__ cnt,
                       int* __restrict__ csr) {
  int e = blockIdx.x * blockDim.x + threadIdx.x;
  if (e >= E2) return;
  int d = edge_dst(ei, e);
  int s = edge_src(ei, e);
  int pos = atomicAdd(&cnt[d], 1);
  csr[pos] = s;
}

// ---------------- fused fp32 GEMM ----------------
// C = outAct( inAct(BN(Ain))[M,K] @ B[K,NC] + biasOut )
// Ain = fp32 A or bf16 Abf. BN optional (32-copy stats). Outputs: fp32 Cf and/or
// bf16 Cbf (scaled by rowScale[row] if given).
__global__ __launch_bounds__(256) void k_gemm(
    const float* __restrict__ A, const unsigned short* __restrict__ Abf,
    const float* __restrict__ B, const float* __restrict__ biasOut,
    const float* __restrict__ bnst, const float* __restrict__ bng,
    const float* __restrict__ bnb, int inAct, int outAct,
    float* __restrict__ Cf, unsigned short* __restrict__ Cbf,
    const float* __restrict__ rowScale,
    int M, int K, int NC) {
  __shared__ float As[64][68];
  __shared__ float Bs[64][68];
  __shared__ float sSc[256], sSh[256];
  int tx = threadIdx.x & 15;
  int ty = threadIdx.x >> 4;
  if (bnst) {
    int c = threadIdx.x;
    if (c < K) {
      float sum = 0.f, sq = 0.f;
      for (int cp = 0; cp < 32; ++cp) {
        sum += bnst[cp * 2 * K + c];
        sq += bnst[cp * 2 * K + K + c];
      }
      const float invN = 1.0f / (float)NN;
      float mu = sum * invN;
      float var = sq * invN - mu * mu;
      float rs = rsqrtf(var + 1e-5f);
      float sc = rs * bng[c];
      sSc[c] = sc;
      sSh[c] = fmaf(-mu, sc, bnb[c]);
    }
    __syncthreads();
  }
  int rowBase = blockIdx.x * 64;
  int colBase = blockIdx.y * 64;
  float acc[4][4];
#pragma unroll
  for (int i = 0; i < 4; ++i)
#pragma unroll
    for (int j = 0; j < 4; ++j) acc[i][j] = 0.f;

  for (int kc = 0; kc < K; kc += 64) {
#pragma unroll
    for (int l = 0; l < 4; ++l) {
      int r = ty + l * 16;
      int gr = rowBase + r;
      float4 av = make_float4(0.f, 0.f, 0.f, 0.f);
      if (gr < M) {
        if (Abf) {
          ushort4 u4 = *(const ushort4*)&Abf[(size_t)gr * K + kc + tx * 4];
          av = make_float4(bf2f(u4.x), bf2f(u4.y), bf2f(u4.z), bf2f(u4.w));
        } else {
          av = *(const float4*)&A[(size_t)gr * K + kc + tx * 4];
        }
      }
      if (bnst) {
        int c = kc + tx * 4;
        av.x = fmaf(av.x, sSc[c + 0], sSh[c + 0]);
        av.y = fmaf(av.y, sSc[c + 1], sSh[c + 1]);
        av.z = fmaf(av.z, sSc[c + 2], sSh[c + 2]);
        av.w = fmaf(av.w, sSc[c + 3], sSh[c + 3]);
      }
      if (inAct == 1) {
        av.x = fmaxf(av.x, 0.f); av.y = fmaxf(av.y, 0.f);
        av.z = fmaxf(av.z, 0.f); av.w = fmaxf(av.w, 0.f);
      } else if (inAct == 2) {
        av.x = av.x > 0.f ? av.x : expm1f(av.x);
        av.y = av.y > 0.f ? av.y : expm1f(av.y);
        av.z = av.z > 0.f ? av.z : expm1f(av.z);
        av.w = av.w > 0.f ? av.w : expm1f(av.w);
      }
      As[tx * 4 + 0][r] = av.x;
      As[tx * 4 + 1][r] = av.y;
      As[tx * 4 + 2][r] = av.z;
      As[tx * 4 + 3][r] = av.w;
      float4 bv = *(const float4*)&B[(size_t)(kc + r) * NC + colBase + tx * 4];
      *(float4*)&Bs[r][tx * 4] = bv;
    }
    __syncthreads();
#pragma unroll
    for (int kk = 0; kk < 64; ++kk) {
      float4 av = *(const float4*)&As[kk][ty * 4];
      float4 bv = *(const float4*)&Bs[kk][tx * 4];
      float a_[4] = {av.x, av.y, av.z, av.w};
      float b_[4] = {bv.x, bv.y, bv.z, bv.w};
#pragma unroll
      for (int i = 0; i < 4; ++i)
#pragma unroll
        for (int j = 0; j < 4; ++j) acc[i][j] = fmaf(a_[i], b_[j], acc[i][j]);
    }
    __syncthreads();
  }

  float4 bb = make_float4(0.f, 0.f, 0.f, 0.f);
  if (biasOut) bb = *(const float4*)&biasOut[colBase + tx * 4];
#pragma unroll
  for (int i = 0; i < 4; ++i) {
    int gr = rowBase + ty * 4 + i;
    if (gr < M) {
      float4 v;
      v.x = acc[i][0] + bb.x;
      v.y = acc[i][1] + bb.y;
      v.z = acc[i][2] + bb.z;
      v.w = acc[i][3] + bb.w;
      if (outAct == 1) {
        v.x = fmaxf(v.x, 0.f); v.y = fmaxf(v.y, 0.f);
        v.z = fmaxf(v.z, 0.f); v.w = fmaxf(v.w, 0.f);
      }
      if (Cf) *(float4*)&Cf[(size_t)gr * NC + colBase + tx * 4] = v;
      if (Cbf) {
        float rs_ = rowScale ? rowScale[gr] : 1.f;
        ushort4 u;
        u.x = f2bf(v.x * rs_); u.y = f2bf(v.y * rs_);
        u.z = f2bf(v.z * rs_); u.w = f2bf(v.w * rs_);
        *(ushort4*)&Cbf[(size_t)gr * NC + colBase + tx * 4] = u;
      }
    }
  }
}

// ---------------- attention dot products (from bf16) ----------------
__global__ void k_dots1(const unsigned short* __restrict__ h1b,
                        const float* __restrict__ a_src, const float* __restrict__ a_dst,
                        float* __restrict__ es, float* __restrict__ ed) {
  int wave = threadIdx.x >> 6;
  int lane = threadIdx.x & 63;
  int i = blockIdx.x * 4 + wave;
  if (i >= NN) return;
  ushort4 hv4 = *(const ushort4*)&h1b[(size_t)i * 256 + lane * 4];
  float4 hv = make_float4(bf2f(hv4.x), bf2f(hv4.y), bf2f(hv4.z), bf2f(hv4.w));
  float4 as = *(const float4*)&a_src[lane * 4];
  float4 ad = *(const float4*)&a_dst[lane * 4];
  float ps = hv.x * as.x + hv.y * as.y + hv.z * as.z + hv.w * as.w;
  float pd = hv.x * ad.x + hv.y * ad.y + hv.z * ad.z + hv.w * ad.w;
#pragma unroll
  for (int off = 8; off > 0; off >>= 1) {
    ps += __shfl_xor(ps, off);
    pd += __shfl_xor(pd, off);
  }
  if ((lane & 15) == 0) {
    int h = lane >> 4;
    es[i * 4 + h] = ps;
    ed[i * 4 + h] = pd;
  }
}

__global__ void k_dots2(const unsigned short* __restrict__ h2b,
                        const float* __restrict__ a_src, const float* __restrict__ a_dst,
                        float* __restrict__ es, float* __restrict__ ed) {
  int wave = threadIdx.x >> 6;
  int lane = threadIdx.x & 63;
  int i = blockIdx.x * 4 + wave;
  if (i >= NN) return;
  float h = bf2f(h2b[(size_t)i * 64 + lane]);
  float ps = h * a_src[lane];
  float pd = h * a_dst[lane];
#pragma unroll
  for (int off = 32; off > 0; off >>= 1) {
    ps += __shfl_xor(ps, off);
    pd += __shfl_xor(pd, off);
  }
  if (lane == 0) { es[i] = ps; ed[i] = pd; }
}

// ---------------- softmax stats + edge weights, GAT1 (4 heads) ----------------
__global__ __launch_bounds__(256) void k_soft1(const float* __restrict__ es,
                                               const float* __restrict__ ed,
                                               const int* __restrict__ rowptr,
                                               const int* __restrict__ csr,
                                               float* __restrict__ w1) {
  int node = blockIdx.x * 16 + (threadIdx.x >> 4);
  int sub = threadIdx.x & 15;
  int start = rowptr[node], end = rowptr[node + 1];
  float4 edv = *(const float4*)&ed[node * 4];
  float m0 = -1e30f, m1 = -1e30f, m2 = -1e30f, m3 = -1e30f;
  float s0 = 0.f, s1 = 0.f, s2 = 0.f, s3 = 0.f;
  for (int k = start + sub; k < end; k += 16) {
    int s = csr[k];
    float4 esv = *(const float4*)&es[s * 4];
    float e0 = leaky(esv.x + edv.x);
    float e1 = leaky(esv.y + edv.y);
    float e2 = leaky(esv.z + edv.z);
    float e3 = leaky(esv.w + edv.w);
    float mn;
    mn = fmaxf(m0, e0); s0 = s0 * __expf(m0 - mn) + __expf(e0 - mn); m0 = mn;
    mn = fmaxf(m1, e1); s1 = s1 * __expf(m1 - mn) + __expf(e1 - mn); m1 = mn;
    mn = fmaxf(m2, e2); s2 = s2 * __expf(m2 - mn) + __expf(e2 - mn); m2 = mn;
    mn = fmaxf(m3, e3); s3 = s3 * __expf(m3 - mn) + __expf(e3 - mn); m3 = mn;
  }
#pragma unroll
  for (int off = 1; off < 16; off <<= 1) {
    float mo, so, mn;
    mo = __shfl_xor(m0, off); so = __shfl_xor(s0, off);
    mn = fmaxf(m0, mo); s0 = s0 * __expf(m0 - mn) + so * __expf(mo - mn); m0 = mn;
    mo = __shfl_xor(m1, off); so = __shfl_xor(s1, off);
    mn = fmaxf(m1, mo); s1 = s1 * __expf(m1 - mn) + so * __expf(mo - mn); m1 = mn;
    mo = __shfl_xor(m2, off); so = __shfl_xor(s2, off);
    mn = fmaxf(m2, mo); s2 = s2 * __expf(m2 - mn) + so * __expf(mo - mn); m2 = mn;
    mo = __shfl_xor(m3, off); so = __shfl_xor(s3, off);
    mn = fmaxf(m3, mo); s3 = s3 * __expf(m3 - mn) + so * __expf(mo - mn); m3 = mn;
  }
  float i0 = 1.f / (s0 + 1e-16f);
  float i1 = 1.f / (s1 + 1e-16f);
  float i2 = 1.f / (s2 + 1e-16f);
  float i3 = 1.f / (s3 + 1e-16f);
  for (int k = start + sub; k < end; k += 16) {
    int s = csr[k];
    float4 esv = *(const float4*)&es[s * 4];
    w1[k]          = __expf(leaky(esv.x + edv.x) - m0) * i0;
    w1[E2 + k]     = __expf(leaky(esv.y + edv.y) - m1) * i1;
    w1[2 * E2 + k] = __expf(leaky(esv.z + edv.z) - m2) * i2;
    w1[3 * E2 + k] = __expf(leaky(esv.w + edv.w) - m3) * i3;
  }
}

// ---------------- softmax stats + edge weights, GAT2 (1 head) ----------------
__global__ __launch_bounds__(256) void k_soft2(const float* __restrict__ es,
                                               const float* __restrict__ ed,
                                               const int* __restrict__ rowptr,
                                               const int* __restrict__ csr,
                                               float* __restrict__ w2) {
  int node = blockIdx.x * 16 + (threadIdx.x >> 4);
  int sub = threadIdx.x & 15;
  int start = rowptr[node], end = rowptr[node + 1];
  float edi = ed[node];
  float m = -1e30f, ss = 0.f;
  for (int k = start + sub; k < end; k += 16) {
    float e = leaky(es[csr[k]] + edi);
    float mn = fmaxf(m, e);
    ss = ss * __expf(m - mn) + __expf(e - mn);
    m = mn;
  }
#pragma unroll
  for (int off = 1; off < 16; off <<= 1) {
    float mo = __shfl_xor(m, off);
    float so = __shfl_xor(ss, off);
    float mn = fmaxf(m, mo);
    ss = ss * __expf(m - mn) + so * __expf(mo - mn);
    m = mn;
  }
  float inv = 1.f / (ss + 1e-16f);
  for (int k = start + sub; k < end; k += 16) {
    float e = leaky(es[csr[k]] + edi);
    w2[k] = __expf(e - m) * inv;
  }
}

// ---------------- GAT1 gather + BN1 stats (bf16 out) ----------------
__global__ __launch_bounds__(256) void k_gat1(const unsigned short* __restrict__ h1b,
                                              const float* __restrict__ w1,
                                              const int* __restrict__ rowptr,
                                              const int* __restrict__ csr,
                                              const float* __restrict__ b1,
                                              unsigned short* __restrict__ outb,
                                              float* __restrict__ st) {
  __shared__ float2 sm[4][256];
  int wave = threadIdx.x >> 6;
  int lane = threadIdx.x & 63;
  int i = blockIdx.x * 4 + wave;
  int start = rowptr[i], end = rowptr[i + 1];
  const float* wh = w1 + (size_t)(lane >> 4) * E2;
  float4 acc = make_float4(0.f, 0.f, 0.f, 0.f);
  int k = start;
  for (; k + 4 <= end; k += 4) {
    int sA = csr[k], sB = csr[k + 1], sC = csr[k + 2], sD = csr[k + 3];
    float wA = wh[k], wB = wh[k + 1], wC = wh[k + 2], wD = wh[k + 3];
    ushort4 a0 = *(const ushort4*)&h1b[(size_t)sA * 256 + lane * 4];
    ushort4 a1 = *(const ushort4*)&h1b[(size_t)sB * 256 + lane * 4];
    ushort4 a2 = *(const ushort4*)&h1b[(size_t)sC * 256 + lane * 4];
    ushort4 a3 = *(const ushort4*)&h1b[(size_t)sD * 256 + lane * 4];
    acc.x = fmaf(bf2f(a0.x), wA, fmaf(bf2f(a1.x), wB, fmaf(bf2f(a2.x), wC, fmaf(bf2f(a3.x), wD, acc.x))));
    acc.y = fmaf(bf2f(a0.y), wA, fmaf(bf2f(a1.y), wB, fmaf(bf2f(a2.y), wC, fmaf(bf2f(a3.y), wD, acc.y))));
    acc.z = fmaf(bf2f(a0.z), wA, fmaf(bf2f(a1.z), wB, fmaf(bf2f(a2.z), wC, fmaf(bf2f(a3.z), wD, acc.z))));
    acc.w = fmaf(bf2f(a0.w), wA, fmaf(bf2f(a1.w), wB, fmaf(bf2f(a2.w), wC, fmaf(bf2f(a3.w), wD, acc.w))));
  }
  for (; k < end; ++k) {
    int s = csr[k];
    float wv = wh[k];
    ushort4 a0 = *(const ushort4*)&h1b[(size_t)s * 256 + lane * 4];
    acc.x = fmaf(bf2f(a0.x), wv, acc.x);
    acc.y = fmaf(bf2f(a0.y), wv, acc.y);
    acc.z = fmaf(bf2f(a0.z), wv, acc.z);
    acc.w = fmaf(bf2f(a0.w), wv, acc.w);
  }
  float4 bv = *(const float4*)&b1[lane * 4];
  float4 o;
  o.x = acc.x + bv.x; o.y = acc.y + bv.y; o.z = acc.z + bv.z; o.w = acc.w + bv.w;
  ushort4 u;
  u.x = f2bf(o.x); u.y = f2bf(o.y); u.z = f2bf(o.z); u.w = f2bf(o.w);
  *(ushort4*)&outb[(size_t)i * 256 + lane * 4] = u;
  sm[wave][lane * 4 + 0] = make_float2(o.x, o.x * o.x);
  sm[wave][lane * 4 + 1] = make_float2(o.y, o.y * o.y);
  sm[wave][lane * 4 + 2] = make_float2(o.z, o.z * o.z);
  sm[wave][lane * 4 + 3] = make_float2(o.w, o.w * o.w);
  __syncthreads();
  int c = threadIdx.x;
  float s_ = 0.f, q_ = 0.f;
#pragma unroll
  for (int wv = 0; wv < 4; ++wv) { float2 v = sm[wv][c]; s_ += v.x; q_ += v.y; }
  float* dst = st + (size_t)(blockIdx.x & 31) * 512;
  atomicAdd(&dst[c], s_);
  atomicAdd(&dst[256 + c], q_);
}

// ---------------- GCN gather (hgb pre-scaled by dinv[src]) + BN2 stats ----------------
__global__ __launch_bounds__(256) void k_gcn(const unsigned short* __restrict__ hgb,
                                             const float* __restrict__ dinv,
                                             const int* __restrict__ rowptr,
                                             const int* __restrict__ csr,
                                             const float* __restrict__ bg,
                                             float* __restrict__ out,
                                             float* __restrict__ st) {
  __shared__ float2 sm[4][64];
  int wave = threadIdx.x >> 6;
  int lane = threadIdx.x & 63;
  int i = blockIdx.x * 4 + wave;
  int start = rowptr[i], end = rowptr[i + 1];
  float acc = 0.f;
  int k = start;
  for (; k + 4 <= end; k += 4) {
    int sA = csr[k], sB = csr[k + 1], sC = csr[k + 2], sD = csr[k + 3];
    acc += bf2f(hgb[(size_t)sA * 64 + lane]) + bf2f(hgb[(size_t)sB * 64 + lane]) +
           bf2f(hgb[(size_t)sC * 64 + lane]) + bf2f(hgb[(size_t)sD * 64 + lane]);
  }
  for (; k < end; ++k) acc += bf2f(hgb[(size_t)csr[k] * 64 + lane]);
  float o = fmaf(acc, dinv[i], bg[lane]);
  out[(size_t)i * 64 + lane] = o;
  sm[wave][lane] = make_float2(o, o * o);
  __syncthreads();
  if (threadIdx.x < 64) {
    int c = threadIdx.x;
    float s_ = 0.f, q_ = 0.f;
#pragma unroll
    for (int wv = 0; wv < 4; ++wv) { float2 v = sm[wv][c]; s_ += v.x; q_ += v.y; }
    float* dst = st + (size_t)(blockIdx.x & 31) * 128;
    atomicAdd(&dst[c], s_);
    atomicAdd(&dst[64 + c], q_);
  }
}

// ---------------- GAT2 gather + BN3 stats ----------------
__global__ __launch_bounds__(256) void k_gat2(const unsigned short* __restrict__ h2b,
                                              const float* __restrict__ w2,
                                              const int* __restrict__ rowptr,
                                              const int* __restrict__ csr,
                                              const float* __restrict__ b2,
                                              float* __restrict__ out,
                                              float* __restrict__ st) {
  __shared__ float2 sm[4][64];
  int wave = threadIdx.x >> 6;
  int lane = threadIdx.x & 63;
  int i = blockIdx.x * 4 + wave;
  int start = rowptr[i], end = rowptr[i + 1];
  float acc = 0.f;
  int k = start;
  for (; k + 4 <= end; k += 4) {
    int sA = csr[k], sB = csr[k + 1], sC = csr[k + 2], sD = csr[k + 3];
    float wA = w2[k], wB = w2[k + 1], wC = w2[k + 2], wD = w2[k + 3];
    acc = fmaf(bf2f(h2b[(size_t)sA * 64 + lane]), wA,
          fmaf(bf2f(h2b[(size_t)sB * 64 + lane]), wB,
          fmaf(bf2f(h2b[(size_t)sC * 64 + lane]), wC,
          fmaf(bf2f(h2b[(size_t)sD * 64 + lane]), wD, acc))));
  }
  for (; k < end; ++k)
    acc = fmaf(bf2f(h2b[(size_t)csr[k] * 64 + lane]), w2[k], acc);
  float o = acc + b2[lane];
  out[(size_t)i * 64 + lane] = o;
  sm[wave][lane] = make_float2(o, o * o);
  __syncthreads();
  if (threadIdx.x < 64) {
    int c = threadIdx.x;
    float s_ = 0.f, q_ = 0.f;
#pragma unroll
    for (int wv = 0; wv < 4; ++wv) { float2 v = sm[wv][c]; s_ += v.x; q_ += v.y; }
    float* dst = st + (size_t)(blockIdx.x & 31) * 128;
    atomicAdd(&dst[c], s_);
    atomicAdd(&dst[64 + c], q_);
  }
}

// ---------------- host ----------------
extern "C" void kernel_launch(void* const* d_in, const int* in_sizes, int n_in,
                              void* d_out, int out_size, void* d_ws, size_t ws_size,
                              hipStream_t stream) {
  const float* x        = (const float*)d_in[0];
  const int*   ei       = (const int*)d_in[1];
  const float* W1       = (const float*)d_in[3];
  const float* att_src1 = (const float*)d_in[4];
  const float* att_dst1 = (const float*)d_in[5];
  const float* b1       = (const float*)d_in[6];
  const float* g1       = (const float*)d_in[7];
  const float* beta1    = (const float*)d_in[8];
  const float* Wg       = (const float*)d_in[9];
  const float* bg       = (const float*)d_in[10];
  const float* g2       = (const float*)d_in[11];
  const float* beta2    = (const float*)d_in[12];
  const float* W2       = (const float*)d_in[13];
  const float* att_src2 = (const float*)d_in[14];
  const float* att_dst2 = (const float*)d_in[15];
  const float* b2       = (const float*)d_in[16];
  const float* g3       = (const float*)d_in[17];
  const float* beta3    = (const float*)d_in[18];
  const float* Wp1      = (const float*)d_in[19];
  const float* bp1      = (const float*)d_in[20];
  const float* Wp2      = (const float*)d_in[21];
  const float* bp2      = (const float*)d_in[22];
  float* out = (float*)d_out;

  char* w = (char*)d_ws;
  unsigned short* bufBb  = (unsigned short*)(w + 0);           // gat1 out bf16 [N,256] (25.6MB)
  float*          bufD   = (float*)(w + 0);                    // gat2 out fp32 [N,64] (aliases, gat1-out dead)
  unsigned short* h1b    = (unsigned short*)(w + 51200000);    // [N,256] bf16
  float*          hidden = (float*)(w + 51200000);             // proj hidden [N,128]
  float*          w1     = (float*)(w + 76800000);             // [4,E2] f32
  float*          w2     = (float*)(w + 76800000);             // [E2] f32
  unsigned short* hgb    = (unsigned short*)(w + 90400000);    // [N,64] bf16 (dinv-scaled)
  float*          bufC   = (float*)(w + 96800000);             // gcn out fp32 [N,64]
  unsigned short* h2b    = (unsigned short*)(w + 109600000);   // [N,64] bf16
  float*          es1    = (float*)(w + 116000000);
  float*          ed1    = (float*)(w + 116800000);
  float*          es2    = (float*)(w + 117600000);
  float*          ed2    = (float*)(w + 117800000);
  float*          dinv   = (float*)(w + 118000000);
  int*            deg    = (int*)(w + 118200000);
  int*            rowptr = (int*)(w + 118400000);
  int*            cnt    = (int*)(w + 118600064);
  int*            csr    = (int*)(w + 118800064);
  float*          st1    = (float*)(w + 122200064);            // 32*512 f32
  float*          st2    = st1 + 32 * 512;                     // 32*128 f32
  float*          st3    = st2 + 32 * 128;                     // 32*128 f32
  int*            partial= (int*)(st3 + 32 * 128);             // SCB ints

  hipMemsetAsync(deg, 0, NN * sizeof(int), stream);
  hipMemsetAsync(st1, 0, (32 * 512 + 32 * 128 + 32 * 128) * sizeof(float), stream);

  const int EB = (E2 + 255) / 256;
  const int WB = NN / 4;          // 12500
  const int SB = NN / 16;         // 3125
  const int GX = (NN + 63) / 64;  // 782

  // CSR build (parallel scan)
  k_deg<<<EB, 256, 0, stream>>>(ei, deg);
  k_scan1<<<SCB, 256, 0, stream>>>(deg, partial);
  k_scan2<<<1, 256, 0, stream>>>(partial);
  k_scan3<<<SCB, 256, 0, stream>>>(deg, partial, rowptr, cnt, dinv);
  k_fill<<<EB, 256, 0, stream>>>(ei, cnt, csr);

  // GAT1
  k_gemm<<<dim3(GX, 4), 256, 0, stream>>>(x, nullptr, W1, nullptr, nullptr, nullptr,
                                          nullptr, 0, 0, nullptr, h1b, nullptr, NN, 128, 256);
  k_dots1<<<WB, 256, 0, stream>>>(h1b, att_src1, att_dst1, es1, ed1);
  k_soft1<<<SB, 256, 0, stream>>>(es1, ed1, rowptr, csr, w1);
  k_gat1<<<WB, 256, 0, stream>>>(h1b, w1, rowptr, csr, b1, bufBb, st1);

  // GCN (BN1+ELU fused into bf16-A staging; hgb pre-scaled by dinv[row])
  k_gemm<<<dim3(GX, 1), 256, 0, stream>>>(nullptr, bufBb, Wg, nullptr, st1, g1,
                                          beta1, 2, 0, nullptr, hgb, dinv, NN, 256, 64);
  k_gcn<<<WB, 256, 0, stream>>>(hgb, dinv, rowptr, csr, bg, bufC, st2);

  // GAT2 (BN2+ReLU fused)
  k_gemm<<<dim3(GX, 1), 256, 0, stream>>>(bufC, nullptr, W2, nullptr, st2, g2,
                                          beta2, 1, 0, nullptr, h2b, nullptr, NN, 64, 64);
  k_dots2<<<WB, 256, 0, stream>>>(h2b, att_src2, att_dst2, es2, ed2);
  k_soft2<<<SB, 256, 0, stream>>>(es2, ed2, rowptr, csr, w2);
  k_gat2<<<WB, 256, 0, stream>>>(h2b, w2, rowptr, csr, b2, bufD, st3);

  // projector (BN3+ELU fused into p1 staging)
  k_gemm<<<dim3(GX, 2), 256, 0, stream>>>(bufD, nullptr, Wp1, bp1, st3, g3,
                                          beta3, 2, 1, hidden, nullptr, nullptr, NN, 64, 128);
  k_gemm<<<dim3(GX, 1), 256, 0, stream>>>(hidden, nullptr, Wp2, bp2, nullptr, nullptr,
                                          nullptr, 0, 0, out, nullptr, nullptr, NN, 128, 64);
}

// Round 5
// 532.422 us; speedup vs baseline: 1.8710x; 1.0183x over previous
//
#include <hip/hip_runtime.h>
#include <math.h>

#define NN 50000
#define EE 800000
#define E2 850000   // EE + NN self loops
#define SCB 196     // ceil(NN/256) scan blocks
#define GXL 391     // ceil(NN/128) gemm row blocks

// ---------------- bf16 helpers ----------------
__device__ __forceinline__ float bf2f(unsigned short u) {
  return __uint_as_float(((unsigned int)u) << 16);
}
__device__ __forceinline__ unsigned short f2bf(float f) {
  unsigned int x = __float_as_uint(f);
  unsigned int r = (x + 0x7fffu + ((x >> 16) & 1u)) >> 16;  // RNE
  return (unsigned short)r;
}

__device__ __forceinline__ float leaky(float x) { return x > 0.f ? x : 0.2f * x; }

// ---------------- edge helpers ----------------
__device__ __forceinline__ int edge_src(const int* ei, int e) {
  return (e < EE) ? ei[e] : (e - EE);
}
__device__ __forceinline__ int edge_dst(const int* ei, int e) {
  return (e < EE) ? ei[EE + e] : (e - EE);
}

// ---------------- CSR build ----------------
__global__ void k_deg(const int* __restrict__ ei, int* __restrict__ deg) {
  int e = blockIdx.x * blockDim.x + threadIdx.x;
  if (e < E2) atomicAdd(&deg[edge_dst(ei, e)], 1);
}

// phase 1: per-block sums of 256-element chunks
__global__ __launch_bounds__(256) void k_scan1(const int* __restrict__ deg,
                                               int* __restrict__ partial) {
  __shared__ int sd[256];
  int i = blockIdx.x * 256 + threadIdx.x;
  sd[threadIdx.x] = (i < NN) ? deg[i] : 0;
  __syncthreads();
  for (int off = 128; off > 0; off >>= 1) {
    if (threadIdx.x < off) sd[threadIdx.x] += sd[threadIdx.x + off];
    __syncthreads();
  }
  if (threadIdx.x == 0) partial[blockIdx.x] = sd[0];
}

// phase 2+3 merged: each block scans partials itself, then local scan -> rowptr
__global__ __launch_bounds__(256) void k_scan3(const int* __restrict__ deg,
                                               const int* __restrict__ partial,
                                               int* __restrict__ rowptr,
                                               int* __restrict__ cnt,
                                               float* __restrict__ dinv) {
  __shared__ int sp[256];
  __shared__ int sd[256];
  int t = threadIdx.x;
  sp[t] = (t < SCB) ? partial[t] : 0;
  __syncthreads();
  for (int off = 1; off < 256; off <<= 1) {
    int v = (t >= off) ? sp[t - off] : 0;
    __syncthreads();
    sp[t] += v;
    __syncthreads();
  }
  int base = (blockIdx.x == 0) ? 0 : sp[blockIdx.x - 1];
  int i = blockIdx.x * 256 + t;
  int v = (i < NN) ? deg[i] : 0;
  sd[t] = v;
  __syncthreads();
  for (int off = 1; off < 256; off <<= 1) {
    int u = (t >= off) ? sd[t - off] : 0;
    __syncthreads();
    sd[t] += u;
    __syncthreads();
  }
  if (i < NN) {
    int excl = base + sd[t] - v;
    rowptr[i] = excl;
    cnt[i] = excl;
    dinv[i] = rsqrtf((float)v);  // deg >= 1 (self-loop)
  }
  if (i == 0) rowptr[NN] = E2;
}

__global__ void k_fill(const int* __restrict__ ei, int* __restrict__ cnt,
                       int* __restrict__ csr) {
  int e = blockIdx.x * blockDim.x + threadIdx.x;
  if (e >= E2) return;
  int d = edge_dst(ei, e);
  int s = edge_src(ei, e);
  int pos = atomicAdd(&cnt[d], 1);
  csr[pos] = s;
}

// ---------------- fused fp32 GEMM, 128x64 tile, 8x4 microtile ----------------
// C = outAct( inAct(BN(Ain))[M,K] @ B[K,NC] + biasOut )
// attMode: 0 none; 1 = 4-head (head = blockIdx.y, es[i*4+h]); 2 = 1-head (es[i]).
__global__ __launch_bounds__(256) void k_gemm(
    const float* __restrict__ A, const unsigned short* __restrict__ Abf,
    const float* __restrict__ B, const float* __restrict__ biasOut,
    const float* __restrict__ bnst, const float* __restrict__ bng,
    const float* __restrict__ bnb, int inAct, int outAct,
    float* __restrict__ Cf, unsigned short* __restrict__ Cbf,
    const float* __restrict__ rowScale,
    const float* __restrict__ attSrc, const float* __restrict__ attDst,
    float* __restrict__ esOut, float* __restrict__ edOut, int attMode,
    int M, int K, int NC) {
  __shared__ float As[32][132];   // [k][row], transposed
  __shared__ float Bs[32][68];    // [k][col]
  __shared__ float sSc[256], sSh[256];
  int t = threadIdx.x;
  int tx = t & 15, ty = t >> 4;
  if (bnst) {
    int c = t;
    if (c < K) {
      float sum = 0.f, sq = 0.f;
      for (int cp = 0; cp < 32; ++cp) {
        sum += bnst[cp * 2 * K + c];
        sq += bnst[cp * 2 * K + K + c];
      }
      const float invN = 1.0f / (float)NN;
      float mu = sum * invN;
      float var = sq * invN - mu * mu;
      float rs = rsqrtf(var + 1e-5f);
      float sc = rs * bng[c];
      sSc[c] = sc;
      sSh[c] = fmaf(-mu, sc, bnb[c]);
    }
    __syncthreads();
  }
  int rowBase = blockIdx.x * 128;
  int colBase = blockIdx.y * 64;
  float acc[8][4];
#pragma unroll
  for (int i = 0; i < 8; ++i)
#pragma unroll
    for (int j = 0; j < 4; ++j) acc[i][j] = 0.f;

  int kq = t & 7;       // A-staging k-quad
  int r0 = t >> 3;      // A-staging row base
  for (int kc = 0; kc < K; kc += 32) {
    // stage A (transposed, BN/act fused)
#pragma unroll
    for (int i2 = 0; i2 < 4; ++i2) {
      int row = r0 + 32 * i2;
      int gr = rowBase + row;
      float4 av = make_float4(0.f, 0.f, 0.f, 0.f);
      if (gr < M) {
        if (Abf) {
          ushort4 u4 = *(const ushort4*)&Abf[(size_t)gr * K + kc + kq * 4];
          av = make_float4(bf2f(u4.x), bf2f(u4.y), bf2f(u4.z), bf2f(u4.w));
        } else {
          av = *(const float4*)&A[(size_t)gr * K + kc + kq * 4];
        }
      }
      if (bnst) {
        int c = kc + kq * 4;
        av.x = fmaf(av.x, sSc[c + 0], sSh[c + 0]);
        av.y = fmaf(av.y, sSc[c + 1], sSh[c + 1]);
        av.z = fmaf(av.z, sSc[c + 2], sSh[c + 2]);
        av.w = fmaf(av.w, sSc[c + 3], sSh[c + 3]);
      }
      if (inAct == 1) {
        av.x = fmaxf(av.x, 0.f); av.y = fmaxf(av.y, 0.f);
        av.z = fmaxf(av.z, 0.f); av.w = fmaxf(av.w, 0.f);
      } else if (inAct == 2) {
        av.x = av.x > 0.f ? av.x : expm1f(av.x);
        av.y = av.y > 0.f ? av.y : expm1f(av.y);
        av.z = av.z > 0.f ? av.z : expm1f(av.z);
        av.w = av.w > 0.f ? av.w : expm1f(av.w);
      }
      As[kq * 4 + 0][row] = av.x;
      As[kq * 4 + 1][row] = av.y;
      As[kq * 4 + 2][row] = av.z;
      As[kq * 4 + 3][row] = av.w;
    }
    // stage B
#pragma unroll
    for (int i2 = 0; i2 < 2; ++i2) {
      int u = t + 256 * i2;
      int c4 = u & 15, kk = u >> 4;
      float4 bv = *(const float4*)&B[(size_t)(kc + kk) * NC + colBase + c4 * 4];
      *(float4*)&Bs[kk][c4 * 4] = bv;
    }
    __syncthreads();
#pragma unroll
    for (int kk = 0; kk < 32; ++kk) {
      float4 a0 = *(const float4*)&As[kk][ty * 8];
      float4 a1 = *(const float4*)&As[kk][ty * 8 + 4];
      float4 bv = *(const float4*)&Bs[kk][tx * 4];
      float a_[8] = {a0.x, a0.y, a0.z, a0.w, a1.x, a1.y, a1.z, a1.w};
      float b_[4] = {bv.x, bv.y, bv.z, bv.w};
#pragma unroll
      for (int i = 0; i < 8; ++i)
#pragma unroll
        for (int j = 0; j < 4; ++j) acc[i][j] = fmaf(a_[i], b_[j], acc[i][j]);
    }
    __syncthreads();
  }

  float4 bb = make_float4(0.f, 0.f, 0.f, 0.f);
  if (biasOut) bb = *(const float4*)&biasOut[colBase + tx * 4];
  float4 as4 = make_float4(0.f, 0.f, 0.f, 0.f), ad4 = as4;
  if (attMode) {
    as4 = *(const float4*)&attSrc[colBase + tx * 4];
    ad4 = *(const float4*)&attDst[colBase + tx * 4];
  }
#pragma unroll
  for (int i = 0; i < 8; ++i) {
    int gr = rowBase + ty * 8 + i;
    if (gr < M) {   // uniform across the 16 tx lanes
      float4 v;
      v.x = acc[i][0] + bb.x;
      v.y = acc[i][1] + bb.y;
      v.z = acc[i][2] + bb.z;
      v.w = acc[i][3] + bb.w;
      if (outAct == 1) {
        v.x = fmaxf(v.x, 0.f); v.y = fmaxf(v.y, 0.f);
        v.z = fmaxf(v.z, 0.f); v.w = fmaxf(v.w, 0.f);
      }
      if (Cf) *(float4*)&Cf[(size_t)gr * NC + colBase + tx * 4] = v;
      if (Cbf) {
        float rs_ = rowScale ? rowScale[gr] : 1.f;
        ushort4 u;
        u.x = f2bf(v.x * rs_); u.y = f2bf(v.y * rs_);
        u.z = f2bf(v.z * rs_); u.w = f2bf(v.w * rs_);
        *(ushort4*)&Cbf[(size_t)gr * NC + colBase + tx * 4] = u;
      }
      if (attMode) {
        float pes = v.x * as4.x + v.y * as4.y + v.z * as4.z + v.w * as4.w;
        float ped = v.x * ad4.x + v.y * ad4.y + v.z * ad4.z + v.w * ad4.w;
#pragma unroll
        for (int off = 8; off > 0; off >>= 1) {
          pes += __shfl_xor(pes, off);
          ped += __shfl_xor(ped, off);
        }
        if (tx == 0) {
          if (attMode == 1) {
            esOut[gr * 4 + blockIdx.y] = pes;
            edOut[gr * 4 + blockIdx.y] = ped;
          } else {
            esOut[gr] = pes;
            edOut[gr] = ped;
          }
        }
      }
    }
  }
}

// ---------------- softmax stats + edge weights, GAT1 (4 heads) ----------------
__global__ __launch_bounds__(256) void k_soft1(const float* __restrict__ es,
                                               const float* __restrict__ ed,
                                               const int* __restrict__ rowptr,
                                               const int* __restrict__ csr,
                                               float* __restrict__ w1) {
  int node = blockIdx.x * 16 + (threadIdx.x >> 4);
  int sub = threadIdx.x & 15;
  int start = rowptr[node], end = rowptr[node + 1];
  float4 edv = *(const float4*)&ed[node * 4];
  float m0 = -1e30f, m1 = -1e30f, m2 = -1e30f, m3 = -1e30f;
  float s0 = 0.f, s1 = 0.f, s2 = 0.f, s3 = 0.f;
  for (int k = start + sub; k < end; k += 16) {
    int s = csr[k];
    float4 esv = *(const float4*)&es[s * 4];
    float e0 = leaky(esv.x + edv.x);
    float e1 = leaky(esv.y + edv.y);
    float e2 = leaky(esv.z + edv.z);
    float e3 = leaky(esv.w + edv.w);
    float mn;
    mn = fmaxf(m0, e0); s0 = s0 * __expf(m0 - mn) + __expf(e0 - mn); m0 = mn;
    mn = fmaxf(m1, e1); s1 = s1 * __expf(m1 - mn) + __expf(e1 - mn); m1 = mn;
    mn = fmaxf(m2, e2); s2 = s2 * __expf(m2 - mn) + __expf(e2 - mn); m2 = mn;
    mn = fmaxf(m3, e3); s3 = s3 * __expf(m3 - mn) + __expf(e3 - mn); m3 = mn;
  }
#pragma unroll
  for (int off = 1; off < 16; off <<= 1) {
    float mo, so, mn;
    mo = __shfl_xor(m0, off); so = __shfl_xor(s0, off);
    mn = fmaxf(m0, mo); s0 = s0 * __expf(m0 - mn) + so * __expf(mo - mn); m0 = mn;
    mo = __shfl_xor(m1, off); so = __shfl_xor(s1, off);
    mn = fmaxf(m1, mo); s1 = s1 * __expf(m1 - mn) + so * __expf(mo - mn); m1 = mn;
    mo = __shfl_xor(m2, off); so = __shfl_xor(s2, off);
    mn = fmaxf(m2, mo); s2 = s2 * __expf(m2 - mn) + so * __expf(mo - mn); m2 = mn;
    mo = __shfl_xor(m3, off); so = __shfl_xor(s3, off);
    mn = fmaxf(m3, mo); s3 = s3 * __expf(m3 - mn) + so * __expf(mo - mn); m3 = mn;
  }
  float i0 = 1.f / (s0 + 1e-16f);
  float i1 = 1.f / (s1 + 1e-16f);
  float i2 = 1.f / (s2 + 1e-16f);
  float i3 = 1.f / (s3 + 1e-16f);
  for (int k = start + sub; k < end; k += 16) {
    int s = csr[k];
    float4 esv = *(const float4*)&es[s * 4];
    w1[k]          = __expf(leaky(esv.x + edv.x) - m0) * i0;
    w1[E2 + k]     = __expf(leaky(esv.y + edv.y) - m1) * i1;
    w1[2 * E2 + k] = __expf(leaky(esv.z + edv.z) - m2) * i2;
    w1[3 * E2 + k] = __expf(leaky(esv.w + edv.w) - m3) * i3;
  }
}

// ---------------- softmax stats + edge weights, GAT2 (1 head) ----------------
__global__ __launch_bounds__(256) void k_soft2(const float* __restrict__ es,
                                               const float* __restrict__ ed,
                                               const int* __restrict__ rowptr,
                                               const int* __restrict__ csr,
                                               float* __restrict__ w2) {
  int node = blockIdx.x * 16 + (threadIdx.x >> 4);
  int sub = threadIdx.x & 15;
  int start = rowptr[node], end = rowptr[node + 1];
  float edi = ed[node];
  float m = -1e30f, ss = 0.f;
  for (int k = start + sub; k < end; k += 16) {
    float e = leaky(es[csr[k]] + edi);
    float mn = fmaxf(m, e);
    ss = ss * __expf(m - mn) + __expf(e - mn);
    m = mn;
  }
#pragma unroll
  for (int off = 1; off < 16; off <<= 1) {
    float mo = __shfl_xor(m, off);
    float so = __shfl_xor(ss, off);
    float mn = fmaxf(m, mo);
    ss = ss * __expf(m - mn) + so * __expf(mo - mn);
    m = mn;
  }
  float inv = 1.f / (ss + 1e-16f);
  for (int k = start + sub; k < end; k += 16) {
    float e = leaky(es[csr[k]] + edi);
    w2[k] = __expf(e - m) * inv;
  }
}

// ---------------- GAT1 gather + BN1 stats (bf16 out, conflict-free stats) -------
__global__ __launch_bounds__(256) void k_gat1(const unsigned short* __restrict__ h1b,
                                              const float* __restrict__ w1,
                                              const int* __restrict__ rowptr,
                                              const int* __restrict__ csr,
                                              const float* __restrict__ b1,
                                              unsigned short* __restrict__ outb,
                                              float* __restrict__ st) {
  __shared__ float smS[4][256];
  __shared__ float smQ[4][256];
  int wave = threadIdx.x >> 6;
  int lane = threadIdx.x & 63;
  int i = blockIdx.x * 4 + wave;
  int start = rowptr[i], end = rowptr[i + 1];
  const float* wh = w1 + (size_t)(lane >> 4) * E2;
  float4 acc = make_float4(0.f, 0.f, 0.f, 0.f);
  int k = start;
  for (; k + 4 <= end; k += 4) {
    int sA = csr[k], sB = csr[k + 1], sC = csr[k + 2], sD = csr[k + 3];
    float wA = wh[k], wB = wh[k + 1], wC = wh[k + 2], wD = wh[k + 3];
    ushort4 a0 = *(const ushort4*)&h1b[(size_t)sA * 256 + lane * 4];
    ushort4 a1 = *(const ushort4*)&h1b[(size_t)sB * 256 + lane * 4];
    ushort4 a2 = *(const ushort4*)&h1b[(size_t)sC * 256 + lane * 4];
    ushort4 a3 = *(const ushort4*)&h1b[(size_t)sD * 256 + lane * 4];
    acc.x = fmaf(bf2f(a0.x), wA, fmaf(bf2f(a1.x), wB, fmaf(bf2f(a2.x), wC, fmaf(bf2f(a3.x), wD, acc.x))));
    acc.y = fmaf(bf2f(a0.y), wA, fmaf(bf2f(a1.y), wB, fmaf(bf2f(a2.y), wC, fmaf(bf2f(a3.y), wD, acc.y))));
    acc.z = fmaf(bf2f(a0.z), wA, fmaf(bf2f(a1.z), wB, fmaf(bf2f(a2.z), wC, fmaf(bf2f(a3.z), wD, acc.z))));
    acc.w = fmaf(bf2f(a0.w), wA, fmaf(bf2f(a1.w), wB, fmaf(bf2f(a2.w), wC, fmaf(bf2f(a3.w), wD, acc.w))));
  }
  for (; k < end; ++k) {
    int s = csr[k];
    float wv = wh[k];
    ushort4 a0 = *(const ushort4*)&h1b[(size_t)s * 256 + lane * 4];
    acc.x = fmaf(bf2f(a0.x), wv, acc.x);
    acc.y = fmaf(bf2f(a0.y), wv, acc.y);
    acc.z = fmaf(bf2f(a0.z), wv, acc.z);
    acc.w = fmaf(bf2f(a0.w), wv, acc.w);
  }
  float4 bv = *(const float4*)&b1[lane * 4];
  float4 o;
  o.x = acc.x + bv.x; o.y = acc.y + bv.y; o.z = acc.z + bv.z; o.w = acc.w + bv.w;
  ushort4 u;
  u.x = f2bf(o.x); u.y = f2bf(o.y); u.z = f2bf(o.z); u.w = f2bf(o.w);
  *(ushort4*)&outb[(size_t)i * 256 + lane * 4] = u;
  *(float4*)&smS[wave][lane * 4] = o;
  float4 q = make_float4(o.x * o.x, o.y * o.y, o.z * o.z, o.w * o.w);
  *(float4*)&smQ[wave][lane * 4] = q;
  __syncthreads();
  int c = threadIdx.x;
  float s_ = 0.f, q_ = 0.f;
#pragma unroll
  for (int wv = 0; wv < 4; ++wv) { s_ += smS[wv][c]; q_ += smQ[wv][c]; }
  float* dst = st + (size_t)(blockIdx.x & 31) * 512;
  atomicAdd(&dst[c], s_);
  atomicAdd(&dst[256 + c], q_);
}

// ---------------- GCN gather (hgb pre-scaled by dinv[src]) + BN2 stats ----------
__global__ __launch_bounds__(256) void k_gcn(const unsigned short* __restrict__ hgb,
                                             const float* __restrict__ dinv,
                                             const int* __restrict__ rowptr,
                                             const int* __restrict__ csr,
                                             const float* __restrict__ bg,
                                             float* __restrict__ out,
                                             float* __restrict__ st) {
  __shared__ float2 sm[4][64];
  int wave = threadIdx.x >> 6;
  int lane = threadIdx.x & 63;
  int i = blockIdx.x * 4 + wave;
  int start = rowptr[i], end = rowptr[i + 1];
  float acc = 0.f;
  int k = start;
  for (; k + 4 <= end; k += 4) {
    int sA = csr[k], sB = csr[k + 1], sC = csr[k + 2], sD = csr[k + 3];
    acc += bf2f(hgb[(size_t)sA * 64 + lane]) + bf2f(hgb[(size_t)sB * 64 + lane]) +
           bf2f(hgb[(size_t)sC * 64 + lane]) + bf2f(hgb[(size_t)sD * 64 + lane]);
  }
  for (; k < end; ++k) acc += bf2f(hgb[(size_t)csr[k] * 64 + lane]);
  float o = fmaf(acc, dinv[i], bg[lane]);
  out[(size_t)i * 64 + lane] = o;
  sm[wave][lane] = make_float2(o, o * o);
  __syncthreads();
  if (threadIdx.x < 64) {
    int c = threadIdx.x;
    float s_ = 0.f, q_ = 0.f;
#pragma unroll
    for (int wv = 0; wv < 4; ++wv) { float2 v = sm[wv][c]; s_ += v.x; q_ += v.y; }
    float* dst = st + (size_t)(blockIdx.x & 31) * 128;
    atomicAdd(&dst[c], s_);
    atomicAdd(&dst[64 + c], q_);
  }
}

// ---------------- GAT2 gather + BN3 stats ----------------
__global__ __launch_bounds__(256) void k_gat2(const unsigned short* __restrict__ h2b,
                                              const float* __restrict__ w2,
                                              const int* __restrict__ rowptr,
                                              const int* __restrict__ csr,
                                              const float* __restrict__ b2,
                                              float* __restrict__ out,
                                              float* __restrict__ st) {
  __shared__ float2 sm[4][64];
  int wave = threadIdx.x >> 6;
  int lane = threadIdx.x & 63;
  int i = blockIdx.x * 4 + wave;
  int start = rowptr[i], end = rowptr[i + 1];
  float acc = 0.f;
  int k = start;
  for (; k + 4 <= end; k += 4) {
    int sA = csr[k], sB = csr[k + 1], sC = csr[k + 2], sD = csr[k + 3];
    float wA = w2[k], wB = w2[k + 1], wC = w2[k + 2], wD = w2[k + 3];
    acc = fmaf(bf2f(h2b[(size_t)sA * 64 + lane]), wA,
          fmaf(bf2f(h2b[(size_t)sB * 64 + lane]), wB,
          fmaf(bf2f(h2b[(size_t)sC * 64 + lane]), wC,
          fmaf(bf2f(h2b[(size_t)sD * 64 + lane]), wD, acc))));
  }
  for (; k < end; ++k)
    acc = fmaf(bf2f(h2b[(size_t)csr[k] * 64 + lane]), w2[k], acc);
  float o = acc + b2[lane];
  out[(size_t)i * 64 + lane] = o;
  sm[wave][lane] = make_float2(o, o * o);
  __syncthreads();
  if (threadIdx.x < 64) {
    int c = threadIdx.x;
    float s_ = 0.f, q_ = 0.f;
#pragma unroll
    for (int wv = 0; wv < 4; ++wv) { float2 v = sm[wv][c]; s_ += v.x; q_ += v.y; }
    float* dst = st + (size_t)(blockIdx.x & 31) * 128;
    atomicAdd(&dst[c], s_);
    atomicAdd(&dst[64 + c], q_);
  }
}

// ---------------- host ----------------
extern "C" void kernel_launch(void* const* d_in, const int* in_sizes, int n_in,
                              void* d_out, int out_size, void* d_ws, size_t ws_size,
                              hipStream_t stream) {
  const float* x        = (const float*)d_in[0];
  const int*   ei       = (const int*)d_in[1];
  const float* W1       = (const float*)d_in[3];
  const float* att_src1 = (const float*)d_in[4];
  const float* att_dst1 = (const float*)d_in[5];
  const float* b1       = (const float*)d_in[6];
  const float* g1       = (const float*)d_in[7];
  const float* beta1    = (const float*)d_in[8];
  const float* Wg       = (const float*)d_in[9];
  const float* bg       = (const float*)d_in[10];
  const float* g2       = (const float*)d_in[11];
  const float* beta2    = (const float*)d_in[12];
  const float* W2       = (const float*)d_in[13];
  const float* att_src2 = (const float*)d_in[14];
  const float* att_dst2 = (const float*)d_in[15];
  const float* b2       = (const float*)d_in[16];
  const float* g3       = (const float*)d_in[17];
  const float* beta3    = (const float*)d_in[18];
  const float* Wp1      = (const float*)d_in[19];
  const float* bp1      = (const float*)d_in[20];
  const float* Wp2      = (const float*)d_in[21];
  const float* bp2      = (const float*)d_in[22];
  float* out = (float*)d_out;

  char* w = (char*)d_ws;
  unsigned short* bufBb  = (unsigned short*)(w + 0);           // gat1 out bf16 [N,256]
  float*          bufD   = (float*)(w + 0);                    // gat2 out fp32 [N,64] (alias)
  unsigned short* h1b    = (unsigned short*)(w + 51200000);    // [N,256] bf16
  float*          hidden = (float*)(w + 51200000);             // proj hidden [N,128] (alias)
  float*          w1     = (float*)(w + 76800000);             // [4,E2] f32
  float*          w2     = (float*)(w + 76800000);             // [E2] f32 (alias)
  unsigned short* hgb    = (unsigned short*)(w + 90400000);    // [N,64] bf16 (dinv-scaled)
  float*          bufC   = (float*)(w + 96800000);             // gcn out fp32 [N,64]
  unsigned short* h2b    = (unsigned short*)(w + 109600000);   // [N,64] bf16
  float*          es1    = (float*)(w + 116000000);
  float*          ed1    = (float*)(w + 116800000);
  float*          es2    = (float*)(w + 117600000);
  float*          ed2    = (float*)(w + 117800000);
  float*          dinv   = (float*)(w + 118000000);
  int*            deg    = (int*)(w + 118200000);
  int*            rowptr = (int*)(w + 118400000);
  int*            cnt    = (int*)(w + 118600064);
  int*            csr    = (int*)(w + 118800064);
  float*          st1    = (float*)(w + 122200064);            // 32*512 f32
  float*          st2    = st1 + 32 * 512;                     // 32*128 f32
  float*          st3    = st2 + 32 * 128;                     // 32*128 f32
  int*            partial= (int*)(st3 + 32 * 128);             // SCB ints

  hipMemsetAsync(deg, 0, NN * sizeof(int), stream);
  hipMemsetAsync(st1, 0, (32 * 512 + 32 * 128 + 32 * 128) * sizeof(float), stream);

  const int EB = (E2 + 255) / 256;
  const int WB = NN / 4;          // 12500
  const int SB = NN / 16;         // 3125

  // CSR build (parallel scan, 2 dispatches)
  k_deg<<<EB, 256, 0, stream>>>(ei, deg);
  k_scan1<<<SCB, 256, 0, stream>>>(deg, partial);
  k_scan3<<<SCB, 256, 0, stream>>>(deg, partial, rowptr, cnt, dinv);
  k_fill<<<EB, 256, 0, stream>>>(ei, cnt, csr);

  // GAT1: h1 = x@W1 -> h1b bf16, es1/ed1 fused in epilogue (4 heads)
  k_gemm<<<dim3(GXL, 4), 256, 0, stream>>>(x, nullptr, W1, nullptr,
                                           nullptr, nullptr, nullptr, 0, 0,
                                           nullptr, h1b, nullptr,
                                           att_src1, att_dst1, es1, ed1, 1,
                                           NN, 128, 256);
  k_soft1<<<SB, 256, 0, stream>>>(es1, ed1, rowptr, csr, w1);
  k_gat1<<<WB, 256, 0, stream>>>(h1b, w1, rowptr, csr, b1, bufBb, st1);

  // GCN: BN1+ELU fused into bf16-A staging; hgb pre-scaled by dinv[row]
  k_gemm<<<dim3(GXL, 1), 256, 0, stream>>>(nullptr, bufBb, Wg, nullptr,
                                           st1, g1, beta1, 2, 0,
                                           nullptr, hgb, dinv,
                                           nullptr, nullptr, nullptr, nullptr, 0,
                                           NN, 256, 64);
  k_gcn<<<WB, 256, 0, stream>>>(hgb, dinv, rowptr, csr, bg, bufC, st2);

  // GAT2: BN2+ReLU fused; es2/ed2 fused in epilogue (1 head)
  k_gemm<<<dim3(GXL, 1), 256, 0, stream>>>(bufC, nullptr, W2, nullptr,
                                           st2, g2, beta2, 1, 0,
                                           nullptr, h2b, nullptr,
                                           att_src2, att_dst2, es2, ed2, 2,
                                           NN, 64, 64);
  k_soft2<<<SB, 256, 0, stream>>>(es2, ed2, rowptr, csr, w2);
  k_gat2<<<WB, 256, 0, stream>>>(h2b, w2, rowptr, csr, b2, bufD, st3);

  // projector: BN3+ELU fused into p1 staging
  k_gemm<<<dim3(GXL, 2), 256, 0, stream>>>(bufD, nullptr, Wp1, bp1,
                                           st3, g3, beta3, 2, 1,
                                           hidden, nullptr, nullptr,
                                           nullptr, nullptr, nullptr, nullptr, 0,
                                           NN, 64, 128);
  k_gemm<<<dim3(GXL, 1), 256, 0, stream>>>(hidden, nullptr, Wp2, bp2,
                                           nullptr, nullptr, nullptr, 0, 0,
                                           out, nullptr, nullptr,
                                           nullptr, nullptr, nullptr, nullptr, 0,
                                           NN, 128, 64);
}

// Round 6
// 485.447 us; speedup vs baseline: 2.0521x; 1.0968x over previous
//
#include <hip/hip_runtime.h>
#include <math.h>

#define NN 50000
#define EE 800000
#define E2 850000   // EE + NN self loops
#define SCB 196     // ceil(NN/256) scan blocks
#define GXL 391     // ceil(NN/128) gemm row blocks

typedef __attribute__((ext_vector_type(8))) short short8;
typedef __attribute__((ext_vector_type(4))) float float4v;

// ---------------- bf16 helpers ----------------
__device__ __forceinline__ float bf2f(unsigned short u) {
  return __uint_as_float(((unsigned int)u) << 16);
}
__device__ __forceinline__ unsigned short f2bf(float f) {
  unsigned int x = __float_as_uint(f);
  unsigned int r = (x + 0x7fffu + ((x >> 16) & 1u)) >> 16;  // RNE
  return (unsigned short)r;
}

__device__ __forceinline__ float leaky(float x) { return x > 0.f ? x : 0.2f * x; }

// ---------------- edge helpers ----------------
__device__ __forceinline__ int edge_src(const int* ei, int e) {
  return (e < EE) ? ei[e] : (e - EE);
}
__device__ __forceinline__ int edge_dst(const int* ei, int e) {
  return (e < EE) ? ei[EE + e] : (e - EE);
}

// ---------------- CSR build ----------------
__global__ void k_deg(const int* __restrict__ ei, int* __restrict__ deg) {
  int e = blockIdx.x * blockDim.x + threadIdx.x;
  if (e < E2) atomicAdd(&deg[edge_dst(ei, e)], 1);
}

__global__ __launch_bounds__(256) void k_scan1(const int* __restrict__ deg,
                                               int* __restrict__ partial) {
  __shared__ int sd[256];
  int i = blockIdx.x * 256 + threadIdx.x;
  sd[threadIdx.x] = (i < NN) ? deg[i] : 0;
  __syncthreads();
  for (int off = 128; off > 0; off >>= 1) {
    if (threadIdx.x < off) sd[threadIdx.x] += sd[threadIdx.x + off];
    __syncthreads();
  }
  if (threadIdx.x == 0) partial[blockIdx.x] = sd[0];
}

__global__ __launch_bounds__(256) void k_scan3(const int* __restrict__ deg,
                                               const int* __restrict__ partial,
                                               int* __restrict__ rowptr,
                                               int* __restrict__ cnt,
                                               float* __restrict__ dinv) {
  __shared__ int sp[256];
  __shared__ int sd[256];
  int t = threadIdx.x;
  sp[t] = (t < SCB) ? partial[t] : 0;
  __syncthreads();
  for (int off = 1; off < 256; off <<= 1) {
    int v = (t >= off) ? sp[t - off] : 0;
    __syncthreads();
    sp[t] += v;
    __syncthreads();
  }
  int base = (blockIdx.x == 0) ? 0 : sp[blockIdx.x - 1];
  int i = blockIdx.x * 256 + t;
  int v = (i < NN) ? deg[i] : 0;
  sd[t] = v;
  __syncthreads();
  for (int off = 1; off < 256; off <<= 1) {
    int u = (t >= off) ? sd[t - off] : 0;
    __syncthreads();
    sd[t] += u;
    __syncthreads();
  }
  if (i < NN) {
    int excl = base + sd[t] - v;
    rowptr[i] = excl;
    cnt[i] = excl;
    dinv[i] = rsqrtf((float)v);  // deg >= 1 (self-loop)
  }
  if (i == 0) rowptr[NN] = E2;
}

__global__ void k_fill(const int* __restrict__ ei, int* __restrict__ cnt,
                       int* __restrict__ csr) {
  int e = blockIdx.x * blockDim.x + threadIdx.x;
  if (e >= E2) return;
  int d = edge_dst(ei, e);
  int s = edge_src(ei, e);
  int pos = atomicAdd(&cnt[d], 1);
  csr[pos] = s;
}

// ---------------- MFMA bf16 GEMM, 128x64 tile, 4 waves ----------------
// C = outAct( inAct(BN(Ain))[M,K] @ B[K,NC] + biasOut )
// A fragments loaded directly from global (BN/act in regs, cvt bf16);
// B^T staged ONCE in LDS as bf16 -> no barriers in the K-loop.
// ATTMODE: 0 none; 1 = 4-head (head=blockIdx.y, es[i*4+h]); 2 = 1-head (es[i]).
template <int K, int ATTMODE, int INACT, bool ABF, bool USEBN>
__global__ __launch_bounds__(256) void k_gemm_mfma(
    const float* __restrict__ A, const unsigned short* __restrict__ Abf,
    const float* __restrict__ B, const float* __restrict__ biasOut,
    const float* __restrict__ bnst, const float* __restrict__ bng,
    const float* __restrict__ bnb, int outAct,
    float* __restrict__ Cf, unsigned short* __restrict__ Cbf,
    const float* __restrict__ rowScale,
    const float* __restrict__ attSrc, const float* __restrict__ attDst,
    float* __restrict__ esOut, float* __restrict__ edOut,
    int M, int NC) {
  __shared__ unsigned short BT[64][K + 8];  // [col][k] bf16
  __shared__ float sSc[256], sSh[256];
  int t = threadIdx.x;
  int lane = t & 63;
  int wv = t >> 6;
  int cl = lane & 15;   // frag row (A) / frag col (B) / D col
  int kg = lane >> 4;   // k-group (frag), D row-group
  int rowBase = blockIdx.x * 128;
  int colBase = blockIdx.y * 64;

  if (USEBN) {
    int c = t;
    if (c < K) {
      float sum = 0.f, sq = 0.f;
      for (int cp = 0; cp < 32; ++cp) {
        sum += bnst[cp * 2 * K + c];
        sq += bnst[cp * 2 * K + K + c];
      }
      const float invN = 1.0f / (float)NN;
      float mu = sum * invN;
      float var = sq * invN - mu * mu;
      float rs = rsqrtf(var + 1e-5f);
      float sc = rs * bng[c];
      sSc[c] = sc;
      sSh[c] = fmaf(-mu, sc, bnb[c]);
    }
  }
  // stage B^T (bf16) once
  {
    int c = t & 63;
    for (int k = t >> 6; k < K; k += 4)
      BT[c][k] = f2bf(B[(size_t)k * NC + colBase + c]);
  }
  __syncthreads();

  float4v acc[2][4];
#pragma unroll
  for (int rt = 0; rt < 2; ++rt)
#pragma unroll
    for (int ct = 0; ct < 4; ++ct) acc[rt][ct] = (float4v){0.f, 0.f, 0.f, 0.f};

  int grA0 = rowBase + wv * 32 + cl;  // A-frag rows
  int grA1 = grA0 + 16;

#pragma unroll
  for (int kc = 0; kc < K; kc += 32) {
    int k0 = kc + kg * 8;
    short8 afr[2];
#pragma unroll
    for (int rt = 0; rt < 2; ++rt) {
      int gr = rt ? grA1 : grA0;
      float v[8];
      if (gr < M) {
        if (ABF) {
          ushort4 u0 = *(const ushort4*)&Abf[(size_t)gr * K + k0];
          ushort4 u1 = *(const ushort4*)&Abf[(size_t)gr * K + k0 + 4];
          v[0] = bf2f(u0.x); v[1] = bf2f(u0.y); v[2] = bf2f(u0.z); v[3] = bf2f(u0.w);
          v[4] = bf2f(u1.x); v[5] = bf2f(u1.y); v[6] = bf2f(u1.z); v[7] = bf2f(u1.w);
        } else {
          float4 f0 = *(const float4*)&A[(size_t)gr * K + k0];
          float4 f1 = *(const float4*)&A[(size_t)gr * K + k0 + 4];
          v[0] = f0.x; v[1] = f0.y; v[2] = f0.z; v[3] = f0.w;
          v[4] = f1.x; v[5] = f1.y; v[6] = f1.z; v[7] = f1.w;
        }
      } else {
#pragma unroll
        for (int i = 0; i < 8; ++i) v[i] = 0.f;
      }
#pragma unroll
      for (int i = 0; i < 8; ++i) {
        float x = v[i];
        if (USEBN) x = fmaf(x, sSc[k0 + i], sSh[k0 + i]);
        if (INACT == 1) x = fmaxf(x, 0.f);
        else if (INACT == 2) x = (x > 0.f) ? x : expm1f(x);
        afr[rt][i] = (short)f2bf(x);
      }
    }
    short8 bfr[4];
#pragma unroll
    for (int ct = 0; ct < 4; ++ct)
      bfr[ct] = *(const short8*)&BT[ct * 16 + cl][k0];
#pragma unroll
    for (int rt = 0; rt < 2; ++rt)
#pragma unroll
      for (int ct = 0; ct < 4; ++ct)
        acc[rt][ct] = __builtin_amdgcn_mfma_f32_16x16x32_bf16(
            afr[rt], bfr[ct], acc[rt][ct], 0, 0, 0);
  }

  // epilogue
  float bb[4], as4[4], ad4[4];
#pragma unroll
  for (int ct = 0; ct < 4; ++ct) {
    int gc = colBase + ct * 16 + cl;
    bb[ct] = biasOut ? biasOut[gc] : 0.f;
    if (ATTMODE) {
      as4[ct] = attSrc[gc];
      ad4[ct] = attDst[gc];
    }
  }
#pragma unroll
  for (int rt = 0; rt < 2; ++rt) {
    float pes[4] = {0.f, 0.f, 0.f, 0.f};
    float ped[4] = {0.f, 0.f, 0.f, 0.f};
#pragma unroll
    for (int reg = 0; reg < 4; ++reg) {
      int gr = rowBase + wv * 32 + rt * 16 + kg * 4 + reg;
      bool ok = gr < M;
      float rs_ = 1.f;
      if (ok && Cbf && rowScale) rs_ = rowScale[gr];
#pragma unroll
      for (int ct = 0; ct < 4; ++ct) {
        float v = acc[rt][ct][reg] + bb[ct];
        if (outAct == 1) v = fmaxf(v, 0.f);
        int gc = colBase + ct * 16 + cl;
        if (ok) {
          if (Cf) Cf[(size_t)gr * NC + gc] = v;
          if (Cbf) Cbf[(size_t)gr * NC + gc] = f2bf(v * rs_);
        }
        if (ATTMODE) {
          pes[reg] = fmaf(v, as4[ct], pes[reg]);
          ped[reg] = fmaf(v, ad4[ct], ped[reg]);
        }
      }
    }
    if (ATTMODE) {
#pragma unroll
      for (int reg = 0; reg < 4; ++reg) {
#pragma unroll
        for (int off = 8; off > 0; off >>= 1) {
          pes[reg] += __shfl_xor(pes[reg], off);
          ped[reg] += __shfl_xor(ped[reg], off);
        }
      }
      if (cl == 0) {
#pragma unroll
        for (int reg = 0; reg < 4; ++reg) {
          int gr = rowBase + wv * 32 + rt * 16 + kg * 4 + reg;
          if (gr < M) {
            if (ATTMODE == 1) {
              esOut[gr * 4 + blockIdx.y] = pes[reg];
              edOut[gr * 4 + blockIdx.y] = ped[reg];
            } else {
              esOut[gr] = pes[reg];
              edOut[gr] = ped[reg];
            }
          }
        }
      }
    }
  }
}

// ---------------- softmax stats + edge weights, GAT1 (4 heads) ----------------
__global__ __launch_bounds__(256) void k_soft1(const float* __restrict__ es,
                                               const float* __restrict__ ed,
                                               const int* __restrict__ rowptr,
                                               const int* __restrict__ csr,
                                               float* __restrict__ w1) {
  int node = blockIdx.x * 16 + (threadIdx.x >> 4);
  int sub = threadIdx.x & 15;
  int start = rowptr[node], end = rowptr[node + 1];
  float4 edv = *(const float4*)&ed[node * 4];
  float m0 = -1e30f, m1 = -1e30f, m2 = -1e30f, m3 = -1e30f;
  float s0 = 0.f, s1 = 0.f, s2 = 0.f, s3 = 0.f;
  for (int k = start + sub; k < end; k += 16) {
    int s = csr[k];
    float4 esv = *(const float4*)&es[s * 4];
    float e0 = leaky(esv.x + edv.x);
    float e1 = leaky(esv.y + edv.y);
    float e2 = leaky(esv.z + edv.z);
    float e3 = leaky(esv.w + edv.w);
    float mn;
    mn = fmaxf(m0, e0); s0 = s0 * __expf(m0 - mn) + __expf(e0 - mn); m0 = mn;
    mn = fmaxf(m1, e1); s1 = s1 * __expf(m1 - mn) + __expf(e1 - mn); m1 = mn;
    mn = fmaxf(m2, e2); s2 = s2 * __expf(m2 - mn) + __expf(e2 - mn); m2 = mn;
    mn = fmaxf(m3, e3); s3 = s3 * __expf(m3 - mn) + __expf(e3 - mn); m3 = mn;
  }
#pragma unroll
  for (int off = 1; off < 16; off <<= 1) {
    float mo, so, mn;
    mo = __shfl_xor(m0, off); so = __shfl_xor(s0, off);
    mn = fmaxf(m0, mo); s0 = s0 * __expf(m0 - mn) + so * __expf(mo - mn); m0 = mn;
    mo = __shfl_xor(m1, off); so = __shfl_xor(s1, off);
    mn = fmaxf(m1, mo); s1 = s1 * __expf(m1 - mn) + so * __expf(mo - mn); m1 = mn;
    mo = __shfl_xor(m2, off); so = __shfl_xor(s2, off);
    mn = fmaxf(m2, mo); s2 = s2 * __expf(m2 - mn) + so * __expf(mo - mn); m2 = mn;
    mo = __shfl_xor(m3, off); so = __shfl_xor(s3, off);
    mn = fmaxf(m3, mo); s3 = s3 * __expf(m3 - mn) + so * __expf(mo - mn); m3 = mn;
  }
  float i0 = 1.f / (s0 + 1e-16f);
  float i1 = 1.f / (s1 + 1e-16f);
  float i2 = 1.f / (s2 + 1e-16f);
  float i3 = 1.f / (s3 + 1e-16f);
  for (int k = start + sub; k < end; k += 16) {
    int s = csr[k];
    float4 esv = *(const float4*)&es[s * 4];
    w1[k]          = __expf(leaky(esv.x + edv.x) - m0) * i0;
    w1[E2 + k]     = __expf(leaky(esv.y + edv.y) - m1) * i1;
    w1[2 * E2 + k] = __expf(leaky(esv.z + edv.z) - m2) * i2;
    w1[3 * E2 + k] = __expf(leaky(esv.w + edv.w) - m3) * i3;
  }
}

// ---------------- softmax stats + edge weights, GAT2 (1 head) ----------------
__global__ __launch_bounds__(256) void k_soft2(const float* __restrict__ es,
                                               const float* __restrict__ ed,
                                               const int* __restrict__ rowptr,
                                               const int* __restrict__ csr,
                                               float* __restrict__ w2) {
  int node = blockIdx.x * 16 + (threadIdx.x >> 4);
  int sub = threadIdx.x & 15;
  int start = rowptr[node], end = rowptr[node + 1];
  float edi = ed[node];
  float m = -1e30f, ss = 0.f;
  for (int k = start + sub; k < end; k += 16) {
    float e = leaky(es[csr[k]] + edi);
    float mn = fmaxf(m, e);
    ss = ss * __expf(m - mn) + __expf(e - mn);
    m = mn;
  }
#pragma unroll
  for (int off = 1; off < 16; off <<= 1) {
    float mo = __shfl_xor(m, off);
    float so = __shfl_xor(ss, off);
    float mn = fmaxf(m, mo);
    ss = ss * __expf(m - mn) + so * __expf(mo - mn);
    m = mn;
  }
  float inv = 1.f / (ss + 1e-16f);
  for (int k = start + sub; k < end; k += 16) {
    float e = leaky(es[csr[k]] + edi);
    w2[k] = __expf(e - m) * inv;
  }
}

// ---------------- GAT1 gather + BN1 stats (bf16 out, conflict-free stats) -------
__global__ __launch_bounds__(256) void k_gat1(const unsigned short* __restrict__ h1b,
                                              const float* __restrict__ w1,
                                              const int* __restrict__ rowptr,
                                              const int* __restrict__ csr,
                                              const float* __restrict__ b1,
                                              unsigned short* __restrict__ outb,
                                              float* __restrict__ st) {
  __shared__ float smS[4][256];
  __shared__ float smQ[4][256];
  int wave = threadIdx.x >> 6;
  int lane = threadIdx.x & 63;
  int i = blockIdx.x * 4 + wave;
  int start = rowptr[i], end = rowptr[i + 1];
  const float* wh = w1 + (size_t)(lane >> 4) * E2;
  float4 acc = make_float4(0.f, 0.f, 0.f, 0.f);
  int k = start;
  for (; k + 4 <= end; k += 4) {
    int sA = csr[k], sB = csr[k + 1], sC = csr[k + 2], sD = csr[k + 3];
    float wA = wh[k], wB = wh[k + 1], wC = wh[k + 2], wD = wh[k + 3];
    ushort4 a0 = *(const ushort4*)&h1b[(size_t)sA * 256 + lane * 4];
    ushort4 a1 = *(const ushort4*)&h1b[(size_t)sB * 256 + lane * 4];
    ushort4 a2 = *(const ushort4*)&h1b[(size_t)sC * 256 + lane * 4];
    ushort4 a3 = *(const ushort4*)&h1b[(size_t)sD * 256 + lane * 4];
    acc.x = fmaf(bf2f(a0.x), wA, fmaf(bf2f(a1.x), wB, fmaf(bf2f(a2.x), wC, fmaf(bf2f(a3.x), wD, acc.x))));
    acc.y = fmaf(bf2f(a0.y), wA, fmaf(bf2f(a1.y), wB, fmaf(bf2f(a2.y), wC, fmaf(bf2f(a3.y), wD, acc.y))));
    acc.z = fmaf(bf2f(a0.z), wA, fmaf(bf2f(a1.z), wB, fmaf(bf2f(a2.z), wC, fmaf(bf2f(a3.z), wD, acc.z))));
    acc.w = fmaf(bf2f(a0.w), wA, fmaf(bf2f(a1.w), wB, fmaf(bf2f(a2.w), wC, fmaf(bf2f(a3.w), wD, acc.w))));
  }
  for (; k < end; ++k) {
    int s = csr[k];
    float wv = wh[k];
    ushort4 a0 = *(const ushort4*)&h1b[(size_t)s * 256 + lane * 4];
    acc.x = fmaf(bf2f(a0.x), wv, acc.x);
    acc.y = fmaf(bf2f(a0.y), wv, acc.y);
    acc.z = fmaf(bf2f(a0.z), wv, acc.z);
    acc.w = fmaf(bf2f(a0.w), wv, acc.w);
  }
  float4 bv = *(const float4*)&b1[lane * 4];
  float4 o;
  o.x = acc.x + bv.x; o.y = acc.y + bv.y; o.z = acc.z + bv.z; o.w = acc.w + bv.w;
  ushort4 u;
  u.x = f2bf(o.x); u.y = f2bf(o.y); u.z = f2bf(o.z); u.w = f2bf(o.w);
  *(ushort4*)&outb[(size_t)i * 256 + lane * 4] = u;
  *(float4*)&smS[wave][lane * 4] = o;
  float4 q = make_float4(o.x * o.x, o.y * o.y, o.z * o.z, o.w * o.w);
  *(float4*)&smQ[wave][lane * 4] = q;
  __syncthreads();
  int c = threadIdx.x;
  float s_ = 0.f, q_ = 0.f;
#pragma unroll
  for (int wv = 0; wv < 4; ++wv) { s_ += smS[wv][c]; q_ += smQ[wv][c]; }
  float* dst = st + (size_t)(blockIdx.x & 31) * 512;
  atomicAdd(&dst[c], s_);
  atomicAdd(&dst[256 + c], q_);
}

// ---------------- GCN gather (hgb pre-scaled by dinv[src]) + BN2 stats ----------
__global__ __launch_bounds__(256) void k_gcn(const unsigned short* __restrict__ hgb,
                                             const float* __restrict__ dinv,
                                             const int* __restrict__ rowptr,
                                             const int* __restrict__ csr,
                                             const float* __restrict__ bg,
                                             float* __restrict__ out,
                                             float* __restrict__ st) {
  __shared__ float2 sm[4][64];
  int wave = threadIdx.x >> 6;
  int lane = threadIdx.x & 63;
  int i = blockIdx.x * 4 + wave;
  int start = rowptr[i], end = rowptr[i + 1];
  float acc = 0.f;
  int k = start;
  for (; k + 4 <= end; k += 4) {
    int sA = csr[k], sB = csr[k + 1], sC = csr[k + 2], sD = csr[k + 3];
    acc += bf2f(hgb[(size_t)sA * 64 + lane]) + bf2f(hgb[(size_t)sB * 64 + lane]) +
           bf2f(hgb[(size_t)sC * 64 + lane]) + bf2f(hgb[(size_t)sD * 64 + lane]);
  }
  for (; k < end; ++k) acc += bf2f(hgb[(size_t)csr[k] * 64 + lane]);
  float o = fmaf(acc, dinv[i], bg[lane]);
  out[(size_t)i * 64 + lane] = o;
  sm[wave][lane] = make_float2(o, o * o);
  __syncthreads();
  if (threadIdx.x < 64) {
    int c = threadIdx.x;
    float s_ = 0.f, q_ = 0.f;
#pragma unroll
    for (int wv = 0; wv < 4; ++wv) { float2 v = sm[wv][c]; s_ += v.x; q_ += v.y; }
    float* dst = st + (size_t)(blockIdx.x & 31) * 128;
    atomicAdd(&dst[c], s_);
    atomicAdd(&dst[64 + c], q_);
  }
}

// ---------------- GAT2 gather + BN3 stats ----------------
__global__ __launch_bounds__(256) void k_gat2(const unsigned short* __restrict__ h2b,
                                              const float* __restrict__ w2,
                                              const int* __restrict__ rowptr,
                                              const int* __restrict__ csr,
                                              const float* __restrict__ b2,
                                              float* __restrict__ out,
                                              float* __restrict__ st) {
  __shared__ float2 sm[4][64];
  int wave = threadIdx.x >> 6;
  int lane = threadIdx.x & 63;
  int i = blockIdx.x * 4 + wave;
  int start = rowptr[i], end = rowptr[i + 1];
  float acc = 0.f;
  int k = start;
  for (; k + 4 <= end; k += 4) {
    int sA = csr[k], sB = csr[k + 1], sC = csr[k + 2], sD = csr[k + 3];
    float wA = w2[k], wB = w2[k + 1], wC = w2[k + 2], wD = w2[k + 3];
    acc = fmaf(bf2f(h2b[(size_t)sA * 64 + lane]), wA,
          fmaf(bf2f(h2b[(size_t)sB * 64 + lane]), wB,
          fmaf(bf2f(h2b[(size_t)sC * 64 + lane]), wC,
          fmaf(bf2f(h2b[(size_t)sD * 64 + lane]), wD, acc))));
  }
  for (; k < end; ++k)
    acc = fmaf(bf2f(h2b[(size_t)csr[k] * 64 + lane]), w2[k], acc);
  float o = acc + b2[lane];
  out[(size_t)i * 64 + lane] = o;
  sm[wave][lane] = make_float2(o, o * o);
  __syncthreads();
  if (threadIdx.x < 64) {
    int c = threadIdx.x;
    float s_ = 0.f, q_ = 0.f;
#pragma unroll
    for (int wv = 0; wv < 4; ++wv) { float2 v = sm[wv][c]; s_ += v.x; q_ += v.y; }
    float* dst = st + (size_t)(blockIdx.x & 31) * 128;
    atomicAdd(&dst[c], s_);
    atomicAdd(&dst[64 + c], q_);
  }
}

// ---------------- host ----------------
extern "C" void kernel_launch(void* const* d_in, const int* in_sizes, int n_in,
                              void* d_out, int out_size, void* d_ws, size_t ws_size,
                              hipStream_t stream) {
  const float* x        = (const float*)d_in[0];
  const int*   ei       = (const int*)d_in[1];
  const float* W1       = (const float*)d_in[3];
  const float* att_src1 = (const float*)d_in[4];
  const float* att_dst1 = (const float*)d_in[5];
  const float* b1       = (const float*)d_in[6];
  const float* g1       = (const float*)d_in[7];
  const float* beta1    = (const float*)d_in[8];
  const float* Wg       = (const float*)d_in[9];
  const float* bg       = (const float*)d_in[10];
  const float* g2       = (const float*)d_in[11];
  const float* beta2    = (const float*)d_in[12];
  const float* W2       = (const float*)d_in[13];
  const float* att_src2 = (const float*)d_in[14];
  const float* att_dst2 = (const float*)d_in[15];
  const float* b2       = (const float*)d_in[16];
  const float* g3       = (const float*)d_in[17];
  const float* beta3    = (const float*)d_in[18];
  const float* Wp1      = (const float*)d_in[19];
  const float* bp1      = (const float*)d_in[20];
  const float* Wp2      = (const float*)d_in[21];
  const float* bp2      = (const float*)d_in[22];
  float* out = (float*)d_out;

  char* w = (char*)d_ws;
  unsigned short* bufBb  = (unsigned short*)(w + 0);           // gat1 out bf16 [N,256]
  float*          bufD   = (float*)(w + 0);                    // gat2 out fp32 [N,64] (alias)
  unsigned short* h1b    = (unsigned short*)(w + 51200000);    // [N,256] bf16
  float*          hidden = (float*)(w + 51200000);             // proj hidden [N,128] (alias)
  float*          w1     = (float*)(w + 76800000);             // [4,E2] f32
  float*          w2     = (float*)(w + 76800000);             // [E2] f32 (alias)
  unsigned short* hgb    = (unsigned short*)(w + 90400000);    // [N,64] bf16 (dinv-scaled)
  float*          bufC   = (float*)(w + 96800000);             // gcn out fp32 [N,64]
  unsigned short* h2b    = (unsigned short*)(w + 109600000);   // [N,64] bf16
  float*          es1    = (float*)(w + 116000000);
  float*          ed1    = (float*)(w + 116800000);
  float*          es2    = (float*)(w + 117600000);
  float*          ed2    = (float*)(w + 117800000);
  float*          dinv   = (float*)(w + 118000000);
  int*            deg    = (int*)(w + 118200000);
  int*            rowptr = (int*)(w + 118400000);
  int*            cnt    = (int*)(w + 118600064);
  int*            csr    = (int*)(w + 118800064);
  float*          st1    = (float*)(w + 122200064);            // 32*512 f32
  float*          st2    = st1 + 32 * 512;                     // 32*128 f32
  float*          st3    = st2 + 32 * 128;                     // 32*128 f32
  int*            partial= (int*)(st3 + 32 * 128);             // SCB ints

  hipMemsetAsync(deg, 0, NN * sizeof(int), stream);
  hipMemsetAsync(st1, 0, (32 * 512 + 32 * 128 + 32 * 128) * sizeof(float), stream);

  const int EB = (E2 + 255) / 256;
  const int WB = NN / 4;          // 12500
  const int SB = NN / 16;         // 3125

  // CSR build
  k_deg<<<EB, 256, 0, stream>>>(ei, deg);
  k_scan1<<<SCB, 256, 0, stream>>>(deg, partial);
  k_scan3<<<SCB, 256, 0, stream>>>(deg, partial, rowptr, cnt, dinv);
  k_fill<<<EB, 256, 0, stream>>>(ei, cnt, csr);

  // GAT1: h1 = x@W1 -> h1b bf16, es1/ed1 fused (4 heads)
  k_gemm_mfma<128, 1, 0, false, false><<<dim3(GXL, 4), 256, 0, stream>>>(
      x, nullptr, W1, nullptr, nullptr, nullptr, nullptr, 0,
      nullptr, h1b, nullptr, att_src1, att_dst1, es1, ed1, NN, 256);
  k_soft1<<<SB, 256, 0, stream>>>(es1, ed1, rowptr, csr, w1);
  k_gat1<<<WB, 256, 0, stream>>>(h1b, w1, rowptr, csr, b1, bufBb, st1);

  // GCN: BN1+ELU fused into A frags; hgb pre-scaled by dinv[row]
  k_gemm_mfma<256, 0, 2, true, true><<<dim3(GXL, 1), 256, 0, stream>>>(
      nullptr, bufBb, Wg, nullptr, st1, g1, beta1, 0,
      nullptr, hgb, dinv, nullptr, nullptr, nullptr, nullptr, NN, 64);
  k_gcn<<<WB, 256, 0, stream>>>(hgb, dinv, rowptr, csr, bg, bufC, st2);

  // GAT2: BN2+ReLU fused; es2/ed2 fused (1 head)
  k_gemm_mfma<64, 2, 1, false, true><<<dim3(GXL, 1), 256, 0, stream>>>(
      bufC, nullptr, W2, nullptr, st2, g2, beta2, 0,
      nullptr, h2b, nullptr, att_src2, att_dst2, es2, ed2, NN, 64);
  k_soft2<<<SB, 256, 0, stream>>>(es2, ed2, rowptr, csr, w2);
  k_gat2<<<WB, 256, 0, stream>>>(h2b, w2, rowptr, csr, b2, bufD, st3);

  // projector: BN3+ELU fused into p1 A-frags, ReLU out
  k_gemm_mfma<64, 0, 2, false, true><<<dim3(GXL, 2), 256, 0, stream>>>(
      bufD, nullptr, Wp1, bp1, st3, g3, beta3, 1,
      hidden, nullptr, nullptr, nullptr, nullptr, nullptr, nullptr, NN, 128);
  k_gemm_mfma<128, 0, 0, false, false><<<dim3(GXL, 1), 256, 0, stream>>>(
      hidden, nullptr, Wp2, bp2, nullptr, nullptr, nullptr, 0,
      out, nullptr, nullptr, nullptr, nullptr, nullptr, nullptr, NN, 64);
}

// Round 8
// 449.997 us; speedup vs baseline: 2.2137x; 1.0788x over previous
//
#include <hip/hip_runtime.h>
#include <math.h>

#define NN 50000
#define EE 800000
#define E2 850000   // EE + NN self loops
#define SCB 196     // ceil(NN/256) scan blocks
#define GXL 391     // ceil(NN/128) gemm row blocks

typedef __attribute__((ext_vector_type(8))) short short8;
typedef __attribute__((ext_vector_type(8))) unsigned short ushort8v;
typedef __attribute__((ext_vector_type(4))) float float4v;

// ---------------- bf16 helpers ----------------
__device__ __forceinline__ float bf2f(unsigned short u) {
  return __uint_as_float(((unsigned int)u) << 16);
}
__device__ __forceinline__ unsigned short f2bf(float f) {
  unsigned int x = __float_as_uint(f);
  unsigned int r = (x + 0x7fffu + ((x >> 16) & 1u)) >> 16;  // RNE
  return (unsigned short)r;
}

__device__ __forceinline__ float leaky(float x) { return x > 0.f ? x : 0.2f * x; }

// ---------------- edge helpers ----------------
__device__ __forceinline__ int edge_src(const int* ei, int e) {
  return (e < EE) ? ei[e] : (e - EE);
}
__device__ __forceinline__ int edge_dst(const int* ei, int e) {
  return (e < EE) ? ei[EE + e] : (e - EE);
}

// ---------------- CSR build ----------------
__global__ void k_deg(const int* __restrict__ ei, int* __restrict__ deg) {
  int e = blockIdx.x * blockDim.x + threadIdx.x;
  if (e < E2) atomicAdd(&deg[edge_dst(ei, e)], 1);
}

__global__ __launch_bounds__(256) void k_scan1(const int* __restrict__ deg,
                                               int* __restrict__ partial) {
  __shared__ int sd[256];
  int i = blockIdx.x * 256 + threadIdx.x;
  sd[threadIdx.x] = (i < NN) ? deg[i] : 0;
  __syncthreads();
  for (int off = 128; off > 0; off >>= 1) {
    if (threadIdx.x < off) sd[threadIdx.x] += sd[threadIdx.x + off];
    __syncthreads();
  }
  if (threadIdx.x == 0) partial[blockIdx.x] = sd[0];
}

__global__ __launch_bounds__(256) void k_scan3(const int* __restrict__ deg,
                                               const int* __restrict__ partial,
                                               int* __restrict__ rowptr,
                                               int* __restrict__ cnt,
                                               float* __restrict__ dinv) {
  __shared__ int sp[256];
  __shared__ int sd[256];
  int t = threadIdx.x;
  sp[t] = (t < SCB) ? partial[t] : 0;
  __syncthreads();
  for (int off = 1; off < 256; off <<= 1) {
    int v = (t >= off) ? sp[t - off] : 0;
    __syncthreads();
    sp[t] += v;
    __syncthreads();
  }
  int base = (blockIdx.x == 0) ? 0 : sp[blockIdx.x - 1];
  int i = blockIdx.x * 256 + t;
  int v = (i < NN) ? deg[i] : 0;
  sd[t] = v;
  __syncthreads();
  for (int off = 1; off < 256; off <<= 1) {
    int u = (t >= off) ? sd[t - off] : 0;
    __syncthreads();
    sd[t] += u;
    __syncthreads();
  }
  if (i < NN) {
    int excl = base + sd[t] - v;
    rowptr[i] = excl;
    cnt[i] = excl;
    dinv[i] = rsqrtf((float)v);
  }
  if (i == 0) rowptr[NN] = E2;
}

__global__ void k_fill(const int* __restrict__ ei, int* __restrict__ cnt,
                       int* __restrict__ csr) {
  int e = blockIdx.x * blockDim.x + threadIdx.x;
  if (e >= E2) return;
  int d = edge_dst(ei, e);
  int s = edge_src(ei, e);
  int pos = atomicAdd(&cnt[d], 1);
  csr[pos] = s;
}

// ---------------- gemm1 specialized: K=128, NC=256, A-frags in regs ----------------
__global__ __launch_bounds__(256) void k_gemm1(
    const float* __restrict__ A, const float* __restrict__ B,
    unsigned short* __restrict__ Cbf,
    const float* __restrict__ attSrc, const float* __restrict__ attDst,
    float* __restrict__ esOut, float* __restrict__ edOut, int M) {
  __shared__ unsigned short BT[64][136];
  int t = threadIdx.x;
  int lane = t & 63;
  int wv = t >> 6;
  int cl = lane & 15;
  int kg = lane >> 4;
  int rowBase = blockIdx.x * 128;

  short8 afr[2][4];
  int grA0 = rowBase + wv * 32 + cl;
#pragma unroll
  for (int rt = 0; rt < 2; ++rt) {
    int gr = grA0 + rt * 16;
#pragma unroll
    for (int ks = 0; ks < 4; ++ks) {
      int k0 = ks * 32 + kg * 8;
      if (gr < M) {
        float4 f0 = *(const float4*)&A[(size_t)gr * 128 + k0];
        float4 f1 = *(const float4*)&A[(size_t)gr * 128 + k0 + 4];
        afr[rt][ks][0] = (short)f2bf(f0.x); afr[rt][ks][1] = (short)f2bf(f0.y);
        afr[rt][ks][2] = (short)f2bf(f0.z); afr[rt][ks][3] = (short)f2bf(f0.w);
        afr[rt][ks][4] = (short)f2bf(f1.x); afr[rt][ks][5] = (short)f2bf(f1.y);
        afr[rt][ks][6] = (short)f2bf(f1.z); afr[rt][ks][7] = (short)f2bf(f1.w);
      } else {
#pragma unroll
        for (int j = 0; j < 8; ++j) afr[rt][ks][j] = 0;
      }
    }
  }

  for (int cg = 0; cg < 4; ++cg) {
    int colBase = cg * 64;
    {
      int c = t & 63;
      for (int k = t >> 6; k < 128; k += 4)
        BT[c][k] = f2bf(B[(size_t)k * 256 + colBase + c]);
    }
    __syncthreads();

    float4v acc[2][4];
#pragma unroll
    for (int rt = 0; rt < 2; ++rt)
#pragma unroll
      for (int ct = 0; ct < 4; ++ct) acc[rt][ct] = (float4v){0.f, 0.f, 0.f, 0.f};

#pragma unroll
    for (int ks = 0; ks < 4; ++ks) {
      int k0 = ks * 32 + kg * 8;
      short8 bfr[4];
#pragma unroll
      for (int ct = 0; ct < 4; ++ct)
        bfr[ct] = *(const short8*)&BT[ct * 16 + cl][k0];
#pragma unroll
      for (int rt = 0; rt < 2; ++rt)
#pragma unroll
        for (int ct = 0; ct < 4; ++ct)
          acc[rt][ct] = __builtin_amdgcn_mfma_f32_16x16x32_bf16(
              afr[rt][ks], bfr[ct], acc[rt][ct], 0, 0, 0);
    }

    float as4[4], ad4[4];
#pragma unroll
    for (int ct = 0; ct < 4; ++ct) {
      int gc = colBase + ct * 16 + cl;
      as4[ct] = attSrc[gc];
      ad4[ct] = attDst[gc];
    }
#pragma unroll
    for (int rt = 0; rt < 2; ++rt) {
      float pes[4] = {0.f, 0.f, 0.f, 0.f};
      float ped[4] = {0.f, 0.f, 0.f, 0.f};
#pragma unroll
      for (int reg = 0; reg < 4; ++reg) {
        int gr = rowBase + wv * 32 + rt * 16 + kg * 4 + reg;
        bool ok = gr < M;
#pragma unroll
        for (int ct = 0; ct < 4; ++ct) {
          float v = acc[rt][ct][reg];
          int gc = colBase + ct * 16 + cl;
          if (ok) Cbf[(size_t)gr * 256 + gc] = f2bf(v);
          pes[reg] = fmaf(v, as4[ct], pes[reg]);
          ped[reg] = fmaf(v, ad4[ct], ped[reg]);
        }
      }
#pragma unroll
      for (int reg = 0; reg < 4; ++reg) {
#pragma unroll
        for (int off = 8; off > 0; off >>= 1) {
          pes[reg] += __shfl_xor(pes[reg], off);
          ped[reg] += __shfl_xor(ped[reg], off);
        }
      }
      if (cl == 0) {
#pragma unroll
        for (int reg = 0; reg < 4; ++reg) {
          int gr = rowBase + wv * 32 + rt * 16 + kg * 4 + reg;
          if (gr < M) {
            esOut[gr * 4 + cg] = pes[reg];
            edOut[gr * 4 + cg] = ped[reg];
          }
        }
      }
    }
    __syncthreads();
  }
}

// ---------------- generic MFMA bf16 GEMM, 128x64 tile ----------------
template <int K, int ATTMODE, int INACT, bool ABF, bool USEBN>
__global__ __launch_bounds__(256) void k_gemm_mfma(
    const float* __restrict__ A, const unsigned short* __restrict__ Abf,
    const float* __restrict__ B, const float* __restrict__ biasOut,
    const float* __restrict__ bnst, const float* __restrict__ bng,
    const float* __restrict__ bnb, int outAct,
    float* __restrict__ Cf, unsigned short* __restrict__ Cbf,
    const float* __restrict__ rowScale,
    const float* __restrict__ attSrc, const float* __restrict__ attDst,
    float* __restrict__ esOut, float* __restrict__ edOut,
    int M, int NC) {
  __shared__ unsigned short BT[64][K + 8];
  __shared__ float sSc[256], sSh[256];
  int t = threadIdx.x;
  int lane = t & 63;
  int wv = t >> 6;
  int cl = lane & 15;
  int kg = lane >> 4;
  int rowBase = blockIdx.x * 128;
  int colBase = blockIdx.y * 64;

  if (USEBN) {
    int c = t;
    if (c < K) {
      float sum = 0.f, sq = 0.f;
      for (int cp = 0; cp < 32; ++cp) {
        sum += bnst[cp * 2 * K + c];
        sq += bnst[cp * 2 * K + K + c];
      }
      const float invN = 1.0f / (float)NN;
      float mu = sum * invN;
      float var = sq * invN - mu * mu;
      float rs = rsqrtf(var + 1e-5f);
      float sc = rs * bng[c];
      sSc[c] = sc;
      sSh[c] = fmaf(-mu, sc, bnb[c]);
    }
  }
  {
    int c = t & 63;
    for (int k = t >> 6; k < K; k += 4)
      BT[c][k] = f2bf(B[(size_t)k * NC + colBase + c]);
  }
  __syncthreads();

  float4v acc[2][4];
#pragma unroll
  for (int rt = 0; rt < 2; ++rt)
#pragma unroll
    for (int ct = 0; ct < 4; ++ct) acc[rt][ct] = (float4v){0.f, 0.f, 0.f, 0.f};

  int grA0 = rowBase + wv * 32 + cl;
  int grA1 = grA0 + 16;

#pragma unroll
  for (int kc = 0; kc < K; kc += 32) {
    int k0 = kc + kg * 8;
    short8 afr[2];
#pragma unroll
    for (int rt = 0; rt < 2; ++rt) {
      int gr = rt ? grA1 : grA0;
      float v[8];
      if (gr < M) {
        if (ABF) {
          ushort4 u0 = *(const ushort4*)&Abf[(size_t)gr * K + k0];
          ushort4 u1 = *(const ushort4*)&Abf[(size_t)gr * K + k0 + 4];
          v[0] = bf2f(u0.x); v[1] = bf2f(u0.y); v[2] = bf2f(u0.z); v[3] = bf2f(u0.w);
          v[4] = bf2f(u1.x); v[5] = bf2f(u1.y); v[6] = bf2f(u1.z); v[7] = bf2f(u1.w);
        } else {
          float4 f0 = *(const float4*)&A[(size_t)gr * K + k0];
          float4 f1 = *(const float4*)&A[(size_t)gr * K + k0 + 4];
          v[0] = f0.x; v[1] = f0.y; v[2] = f0.z; v[3] = f0.w;
          v[4] = f1.x; v[5] = f1.y; v[6] = f1.z; v[7] = f1.w;
        }
      } else {
#pragma unroll
        for (int i = 0; i < 8; ++i) v[i] = 0.f;
      }
#pragma unroll
      for (int i = 0; i < 8; ++i) {
        float x = v[i];
        if (USEBN) x = fmaf(x, sSc[k0 + i], sSh[k0 + i]);
        if (INACT == 1) x = fmaxf(x, 0.f);
        else if (INACT == 2) x = (x > 0.f) ? x : expm1f(x);
        afr[rt][i] = (short)f2bf(x);
      }
    }
    short8 bfr[4];
#pragma unroll
    for (int ct = 0; ct < 4; ++ct)
      bfr[ct] = *(const short8*)&BT[ct * 16 + cl][k0];
#pragma unroll
    for (int rt = 0; rt < 2; ++rt)
#pragma unroll
      for (int ct = 0; ct < 4; ++ct)
        acc[rt][ct] = __builtin_amdgcn_mfma_f32_16x16x32_bf16(
            afr[rt], bfr[ct], acc[rt][ct], 0, 0, 0);
  }

  float bb[4], as4[4], ad4[4];
#pragma unroll
  for (int ct = 0; ct < 4; ++ct) {
    int gc = colBase + ct * 16 + cl;
    bb[ct] = biasOut ? biasOut[gc] : 0.f;
    if (ATTMODE) {
      as4[ct] = attSrc[gc];
      ad4[ct] = attDst[gc];
    }
  }
#pragma unroll
  for (int rt = 0; rt < 2; ++rt) {
    float pes[4] = {0.f, 0.f, 0.f, 0.f};
    float ped[4] = {0.f, 0.f, 0.f, 0.f};
#pragma unroll
    for (int reg = 0; reg < 4; ++reg) {
      int gr = rowBase + wv * 32 + rt * 16 + kg * 4 + reg;
      bool ok = gr < M;
      float rs_ = 1.f;
      if (ok && Cbf && rowScale) rs_ = rowScale[gr];
#pragma unroll
      for (int ct = 0; ct < 4; ++ct) {
        float v = acc[rt][ct][reg] + bb[ct];
        if (outAct == 1) v = fmaxf(v, 0.f);
        int gc = colBase + ct * 16 + cl;
        if (ok) {
          if (Cf) Cf[(size_t)gr * NC + gc] = v;
          if (Cbf) Cbf[(size_t)gr * NC + gc] = f2bf(v * rs_);
        }
        if (ATTMODE) {
          pes[reg] = fmaf(v, as4[ct], pes[reg]);
          ped[reg] = fmaf(v, ad4[ct], ped[reg]);
        }
      }
    }
    if (ATTMODE) {
#pragma unroll
      for (int reg = 0; reg < 4; ++reg) {
#pragma unroll
        for (int off = 8; off > 0; off >>= 1) {
          pes[reg] += __shfl_xor(pes[reg], off);
          ped[reg] += __shfl_xor(ped[reg], off);
        }
      }
      if (cl == 0) {
#pragma unroll
        for (int reg = 0; reg < 4; ++reg) {
          int gr = rowBase + wv * 32 + rt * 16 + kg * 4 + reg;
          if (gr < M) {
            if (ATTMODE == 1) {
              esOut[gr * 4 + blockIdx.y] = pes[reg];
              edOut[gr * 4 + blockIdx.y] = ped[reg];
            } else {
              esOut[gr] = pes[reg];
              edOut[gr] = ped[reg];
            }
          }
        }
      }
    }
  }
}

// ---------------- softmax stats + edge weights, GAT1 (4 heads) ----------------
__global__ __launch_bounds__(256) void k_soft1(const float* __restrict__ es,
                                               const float* __restrict__ ed,
                                               const int* __restrict__ rowptr,
                                               const int* __restrict__ csr,
                                               float* __restrict__ w1) {
  int node = blockIdx.x * 16 + (threadIdx.x >> 4);
  int sub = threadIdx.x & 15;
  int start = rowptr[node], end = rowptr[node + 1];
  float4 edv = *(const float4*)&ed[node * 4];
  float m0 = -1e30f, m1 = -1e30f, m2 = -1e30f, m3 = -1e30f;
  float s0 = 0.f, s1 = 0.f, s2 = 0.f, s3 = 0.f;
  for (int k = start + sub; k < end; k += 16) {
    int s = csr[k];
    float4 esv = *(const float4*)&es[s * 4];
    float e0 = leaky(esv.x + edv.x);
    float e1 = leaky(esv.y + edv.y);
    float e2 = leaky(esv.z + edv.z);
    float e3 = leaky(esv.w + edv.w);
    float mn;
    mn = fmaxf(m0, e0); s0 = s0 * __expf(m0 - mn) + __expf(e0 - mn); m0 = mn;
    mn = fmaxf(m1, e1); s1 = s1 * __expf(m1 - mn) + __expf(e1 - mn); m1 = mn;
    mn = fmaxf(m2, e2); s2 = s2 * __expf(m2 - mn) + __expf(e2 - mn); m2 = mn;
    mn = fmaxf(m3, e3); s3 = s3 * __expf(m3 - mn) + __expf(e3 - mn); m3 = mn;
  }
#pragma unroll
  for (int off = 1; off < 16; off <<= 1) {
    float mo, so, mn;
    mo = __shfl_xor(m0, off); so = __shfl_xor(s0, off);
    mn = fmaxf(m0, mo); s0 = s0 * __expf(m0 - mn) + so * __expf(mo - mn); m0 = mn;
    mo = __shfl_xor(m1, off); so = __shfl_xor(s1, off);
    mn = fmaxf(m1, mo); s1 = s1 * __expf(m1 - mn) + so * __expf(mo - mn); m1 = mn;
    mo = __shfl_xor(m2, off); so = __shfl_xor(s2, off);
    mn = fmaxf(m2, mo); s2 = s2 * __expf(m2 - mn) + so * __expf(mo - mn); m2 = mn;
    mo = __shfl_xor(m3, off); so = __shfl_xor(s3, off);
    mn = fmaxf(m3, mo); s3 = s3 * __expf(m3 - mn) + so * __expf(mo - mn); m3 = mn;
  }
  float i0 = 1.f / (s0 + 1e-16f);
  float i1 = 1.f / (s1 + 1e-16f);
  float i2 = 1.f / (s2 + 1e-16f);
  float i3 = 1.f / (s3 + 1e-16f);
  for (int k = start + sub; k < end; k += 16) {
    int s = csr[k];
    float4 esv = *(const float4*)&es[s * 4];
    w1[k]          = __expf(leaky(esv.x + edv.x) - m0) * i0;
    w1[E2 + k]     = __expf(leaky(esv.y + edv.y) - m1) * i1;
    w1[2 * E2 + k] = __expf(leaky(esv.z + edv.z) - m2) * i2;
    w1[3 * E2 + k] = __expf(leaky(esv.w + edv.w) - m3) * i3;
  }
}

// ---------------- softmax stats + edge weights, GAT2 (1 head) ----------------
__global__ __launch_bounds__(256) void k_soft2(const float* __restrict__ es,
                                               const float* __restrict__ ed,
                                               const int* __restrict__ rowptr,
                                               const int* __restrict__ csr,
                                               float* __restrict__ w2) {
  int node = blockIdx.x * 16 + (threadIdx.x >> 4);
  int sub = threadIdx.x & 15;
  int start = rowptr[node], end = rowptr[node + 1];
  float edi = ed[node];
  float m = -1e30f, ss = 0.f;
  for (int k = start + sub; k < end; k += 16) {
    float e = leaky(es[csr[k]] + edi);
    float mn = fmaxf(m, e);
    ss = ss * __expf(m - mn) + __expf(e - mn);
    m = mn;
  }
#pragma unroll
  for (int off = 1; off < 16; off <<= 1) {
    float mo = __shfl_xor(m, off);
    float so = __shfl_xor(ss, off);
    float mn = fmaxf(m, mo);
    ss = ss * __expf(m - mn) + so * __expf(mo - mn);
    m = mn;
  }
  float inv = 1.f / (ss + 1e-16f);
  for (int k = start + sub; k < end; k += 16) {
    float e = leaky(es[csr[k]] + edi);
    w2[k] = __expf(e - m) * inv;
  }
}

// ---------------- GAT1 gather: 2 edges/wave-step, ushort8 ----------------
__global__ __launch_bounds__(256) void k_gat1(const unsigned short* __restrict__ h1b,
                                              const float* __restrict__ w1,
                                              const int* __restrict__ rowptr,
                                              const int* __restrict__ csr,
                                              const float* __restrict__ b1,
                                              unsigned short* __restrict__ outb,
                                              float* __restrict__ st) {
  __shared__ float smS[4][256];
  __shared__ float smQ[4][256];
  int wave = threadIdx.x >> 6;
  int lane = threadIdx.x & 63;
  int i = blockIdx.x * 4 + wave;
  int start = rowptr[i], end = rowptr[i + 1];
  int half = lane >> 5;
  int cl5 = lane & 31;
  int head = cl5 >> 3;
  int cOff = cl5 * 8;
  const float* wh = w1 + (size_t)head * E2;
  float acc[8];
#pragma unroll
  for (int j = 0; j < 8; ++j) acc[j] = 0.f;

  int k = start;
  for (; k + 4 <= end; k += 4) {
#pragma unroll
    for (int u = 0; u < 2; ++u) {
      int kk = k + u * 2 + half;
      int s = csr[kk];
      float wv = wh[kk];
      ushort8v hv = *(const ushort8v*)&h1b[(size_t)s * 256 + cOff];
#pragma unroll
      for (int j = 0; j < 8; ++j) acc[j] = fmaf(bf2f(hv[j]), wv, acc[j]);
    }
  }
  for (; k + 2 <= end; k += 2) {
    int kk = k + half;
    int s = csr[kk];
    float wv = wh[kk];
    ushort8v hv = *(const ushort8v*)&h1b[(size_t)s * 256 + cOff];
#pragma unroll
    for (int j = 0; j < 8; ++j) acc[j] = fmaf(bf2f(hv[j]), wv, acc[j]);
  }
  if (k < end) {
    int s = csr[k];
    float wv = (half == 0) ? wh[k] : 0.f;
    ushort8v hv = *(const ushort8v*)&h1b[(size_t)s * 256 + cOff];
#pragma unroll
    for (int j = 0; j < 8; ++j) acc[j] = fmaf(bf2f(hv[j]), wv, acc[j]);
  }
#pragma unroll
  for (int j = 0; j < 8; ++j) acc[j] += __shfl_xor(acc[j], 32);

  float4 b0 = *(const float4*)&b1[cOff];
  float4 b1v = *(const float4*)&b1[cOff + 4];
  float bb[8] = {b0.x, b0.y, b0.z, b0.w, b1v.x, b1v.y, b1v.z, b1v.w};
  if (half == 0) {
    float o[8];
    ushort8v u8;
#pragma unroll
    for (int j = 0; j < 8; ++j) {
      o[j] = acc[j] + bb[j];
      u8[j] = f2bf(o[j]);
    }
    *(ushort8v*)&outb[(size_t)i * 256 + cOff] = u8;
    float4 s0 = make_float4(o[0], o[1], o[2], o[3]);
    float4 s1 = make_float4(o[4], o[5], o[6], o[7]);
    *(float4*)&smS[wave][cOff] = s0;
    *(float4*)&smS[wave][cOff + 4] = s1;
    float4 q0 = make_float4(o[0]*o[0], o[1]*o[1], o[2]*o[2], o[3]*o[3]);
    float4 q1 = make_float4(o[4]*o[4], o[5]*o[5], o[6]*o[6], o[7]*o[7]);
    *(float4*)&smQ[wave][cOff] = q0;
    *(float4*)&smQ[wave][cOff + 4] = q1;
  }
  __syncthreads();
  int c = threadIdx.x;
  float s_ = 0.f, q_ = 0.f;
#pragma unroll
  for (int wv = 0; wv < 4; ++wv) { s_ += smS[wv][c]; q_ += smQ[wv][c]; }
  float* dst = st + (size_t)(blockIdx.x & 31) * 512;
  atomicAdd(&dst[c], s_);
  atomicAdd(&dst[256 + c], q_);
}

// ---------------- GCN gather: 8 edges/wave-step, ushort8; bf16 out ----------------
__global__ __launch_bounds__(256) void k_gcn(const unsigned short* __restrict__ hgb,
                                             const float* __restrict__ dinv,
                                             const int* __restrict__ rowptr,
                                             const int* __restrict__ csr,
                                             const float* __restrict__ bg,
                                             unsigned short* __restrict__ outb,
                                             float* __restrict__ st) {
  __shared__ float smS[4][64];
  __shared__ float smQ[4][64];
  int wave = threadIdx.x >> 6;
  int lane = threadIdx.x & 63;
  int i = blockIdx.x * 4 + wave;
  int start = rowptr[i], end = rowptr[i + 1];
  int grp = lane >> 3;
  int cOff = (lane & 7) * 8;
  float acc[8];
#pragma unroll
  for (int j = 0; j < 8; ++j) acc[j] = 0.f;

  int k = start;
  for (; k + 8 <= end; k += 8) {
    int s = csr[k + grp];
    ushort8v hv = *(const ushort8v*)&hgb[(size_t)s * 64 + cOff];
#pragma unroll
    for (int j = 0; j < 8; ++j) acc[j] += bf2f(hv[j]);
  }
  if (k < end) {
    int kk = k + grp;
    bool act = kk < end;
    int s = csr[act ? kk : start];
    float m_ = act ? 1.f : 0.f;
    ushort8v hv = *(const ushort8v*)&hgb[(size_t)s * 64 + cOff];
#pragma unroll
    for (int j = 0; j < 8; ++j) acc[j] = fmaf(bf2f(hv[j]), m_, acc[j]);
  }
#pragma unroll
  for (int off = 8; off <= 32; off <<= 1)
#pragma unroll
    for (int j = 0; j < 8; ++j) acc[j] += __shfl_xor(acc[j], off);

  if (lane < 8) {
    float di = dinv[i];
    float4 g0 = *(const float4*)&bg[cOff];
    float4 g1 = *(const float4*)&bg[cOff + 4];
    float bb[8] = {g0.x, g0.y, g0.z, g0.w, g1.x, g1.y, g1.z, g1.w};
    float o[8];
    ushort8v u8;
#pragma unroll
    for (int j = 0; j < 8; ++j) {
      o[j] = fmaf(acc[j], di, bb[j]);
      u8[j] = f2bf(o[j]);
      smS[wave][cOff + j] = o[j];
      smQ[wave][cOff + j] = o[j] * o[j];
    }
    *(ushort8v*)&outb[(size_t)i * 64 + cOff] = u8;
  }
  __syncthreads();
  if (threadIdx.x < 64) {
    int c = threadIdx.x;
    float s_ = 0.f, q_ = 0.f;
#pragma unroll
    for (int wv = 0; wv < 4; ++wv) { s_ += smS[wv][c]; q_ += smQ[wv][c]; }
    float* dst = st + (size_t)(blockIdx.x & 31) * 128;
    atomicAdd(&dst[c], s_);
    atomicAdd(&dst[64 + c], q_);
  }
}

// ---------------- GAT2 gather: 8 edges/wave-step, ushort8; bf16 out ----------------
__global__ __launch_bounds__(256) void k_gat2(const unsigned short* __restrict__ h2b,
                                              const float* __restrict__ w2,
                                              const int* __restrict__ rowptr,
                                              const int* __restrict__ csr,
                                              const float* __restrict__ b2,
                                              unsigned short* __restrict__ outb,
                                              float* __restrict__ st) {
  __shared__ float smS[4][64];
  __shared__ float smQ[4][64];
  int wave = threadIdx.x >> 6;
  int lane = threadIdx.x & 63;
  int i = blockIdx.x * 4 + wave;
  int start = rowptr[i], end = rowptr[i + 1];
  int grp = lane >> 3;
  int cOff = (lane & 7) * 8;
  float acc[8];
#pragma unroll
  for (int j = 0; j < 8; ++j) acc[j] = 0.f;

  int k = start;
  for (; k + 8 <= end; k += 8) {
    int kk = k + grp;
    int s = csr[kk];
    float wv = w2[kk];
    ushort8v hv = *(const ushort8v*)&h2b[(size_t)s * 64 + cOff];
#pragma unroll
    for (int j = 0; j < 8; ++j) acc[j] = fmaf(bf2f(hv[j]), wv, acc[j]);
  }
  if (k < end) {
    int kk = k + grp;
    bool act = kk < end;
    int s = csr[act ? kk : start];
    float wv = act ? w2[kk] : 0.f;
    ushort8v hv = *(const ushort8v*)&h2b[(size_t)s * 64 + cOff];
#pragma unroll
    for (int j = 0; j < 8; ++j) acc[j] = fmaf(bf2f(hv[j]), wv, acc[j]);
  }
#pragma unroll
  for (int off = 8; off <= 32; off <<= 1)
#pragma unroll
    for (int j = 0; j < 8; ++j) acc[j] += __shfl_xor(acc[j], off);

  if (lane < 8) {
    float4 g0 = *(const float4*)&b2[cOff];
    float4 g1 = *(const float4*)&b2[cOff + 4];
    float bb[8] = {g0.x, g0.y, g0.z, g0.w, g1.x, g1.y, g1.z, g1.w};
    float o[8];
    ushort8v u8;
#pragma unroll
    for (int j = 0; j < 8; ++j) {
      o[j] = acc[j] + bb[j];
      u8[j] = f2bf(o[j]);
      smS[wave][cOff + j] = o[j];
      smQ[wave][cOff + j] = o[j] * o[j];
    }
    *(ushort8v*)&outb[(size_t)i * 64 + cOff] = u8;
  }
  __syncthreads();
  if (threadIdx.x < 64) {
    int c = threadIdx.x;
    float s_ = 0.f, q_ = 0.f;
#pragma unroll
    for (int wv = 0; wv < 4; ++wv) { s_ += smS[wv][c]; q_ += smQ[wv][c]; }
    float* dst = st + (size_t)(blockIdx.x & 31) * 128;
    atomicAdd(&dst[c], s_);
    atomicAdd(&dst[64 + c], q_);
  }
}

// ---------------- host ----------------
extern "C" void kernel_launch(void* const* d_in, const int* in_sizes, int n_in,
                              void* d_out, int out_size, void* d_ws, size_t ws_size,
                              hipStream_t stream) {
  const float* x        = (const float*)d_in[0];
  const int*   ei       = (const int*)d_in[1];
  const float* W1       = (const float*)d_in[3];
  const float* att_src1 = (const float*)d_in[4];
  const float* att_dst1 = (const float*)d_in[5];
  const float* b1       = (const float*)d_in[6];
  const float* g1       = (const float*)d_in[7];
  const float* beta1    = (const float*)d_in[8];
  const float* Wg       = (const float*)d_in[9];
  const float* bg       = (const float*)d_in[10];
  const float* g2       = (const float*)d_in[11];
  const float* beta2    = (const float*)d_in[12];
  const float* W2       = (const float*)d_in[13];
  const float* att_src2 = (const float*)d_in[14];
  const float* att_dst2 = (const float*)d_in[15];
  const float* b2       = (const float*)d_in[16];
  const float* g3       = (const float*)d_in[17];
  const float* beta3    = (const float*)d_in[18];
  const float* Wp1      = (const float*)d_in[19];
  const float* bp1      = (const float*)d_in[20];
  const float* Wp2      = (const float*)d_in[21];
  const float* bp2      = (const float*)d_in[22];
  float* out = (float*)d_out;

  char* w = (char*)d_ws;
  unsigned short* bufBb  = (unsigned short*)(w + 0);           // gat1 out bf16 [N,256]
  unsigned short* bufDb  = (unsigned short*)(w + 0);           // gat2 out bf16 [N,64] (alias; bufBb dead)
  unsigned short* h1b    = (unsigned short*)(w + 51200000);    // [N,256] bf16
  unsigned short* hiddenb= (unsigned short*)(w + 51200000);    // proj hidden bf16 [N,128] (alias; h1b dead)
  float*          w1     = (float*)(w + 76800000);             // [4,E2] f32
  float*          w2     = (float*)(w + 76800000);             // [E2] f32 (alias)
  unsigned short* hgb    = (unsigned short*)(w + 90400000);    // [N,64] bf16 (dinv-scaled)
  unsigned short* bufCb  = (unsigned short*)(w + 96800000);    // gcn out bf16 [N,64]
  unsigned short* h2b    = (unsigned short*)(w + 109600000);   // [N,64] bf16
  float*          es1    = (float*)(w + 116000000);
  float*          ed1    = (float*)(w + 116800000);
  float*          es2    = (float*)(w + 117600000);
  float*          ed2    = (float*)(w + 117800000);
  float*          dinv   = (float*)(w + 118000000);
  int*            deg    = (int*)(w + 118200000);
  int*            rowptr = (int*)(w + 118400000);
  int*            cnt    = (int*)(w + 118600064);
  int*            csr    = (int*)(w + 118800064);
  float*          st1    = (float*)(w + 122200064);            // 32*512 f32
  float*          st2    = st1 + 32 * 512;                     // 32*128 f32
  float*          st3    = st2 + 32 * 128;                     // 32*128 f32
  int*            partial= (int*)(st3 + 32 * 128);             // SCB ints

  hipMemsetAsync(deg, 0, NN * sizeof(int), stream);
  hipMemsetAsync(st1, 0, (32 * 512 + 32 * 128 + 32 * 128) * sizeof(float), stream);

  const int EB = (E2 + 255) / 256;
  const int WB = NN / 4;          // 12500
  const int SB = NN / 16;         // 3125

  // CSR build
  k_deg<<<EB, 256, 0, stream>>>(ei, deg);
  k_scan1<<<SCB, 256, 0, stream>>>(deg, partial);
  k_scan3<<<SCB, 256, 0, stream>>>(deg, partial, rowptr, cnt, dinv);
  k_fill<<<EB, 256, 0, stream>>>(ei, cnt, csr);

  // GAT1: h1 = x@W1 -> h1b bf16, es1/ed1 fused (A-frags in regs, x read once)
  k_gemm1<<<GXL, 256, 0, stream>>>(x, W1, h1b, att_src1, att_dst1, es1, ed1, NN);
  k_soft1<<<SB, 256, 0, stream>>>(es1, ed1, rowptr, csr, w1);
  k_gat1<<<WB, 256, 0, stream>>>(h1b, w1, rowptr, csr, b1, bufBb, st1);

  // GCN: BN1+ELU fused into A frags; hgb pre-scaled by dinv[row]
  k_gemm_mfma<256, 0, 2, true, true><<<dim3(GXL, 1), 256, 0, stream>>>(
      nullptr, bufBb, Wg, nullptr, st1, g1, beta1, 0,
      nullptr, hgb, dinv, nullptr, nullptr, nullptr, nullptr, NN, 64);
  k_gcn<<<WB, 256, 0, stream>>>(hgb, dinv, rowptr, csr, bg, bufCb, st2);

  // GAT2: BN2+ReLU fused; es2/ed2 fused (1 head)
  k_gemm_mfma<64, 2, 1, true, true><<<dim3(GXL, 1), 256, 0, stream>>>(
      nullptr, bufCb, W2, nullptr, st2, g2, beta2, 0,
      nullptr, h2b, nullptr, att_src2, att_dst2, es2, ed2, NN, 64);
  k_soft2<<<SB, 256, 0, stream>>>(es2, ed2, rowptr, csr, w2);
  k_gat2<<<WB, 256, 0, stream>>>(h2b, w2, rowptr, csr, b2, bufDb, st3);

  // projector: BN3+ELU fused into p1 A-frags, ReLU out -> hiddenb bf16
  // NC=128 -> TWO column blocks (this was the round-7 bug: grid y was 1)
  k_gemm_mfma<64, 0, 2, true, true><<<dim3(GXL, 2), 256, 0, stream>>>(
      nullptr, bufDb, Wp1, bp1, st3, g3, beta3, 1,
      nullptr, hiddenb, nullptr, nullptr, nullptr, nullptr, nullptr, NN, 128);
  k_gemm_mfma<128, 0, 0, true, false><<<dim3(GXL, 1), 256, 0, stream>>>(
      nullptr, hiddenb, Wp2, bp2, nullptr, nullptr, nullptr, 0,
      out, nullptr, nullptr, nullptr, nullptr, nullptr, nullptr, NN, 64);
}

// Round 9
// 439.224 us; speedup vs baseline: 2.2680x; 1.0245x over previous
//
#include <hip/hip_runtime.h>
#include <math.h>

#define NN 50000
#define EE 800000
#define E2 850000   // EE + NN self loops
#define SCB 196     // ceil(NN/256) scan blocks
#define GXL 391     // ceil(NN/128) gemm row blocks

typedef __attribute__((ext_vector_type(8))) short short8;
typedef __attribute__((ext_vector_type(8))) unsigned short ushort8v;
typedef __attribute__((ext_vector_type(4))) float float4v;

// ---------------- bf16 helpers ----------------
__device__ __forceinline__ float bf2f(unsigned short u) {
  return __uint_as_float(((unsigned int)u) << 16);
}
__device__ __forceinline__ unsigned short f2bf(float f) {
  unsigned int x = __float_as_uint(f);
  unsigned int r = (x + 0x7fffu + ((x >> 16) & 1u)) >> 16;  // RNE
  return (unsigned short)r;
}

__device__ __forceinline__ float leaky(float x) { return x > 0.f ? x : 0.2f * x; }

// ---------------- edge helpers ----------------
__device__ __forceinline__ int edge_src(const int* ei, int e) {
  return (e < EE) ? ei[e] : (e - EE);
}
__device__ __forceinline__ int edge_dst(const int* ei, int e) {
  return (e < EE) ? ei[EE + e] : (e - EE);
}

// ---------------- CSR build ----------------
__global__ void k_deg(const int* __restrict__ ei, int* __restrict__ deg) {
  int e = blockIdx.x * blockDim.x + threadIdx.x;
  if (e < E2) atomicAdd(&deg[edge_dst(ei, e)], 1);
}

__global__ __launch_bounds__(256) void k_scan1(const int* __restrict__ deg,
                                               int* __restrict__ partial) {
  __shared__ int sd[256];
  int i = blockIdx.x * 256 + threadIdx.x;
  sd[threadIdx.x] = (i < NN) ? deg[i] : 0;
  __syncthreads();
  for (int off = 128; off > 0; off >>= 1) {
    if (threadIdx.x < off) sd[threadIdx.x] += sd[threadIdx.x + off];
    __syncthreads();
  }
  if (threadIdx.x == 0) partial[blockIdx.x] = sd[0];
}

__global__ __launch_bounds__(256) void k_scan3(const int* __restrict__ deg,
                                               const int* __restrict__ partial,
                                               int* __restrict__ rowptr,
                                               int* __restrict__ cnt,
                                               float* __restrict__ dinv) {
  __shared__ int sp[256];
  __shared__ int sd[256];
  int t = threadIdx.x;
  sp[t] = (t < SCB) ? partial[t] : 0;
  __syncthreads();
  for (int off = 1; off < 256; off <<= 1) {
    int v = (t >= off) ? sp[t - off] : 0;
    __syncthreads();
    sp[t] += v;
    __syncthreads();
  }
  int base = (blockIdx.x == 0) ? 0 : sp[blockIdx.x - 1];
  int i = blockIdx.x * 256 + t;
  int v = (i < NN) ? deg[i] : 0;
  sd[t] = v;
  __syncthreads();
  for (int off = 1; off < 256; off <<= 1) {
    int u = (t >= off) ? sd[t - off] : 0;
    __syncthreads();
    sd[t] += u;
    __syncthreads();
  }
  if (i < NN) {
    int excl = base + sd[t] - v;
    rowptr[i] = excl;
    cnt[i] = excl;
    dinv[i] = rsqrtf((float)v);
  }
  if (i == 0) rowptr[NN] = E2;
}

__global__ void k_fill(const int* __restrict__ ei, int* __restrict__ cnt,
                       int* __restrict__ csr) {
  int e = blockIdx.x * blockDim.x + threadIdx.x;
  if (e >= E2) return;
  int d = edge_dst(ei, e);
  int s = edge_src(ei, e);
  int pos = atomicAdd(&cnt[d], 1);
  csr[pos] = s;
}

// ---------------- gemm1 specialized: K=128, NC=256, A-frags in regs ----------------
__global__ __launch_bounds__(256) void k_gemm1(
    const float* __restrict__ A, const float* __restrict__ B,
    unsigned short* __restrict__ Cbf,
    const float* __restrict__ attSrc, const float* __restrict__ attDst,
    float* __restrict__ esOut, float* __restrict__ edOut, int M) {
  __shared__ unsigned short BT[64][136];
  int t = threadIdx.x;
  int lane = t & 63;
  int wv = t >> 6;
  int cl = lane & 15;
  int kg = lane >> 4;
  int rowBase = blockIdx.x * 128;

  short8 afr[2][4];
  int grA0 = rowBase + wv * 32 + cl;
#pragma unroll
  for (int rt = 0; rt < 2; ++rt) {
    int gr = grA0 + rt * 16;
#pragma unroll
    for (int ks = 0; ks < 4; ++ks) {
      int k0 = ks * 32 + kg * 8;
      if (gr < M) {
        float4 f0 = *(const float4*)&A[(size_t)gr * 128 + k0];
        float4 f1 = *(const float4*)&A[(size_t)gr * 128 + k0 + 4];
        afr[rt][ks][0] = (short)f2bf(f0.x); afr[rt][ks][1] = (short)f2bf(f0.y);
        afr[rt][ks][2] = (short)f2bf(f0.z); afr[rt][ks][3] = (short)f2bf(f0.w);
        afr[rt][ks][4] = (short)f2bf(f1.x); afr[rt][ks][5] = (short)f2bf(f1.y);
        afr[rt][ks][6] = (short)f2bf(f1.z); afr[rt][ks][7] = (short)f2bf(f1.w);
      } else {
#pragma unroll
        for (int j = 0; j < 8; ++j) afr[rt][ks][j] = 0;
      }
    }
  }

  for (int cg = 0; cg < 4; ++cg) {
    int colBase = cg * 64;
    {
      int c = t & 63;
      for (int k = t >> 6; k < 128; k += 4)
        BT[c][k] = f2bf(B[(size_t)k * 256 + colBase + c]);
    }
    __syncthreads();

    float4v acc[2][4];
#pragma unroll
    for (int rt = 0; rt < 2; ++rt)
#pragma unroll
      for (int ct = 0; ct < 4; ++ct) acc[rt][ct] = (float4v){0.f, 0.f, 0.f, 0.f};

#pragma unroll
    for (int ks = 0; ks < 4; ++ks) {
      int k0 = ks * 32 + kg * 8;
      short8 bfr[4];
#pragma unroll
      for (int ct = 0; ct < 4; ++ct)
        bfr[ct] = *(const short8*)&BT[ct * 16 + cl][k0];
#pragma unroll
      for (int rt = 0; rt < 2; ++rt)
#pragma unroll
        for (int ct = 0; ct < 4; ++ct)
          acc[rt][ct] = __builtin_amdgcn_mfma_f32_16x16x32_bf16(
              afr[rt][ks], bfr[ct], acc[rt][ct], 0, 0, 0);
    }

    float as4[4], ad4[4];
#pragma unroll
    for (int ct = 0; ct < 4; ++ct) {
      int gc = colBase + ct * 16 + cl;
      as4[ct] = attSrc[gc];
      ad4[ct] = attDst[gc];
    }
#pragma unroll
    for (int rt = 0; rt < 2; ++rt) {
      float pes[4] = {0.f, 0.f, 0.f, 0.f};
      float ped[4] = {0.f, 0.f, 0.f, 0.f};
#pragma unroll
      for (int reg = 0; reg < 4; ++reg) {
        int gr = rowBase + wv * 32 + rt * 16 + kg * 4 + reg;
        bool ok = gr < M;
#pragma unroll
        for (int ct = 0; ct < 4; ++ct) {
          float v = acc[rt][ct][reg];
          int gc = colBase + ct * 16 + cl;
          if (ok) Cbf[(size_t)gr * 256 + gc] = f2bf(v);
          pes[reg] = fmaf(v, as4[ct], pes[reg]);
          ped[reg] = fmaf(v, ad4[ct], ped[reg]);
        }
      }
#pragma unroll
      for (int reg = 0; reg < 4; ++reg) {
#pragma unroll
        for (int off = 8; off > 0; off >>= 1) {
          pes[reg] += __shfl_xor(pes[reg], off);
          ped[reg] += __shfl_xor(ped[reg], off);
        }
      }
      if (cl == 0) {
#pragma unroll
        for (int reg = 0; reg < 4; ++reg) {
          int gr = rowBase + wv * 32 + rt * 16 + kg * 4 + reg;
          if (gr < M) {
            esOut[gr * 4 + cg] = pes[reg];
            edOut[gr * 4 + cg] = ped[reg];
          }
        }
      }
    }
    __syncthreads();
  }
}

// ---------------- generic MFMA bf16 GEMM, 128x64 tile ----------------
template <int K, int ATTMODE, int INACT, bool ABF, bool USEBN>
__global__ __launch_bounds__(256) void k_gemm_mfma(
    const float* __restrict__ A, const unsigned short* __restrict__ Abf,
    const float* __restrict__ B, const float* __restrict__ biasOut,
    const float* __restrict__ bnst, const float* __restrict__ bng,
    const float* __restrict__ bnb, int outAct,
    float* __restrict__ Cf, unsigned short* __restrict__ Cbf,
    const float* __restrict__ rowScale,
    const float* __restrict__ attSrc, const float* __restrict__ attDst,
    float* __restrict__ esOut, float* __restrict__ edOut,
    int M, int NC) {
  __shared__ unsigned short BT[64][K + 8];
  __shared__ float sSc[256], sSh[256];
  int t = threadIdx.x;
  int lane = t & 63;
  int wv = t >> 6;
  int cl = lane & 15;
  int kg = lane >> 4;
  int rowBase = blockIdx.x * 128;
  int colBase = blockIdx.y * 64;

  if (USEBN) {
    int c = t;
    if (c < K) {
      float sum = 0.f, sq = 0.f;
      for (int cp = 0; cp < 32; ++cp) {
        sum += bnst[cp * 2 * K + c];
        sq += bnst[cp * 2 * K + K + c];
      }
      const float invN = 1.0f / (float)NN;
      float mu = sum * invN;
      float var = sq * invN - mu * mu;
      float rs = rsqrtf(var + 1e-5f);
      float sc = rs * bng[c];
      sSc[c] = sc;
      sSh[c] = fmaf(-mu, sc, bnb[c]);
    }
  }
  {
    int c = t & 63;
    for (int k = t >> 6; k < K; k += 4)
      BT[c][k] = f2bf(B[(size_t)k * NC + colBase + c]);
  }
  __syncthreads();

  float4v acc[2][4];
#pragma unroll
  for (int rt = 0; rt < 2; ++rt)
#pragma unroll
    for (int ct = 0; ct < 4; ++ct) acc[rt][ct] = (float4v){0.f, 0.f, 0.f, 0.f};

  int grA0 = rowBase + wv * 32 + cl;
  int grA1 = grA0 + 16;

#pragma unroll
  for (int kc = 0; kc < K; kc += 32) {
    int k0 = kc + kg * 8;
    short8 afr[2];
#pragma unroll
    for (int rt = 0; rt < 2; ++rt) {
      int gr = rt ? grA1 : grA0;
      float v[8];
      if (gr < M) {
        if (ABF) {
          ushort4 u0 = *(const ushort4*)&Abf[(size_t)gr * K + k0];
          ushort4 u1 = *(const ushort4*)&Abf[(size_t)gr * K + k0 + 4];
          v[0] = bf2f(u0.x); v[1] = bf2f(u0.y); v[2] = bf2f(u0.z); v[3] = bf2f(u0.w);
          v[4] = bf2f(u1.x); v[5] = bf2f(u1.y); v[6] = bf2f(u1.z); v[7] = bf2f(u1.w);
        } else {
          float4 f0 = *(const float4*)&A[(size_t)gr * K + k0];
          float4 f1 = *(const float4*)&A[(size_t)gr * K + k0 + 4];
          v[0] = f0.x; v[1] = f0.y; v[2] = f0.z; v[3] = f0.w;
          v[4] = f1.x; v[5] = f1.y; v[6] = f1.z; v[7] = f1.w;
        }
      } else {
#pragma unroll
        for (int i = 0; i < 8; ++i) v[i] = 0.f;
      }
#pragma unroll
      for (int i = 0; i < 8; ++i) {
        float x = v[i];
        if (USEBN) x = fmaf(x, sSc[k0 + i], sSh[k0 + i]);
        if (INACT == 1) x = fmaxf(x, 0.f);
        else if (INACT == 2) x = (x > 0.f) ? x : expm1f(x);
        afr[rt][i] = (short)f2bf(x);
      }
    }
    short8 bfr[4];
#pragma unroll
    for (int ct = 0; ct < 4; ++ct)
      bfr[ct] = *(const short8*)&BT[ct * 16 + cl][k0];
#pragma unroll
    for (int rt = 0; rt < 2; ++rt)
#pragma unroll
      for (int ct = 0; ct < 4; ++ct)
        acc[rt][ct] = __builtin_amdgcn_mfma_f32_16x16x32_bf16(
            afr[rt], bfr[ct], acc[rt][ct], 0, 0, 0);
  }

  float bb[4], as4[4], ad4[4];
#pragma unroll
  for (int ct = 0; ct < 4; ++ct) {
    int gc = colBase + ct * 16 + cl;
    bb[ct] = biasOut ? biasOut[gc] : 0.f;
    if (ATTMODE) {
      as4[ct] = attSrc[gc];
      ad4[ct] = attDst[gc];
    }
  }
#pragma unroll
  for (int rt = 0; rt < 2; ++rt) {
    float pes[4] = {0.f, 0.f, 0.f, 0.f};
    float ped[4] = {0.f, 0.f, 0.f, 0.f};
#pragma unroll
    for (int reg = 0; reg < 4; ++reg) {
      int gr = rowBase + wv * 32 + rt * 16 + kg * 4 + reg;
      bool ok = gr < M;
      float rs_ = 1.f;
      if (ok && Cbf && rowScale) rs_ = rowScale[gr];
#pragma unroll
      for (int ct = 0; ct < 4; ++ct) {
        float v = acc[rt][ct][reg] + bb[ct];
        if (outAct == 1) v = fmaxf(v, 0.f);
        int gc = colBase + ct * 16 + cl;
        if (ok) {
          if (Cf) Cf[(size_t)gr * NC + gc] = v;
          if (Cbf) Cbf[(size_t)gr * NC + gc] = f2bf(v * rs_);
        }
        if (ATTMODE) {
          pes[reg] = fmaf(v, as4[ct], pes[reg]);
          ped[reg] = fmaf(v, ad4[ct], ped[reg]);
        }
      }
    }
    if (ATTMODE) {
#pragma unroll
      for (int reg = 0; reg < 4; ++reg) {
#pragma unroll
        for (int off = 8; off > 0; off >>= 1) {
          pes[reg] += __shfl_xor(pes[reg], off);
          ped[reg] += __shfl_xor(ped[reg], off);
        }
      }
      if (cl == 0) {
#pragma unroll
        for (int reg = 0; reg < 4; ++reg) {
          int gr = rowBase + wv * 32 + rt * 16 + kg * 4 + reg;
          if (gr < M) {
            if (ATTMODE == 1) {
              esOut[gr * 4 + blockIdx.y] = pes[reg];
              edOut[gr * 4 + blockIdx.y] = ped[reg];
            } else {
              esOut[gr] = pes[reg];
              edOut[gr] = ped[reg];
            }
          }
        }
      }
    }
  }
}

// ---------------- GAT1: fused softmax (pass A) + gather (pass B) + BN1 stats ----
__global__ __launch_bounds__(256) void k_gat1(const unsigned short* __restrict__ h1b,
                                              const float* __restrict__ es,
                                              const float* __restrict__ ed,
                                              const int* __restrict__ rowptr,
                                              const int* __restrict__ csr,
                                              const float* __restrict__ b1,
                                              unsigned short* __restrict__ outb,
                                              float* __restrict__ st) {
  __shared__ float smS[4][256];
  __shared__ float smQ[4][256];
  int wave = threadIdx.x >> 6;
  int lane = threadIdx.x & 63;
  int i = blockIdx.x * 4 + wave;
  int start = rowptr[i], end = rowptr[i + 1];
  float4 edv = *(const float4*)&ed[i * 4];

  // ---- pass A: online softmax stats over all 64 lanes ----
  float m0 = -1e30f, m1 = -1e30f, m2 = -1e30f, m3 = -1e30f;
  float s0 = 0.f, s1 = 0.f, s2 = 0.f, s3 = 0.f;
  for (int k = start + lane; k < end; k += 64) {
    int s = csr[k];
    float4 esv = *(const float4*)&es[s * 4];
    float e0 = leaky(esv.x + edv.x);
    float e1 = leaky(esv.y + edv.y);
    float e2 = leaky(esv.z + edv.z);
    float e3 = leaky(esv.w + edv.w);
    float mn;
    mn = fmaxf(m0, e0); s0 = s0 * __expf(m0 - mn) + __expf(e0 - mn); m0 = mn;
    mn = fmaxf(m1, e1); s1 = s1 * __expf(m1 - mn) + __expf(e1 - mn); m1 = mn;
    mn = fmaxf(m2, e2); s2 = s2 * __expf(m2 - mn) + __expf(e2 - mn); m2 = mn;
    mn = fmaxf(m3, e3); s3 = s3 * __expf(m3 - mn) + __expf(e3 - mn); m3 = mn;
  }
#pragma unroll
  for (int off = 1; off < 64; off <<= 1) {
    float mo, so, mn;
    mo = __shfl_xor(m0, off); so = __shfl_xor(s0, off);
    mn = fmaxf(m0, mo); s0 = s0 * __expf(m0 - mn) + so * __expf(mo - mn); m0 = mn;
    mo = __shfl_xor(m1, off); so = __shfl_xor(s1, off);
    mn = fmaxf(m1, mo); s1 = s1 * __expf(m1 - mn) + so * __expf(mo - mn); m1 = mn;
    mo = __shfl_xor(m2, off); so = __shfl_xor(s2, off);
    mn = fmaxf(m2, mo); s2 = s2 * __expf(m2 - mn) + so * __expf(mo - mn); m2 = mn;
    mo = __shfl_xor(m3, off); so = __shfl_xor(s3, off);
    mn = fmaxf(m3, mo); s3 = s3 * __expf(m3 - mn) + so * __expf(mo - mn); m3 = mn;
  }

  // ---- pass B layout: half x head x 8-channel-group ----
  int half = lane >> 5;
  int cl5 = lane & 31;
  int head = cl5 >> 3;
  int cOff = cl5 * 8;
  float mh  = (head == 0) ? m0 : (head == 1) ? m1 : (head == 2) ? m2 : m3;
  float sh  = (head == 0) ? s0 : (head == 1) ? s1 : (head == 2) ? s2 : s3;
  float edh = (head == 0) ? edv.x : (head == 1) ? edv.y : (head == 2) ? edv.z : edv.w;
  float inv = 1.f / (sh + 1e-16f);

  float acc[8];
#pragma unroll
  for (int j = 0; j < 8; ++j) acc[j] = 0.f;

  int k = start;
  for (; k + 4 <= end; k += 4) {
#pragma unroll
    for (int u = 0; u < 2; ++u) {
      int kk = k + u * 2 + half;
      int s = csr[kk];
      float e = leaky(es[s * 4 + head] + edh);
      float wv = __expf(e - mh) * inv;
      ushort8v hv = *(const ushort8v*)&h1b[(size_t)s * 256 + cOff];
#pragma unroll
      for (int j = 0; j < 8; ++j) acc[j] = fmaf(bf2f(hv[j]), wv, acc[j]);
    }
  }
  for (; k + 2 <= end; k += 2) {
    int kk = k + half;
    int s = csr[kk];
    float e = leaky(es[s * 4 + head] + edh);
    float wv = __expf(e - mh) * inv;
    ushort8v hv = *(const ushort8v*)&h1b[(size_t)s * 256 + cOff];
#pragma unroll
    for (int j = 0; j < 8; ++j) acc[j] = fmaf(bf2f(hv[j]), wv, acc[j]);
  }
  if (k < end) {
    int s = csr[k];
    float e = leaky(es[s * 4 + head] + edh);
    float wv = (half == 0) ? __expf(e - mh) * inv : 0.f;
    ushort8v hv = *(const ushort8v*)&h1b[(size_t)s * 256 + cOff];
#pragma unroll
    for (int j = 0; j < 8; ++j) acc[j] = fmaf(bf2f(hv[j]), wv, acc[j]);
  }
#pragma unroll
  for (int j = 0; j < 8; ++j) acc[j] += __shfl_xor(acc[j], 32);

  float4 b0 = *(const float4*)&b1[cOff];
  float4 b1v = *(const float4*)&b1[cOff + 4];
  float bb[8] = {b0.x, b0.y, b0.z, b0.w, b1v.x, b1v.y, b1v.z, b1v.w};
  if (half == 0) {
    float o[8];
    ushort8v u8;
#pragma unroll
    for (int j = 0; j < 8; ++j) {
      o[j] = acc[j] + bb[j];
      u8[j] = f2bf(o[j]);
    }
    *(ushort8v*)&outb[(size_t)i * 256 + cOff] = u8;
    float4 s0_ = make_float4(o[0], o[1], o[2], o[3]);
    float4 s1_ = make_float4(o[4], o[5], o[6], o[7]);
    *(float4*)&smS[wave][cOff] = s0_;
    *(float4*)&smS[wave][cOff + 4] = s1_;
    float4 q0 = make_float4(o[0]*o[0], o[1]*o[1], o[2]*o[2], o[3]*o[3]);
    float4 q1 = make_float4(o[4]*o[4], o[5]*o[5], o[6]*o[6], o[7]*o[7]);
    *(float4*)&smQ[wave][cOff] = q0;
    *(float4*)&smQ[wave][cOff + 4] = q1;
  }
  __syncthreads();
  int c = threadIdx.x;
  float s_ = 0.f, q_ = 0.f;
#pragma unroll
  for (int wv = 0; wv < 4; ++wv) { s_ += smS[wv][c]; q_ += smQ[wv][c]; }
  float* dst = st + (size_t)(blockIdx.x & 31) * 512;
  atomicAdd(&dst[c], s_);
  atomicAdd(&dst[256 + c], q_);
}

// ---------------- GCN gather: 8 edges/wave-step, ushort8; bf16 out ----------------
__global__ __launch_bounds__(256) void k_gcn(const unsigned short* __restrict__ hgb,
                                             const float* __restrict__ dinv,
                                             const int* __restrict__ rowptr,
                                             const int* __restrict__ csr,
                                             const float* __restrict__ bg,
                                             unsigned short* __restrict__ outb,
                                             float* __restrict__ st) {
  __shared__ float smS[4][64];
  __shared__ float smQ[4][64];
  int wave = threadIdx.x >> 6;
  int lane = threadIdx.x & 63;
  int i = blockIdx.x * 4 + wave;
  int start = rowptr[i], end = rowptr[i + 1];
  int grp = lane >> 3;
  int cOff = (lane & 7) * 8;
  float acc[8];
#pragma unroll
  for (int j = 0; j < 8; ++j) acc[j] = 0.f;

  int k = start;
  for (; k + 8 <= end; k += 8) {
    int s = csr[k + grp];
    ushort8v hv = *(const ushort8v*)&hgb[(size_t)s * 64 + cOff];
#pragma unroll
    for (int j = 0; j < 8; ++j) acc[j] += bf2f(hv[j]);
  }
  if (k < end) {
    int kk = k + grp;
    bool act = kk < end;
    int s = csr[act ? kk : start];
    float m_ = act ? 1.f : 0.f;
    ushort8v hv = *(const ushort8v*)&hgb[(size_t)s * 64 + cOff];
#pragma unroll
    for (int j = 0; j < 8; ++j) acc[j] = fmaf(bf2f(hv[j]), m_, acc[j]);
  }
#pragma unroll
  for (int off = 8; off <= 32; off <<= 1)
#pragma unroll
    for (int j = 0; j < 8; ++j) acc[j] += __shfl_xor(acc[j], off);

  if (lane < 8) {
    float di = dinv[i];
    float4 g0 = *(const float4*)&bg[cOff];
    float4 g1 = *(const float4*)&bg[cOff + 4];
    float bb[8] = {g0.x, g0.y, g0.z, g0.w, g1.x, g1.y, g1.z, g1.w};
    float o[8];
    ushort8v u8;
#pragma unroll
    for (int j = 0; j < 8; ++j) {
      o[j] = fmaf(acc[j], di, bb[j]);
      u8[j] = f2bf(o[j]);
      smS[wave][cOff + j] = o[j];
      smQ[wave][cOff + j] = o[j] * o[j];
    }
    *(ushort8v*)&outb[(size_t)i * 64 + cOff] = u8;
  }
  __syncthreads();
  if (threadIdx.x < 64) {
    int c = threadIdx.x;
    float s_ = 0.f, q_ = 0.f;
#pragma unroll
    for (int wv = 0; wv < 4; ++wv) { s_ += smS[wv][c]; q_ += smQ[wv][c]; }
    float* dst = st + (size_t)(blockIdx.x & 31) * 128;
    atomicAdd(&dst[c], s_);
    atomicAdd(&dst[64 + c], q_);
  }
}

// ---------------- GAT2: fused softmax + gather + BN3 stats ----------------
__global__ __launch_bounds__(256) void k_gat2(const unsigned short* __restrict__ h2b,
                                              const float* __restrict__ es,
                                              const float* __restrict__ ed,
                                              const int* __restrict__ rowptr,
                                              const int* __restrict__ csr,
                                              const float* __restrict__ b2,
                                              unsigned short* __restrict__ outb,
                                              float* __restrict__ st) {
  __shared__ float smS[4][64];
  __shared__ float smQ[4][64];
  int wave = threadIdx.x >> 6;
  int lane = threadIdx.x & 63;
  int i = blockIdx.x * 4 + wave;
  int start = rowptr[i], end = rowptr[i + 1];
  float edi = ed[i];

  // pass A: online softmax stats
  float m = -1e30f, ss = 0.f;
  for (int k = start + lane; k < end; k += 64) {
    float e = leaky(es[csr[k]] + edi);
    float mn = fmaxf(m, e);
    ss = ss * __expf(m - mn) + __expf(e - mn);
    m = mn;
  }
#pragma unroll
  for (int off = 1; off < 64; off <<= 1) {
    float mo = __shfl_xor(m, off);
    float so = __shfl_xor(ss, off);
    float mn = fmaxf(m, mo);
    ss = ss * __expf(m - mn) + so * __expf(mo - mn);
    m = mn;
  }
  float inv = 1.f / (ss + 1e-16f);

  // pass B: 8 edges/step
  int grp = lane >> 3;
  int cOff = (lane & 7) * 8;
  float acc[8];
#pragma unroll
  for (int j = 0; j < 8; ++j) acc[j] = 0.f;

  int k = start;
  for (; k + 8 <= end; k += 8) {
    int kk = k + grp;
    int s = csr[kk];
    float e = leaky(es[s] + edi);
    float wv = __expf(e - m) * inv;
    ushort8v hv = *(const ushort8v*)&h2b[(size_t)s * 64 + cOff];
#pragma unroll
    for (int j = 0; j < 8; ++j) acc[j] = fmaf(bf2f(hv[j]), wv, acc[j]);
  }
  if (k < end) {
    int kk = k + grp;
    bool act = kk < end;
    int s = csr[act ? kk : start];
    float e = leaky(es[s] + edi);
    float wv = act ? __expf(e - m) * inv : 0.f;
    ushort8v hv = *(const ushort8v*)&h2b[(size_t)s * 64 + cOff];
#pragma unroll
    for (int j = 0; j < 8; ++j) acc[j] = fmaf(bf2f(hv[j]), wv, acc[j]);
  }
#pragma unroll
  for (int off = 8; off <= 32; off <<= 1)
#pragma unroll
    for (int j = 0; j < 8; ++j) acc[j] += __shfl_xor(acc[j], off);

  if (lane < 8) {
    float4 g0 = *(const float4*)&b2[cOff];
    float4 g1 = *(const float4*)&b2[cOff + 4];
    float bb[8] = {g0.x, g0.y, g0.z, g0.w, g1.x, g1.y, g1.z, g1.w};
    float o[8];
    ushort8v u8;
#pragma unroll
    for (int j = 0; j < 8; ++j) {
      o[j] = acc[j] + bb[j];
      u8[j] = f2bf(o[j]);
      smS[wave][cOff + j] = o[j];
      smQ[wave][cOff + j] = o[j] * o[j];
    }
    *(ushort8v*)&outb[(size_t)i * 64 + cOff] = u8;
  }
  __syncthreads();
  if (threadIdx.x < 64) {
    int c = threadIdx.x;
    float s_ = 0.f, q_ = 0.f;
#pragma unroll
    for (int wv = 0; wv < 4; ++wv) { s_ += smS[wv][c]; q_ += smQ[wv][c]; }
    float* dst = st + (size_t)(blockIdx.x & 31) * 128;
    atomicAdd(&dst[c], s_);
    atomicAdd(&dst[64 + c], q_);
  }
}

// ---------------- host ----------------
extern "C" void kernel_launch(void* const* d_in, const int* in_sizes, int n_in,
                              void* d_out, int out_size, void* d_ws, size_t ws_size,
                              hipStream_t stream) {
  const float* x        = (const float*)d_in[0];
  const int*   ei       = (const int*)d_in[1];
  const float* W1       = (const float*)d_in[3];
  const float* att_src1 = (const float*)d_in[4];
  const float* att_dst1 = (const float*)d_in[5];
  const float* b1       = (const float*)d_in[6];
  const float* g1       = (const float*)d_in[7];
  const float* beta1    = (const float*)d_in[8];
  const float* Wg       = (const float*)d_in[9];
  const float* bg       = (const float*)d_in[10];
  const float* g2       = (const float*)d_in[11];
  const float* beta2    = (const float*)d_in[12];
  const float* W2       = (const float*)d_in[13];
  const float* att_src2 = (const float*)d_in[14];
  const float* att_dst2 = (const float*)d_in[15];
  const float* b2       = (const float*)d_in[16];
  const float* g3       = (const float*)d_in[17];
  const float* beta3    = (const float*)d_in[18];
  const float* Wp1      = (const float*)d_in[19];
  const float* bp1      = (const float*)d_in[20];
  const float* Wp2      = (const float*)d_in[21];
  const float* bp2      = (const float*)d_in[22];
  float* out = (float*)d_out;

  char* w = (char*)d_ws;
  unsigned short* bufBb  = (unsigned short*)(w + 0);           // gat1 out bf16 [N,256]
  unsigned short* bufDb  = (unsigned short*)(w + 0);           // gat2 out bf16 [N,64] (alias)
  unsigned short* h1b    = (unsigned short*)(w + 51200000);    // [N,256] bf16
  unsigned short* hiddenb= (unsigned short*)(w + 51200000);    // proj hidden bf16 [N,128] (alias)
  unsigned short* hgb    = (unsigned short*)(w + 90400000);    // [N,64] bf16 (dinv-scaled)
  unsigned short* bufCb  = (unsigned short*)(w + 96800000);    // gcn out bf16 [N,64]
  unsigned short* h2b    = (unsigned short*)(w + 109600000);   // [N,64] bf16
  float*          es1    = (float*)(w + 116000000);
  float*          ed1    = (float*)(w + 116800000);
  float*          es2    = (float*)(w + 117600000);
  float*          ed2    = (float*)(w + 117800000);
  float*          dinv   = (float*)(w + 118000000);
  int*            deg    = (int*)(w + 118200000);
  int*            rowptr = (int*)(w + 118400000);
  int*            cnt    = (int*)(w + 118600064);
  int*            csr    = (int*)(w + 118800064);
  float*          st1    = (float*)(w + 122200064);            // 32*512 f32
  float*          st2    = st1 + 32 * 512;                     // 32*128 f32
  float*          st3    = st2 + 32 * 128;                     // 32*128 f32
  int*            partial= (int*)(st3 + 32 * 128);             // SCB ints

  hipMemsetAsync(deg, 0, NN * sizeof(int), stream);
  hipMemsetAsync(st1, 0, (32 * 512 + 32 * 128 + 32 * 128) * sizeof(float), stream);

  const int EB = (E2 + 255) / 256;
  const int WB = NN / 4;          // 12500

  // CSR build
  k_deg<<<EB, 256, 0, stream>>>(ei, deg);
  k_scan1<<<SCB, 256, 0, stream>>>(deg, partial);
  k_scan3<<<SCB, 256, 0, stream>>>(deg, partial, rowptr, cnt, dinv);
  k_fill<<<EB, 256, 0, stream>>>(ei, cnt, csr);

  // GAT1: h1 = x@W1 -> h1b bf16, es1/ed1 fused; gather has softmax fused
  k_gemm1<<<GXL, 256, 0, stream>>>(x, W1, h1b, att_src1, att_dst1, es1, ed1, NN);
  k_gat1<<<WB, 256, 0, stream>>>(h1b, es1, ed1, rowptr, csr, b1, bufBb, st1);

  // GCN: BN1+ELU fused into A frags; hgb pre-scaled by dinv[row]
  k_gemm_mfma<256, 0, 2, true, true><<<dim3(GXL, 1), 256, 0, stream>>>(
      nullptr, bufBb, Wg, nullptr, st1, g1, beta1, 0,
      nullptr, hgb, dinv, nullptr, nullptr, nullptr, nullptr, NN, 64);
  k_gcn<<<WB, 256, 0, stream>>>(hgb, dinv, rowptr, csr, bg, bufCb, st2);

  // GAT2: BN2+ReLU fused; es2/ed2 fused (1 head); gather has softmax fused
  k_gemm_mfma<64, 2, 1, true, true><<<dim3(GXL, 1), 256, 0, stream>>>(
      nullptr, bufCb, W2, nullptr, st2, g2, beta2, 0,
      nullptr, h2b, nullptr, att_src2, att_dst2, es2, ed2, NN, 64);
  k_gat2<<<WB, 256, 0, stream>>>(h2b, es2, ed2, rowptr, csr, b2, bufDb, st3);

  // projector: BN3+ELU fused into p1 A-frags, ReLU out -> hiddenb bf16 (NC=128: 2 col blocks)
  k_gemm_mfma<64, 0, 2, true, true><<<dim3(GXL, 2), 256, 0, stream>>>(
      nullptr, bufDb, Wp1, bp1, st3, g3, beta3, 1,
      nullptr, hiddenb, nullptr, nullptr, nullptr, nullptr, nullptr, NN, 128);
  k_gemm_mfma<128, 0, 0, true, false><<<dim3(GXL, 1), 256, 0, stream>>>(
      nullptr, hiddenb, Wp2, bp2, nullptr, nullptr, nullptr, 0,
      out, nullptr, nullptr, nullptr, nullptr, nullptr, nullptr, NN, 64);
}